// Round 2
// baseline (338.662 us; speedup 1.0000x reference)
//
#include <hip/hip_runtime.h>
#include <cstdint>
#include <cstddef>

typedef __attribute__((ext_vector_type(8))) short short8;
typedef __attribute__((ext_vector_type(8))) unsigned short ushort8;
typedef __attribute__((ext_vector_type(4))) float f32x4;

#define EPSV 1e-5f
#define NB 1024
#define NEDGE 1048576
#define EPG 1024
#define CNTF 65536.0f
#define REP 32           // stats replica slots (contention spreading)
#define MAXGRID 1024     // never launch more than this (work max = 1441 items phase0)
#define BARSLOT 64       // u32 per barrier slot (256 B -> no line sharing)
#define NPHASE 4

__device__ __forceinline__ ushort f2bf(float f) {
  uint u = __float_as_uint(f);
  return (ushort)((u + 0x7FFFu + ((u >> 16) & 1u)) >> 16);
}
__device__ __forceinline__ float bf2f(ushort u) {
  return __uint_as_float((uint)u << 16);
}

// ---------------------------------------------------------------------------
// LDS union: per-phase layouts overlap. Max member = conv (36,384 B) -> with
// __launch_bounds__(256,4) (VGPR<=128) 4 blocks/CU fit (145.5 KB LDS/CU).
// ---------------------------------------------------------------------------
union __align__(16) SMem {
  struct { ushort T[64][72]; } prep;                                 //  9,216 B
  struct { float xs[64]; float aggT[4][5][72]; float aggC[64][8];
           float w1s[8], b1s[4], w2s[256], b2s[64];
           float rs[4][64], rss[4][64]; } edge;                      // ~11,424 B
  struct { ushort As[64][200]; ushort Yt[66][72];
           float aco[64], bco[64], cbs[64], ldsS[64], ldsSS[64]; } conv; // 36,384 B
  struct { ushort Ys[32][72]; ushort Ws[64][72];
           float a3s[64], b3s[64]; } mlp;                            // 14,336 B
  struct { ushort h1s[16][264]; ushort h2s[16][264]; } tail;         // 16,896 B
};

// ---------------------------------------------------------------------------
// Software grid barrier (two-level, per-phase counters; zeroed by memset
// before each launch). Arrival: 1 agent-scope atomic per block on a leaf
// (32 leaves, 256B apart); last leaf arriver promotes to root; all spin on
// root. Pre-barrier __syncthreads drains each wave's stores (vmcnt(0)), so
// the leader's release-RMW publishes the whole block's writes; the acquire
// load invalidates L1 (+ stale cross-XCD L2 lines) for the CU.
// Stale (non-zero) counters -- e.g. rocprof kernel replay without the memset
// -- make barriers fall through; they can never deadlock.
// ---------------------------------------------------------------------------
__device__ __forceinline__ void gbar(unsigned* bar, int phase, int bid,
                                     int nblk, int tid)
{
  __syncthreads();
  if (tid == 0) {
    const int lf = bid & 31;
    unsigned* leaf = bar + (size_t)(phase * 33 + lf) * BARSLOT;
    unsigned* root = bar + (size_t)(phase * 33 + 32) * BARSLOT;
    const unsigned leafcnt = (unsigned)((nblk + 31 - lf) >> 5); // blocks on this leaf
    const unsigned nleaf = (unsigned)(nblk < 32 ? nblk : 32);
    __threadfence();
    unsigned old = __hip_atomic_fetch_add(leaf, 1u, __ATOMIC_ACQ_REL,
                                          __HIP_MEMORY_SCOPE_AGENT);
    if (old >= leafcnt - 1)
      __hip_atomic_fetch_add(root, 1u, __ATOMIC_ACQ_REL,
                             __HIP_MEMORY_SCOPE_AGENT);
    while (__hip_atomic_load(root, __ATOMIC_ACQUIRE,
                             __HIP_MEMORY_SCOPE_AGENT) < nleaf)
      __builtin_amdgcn_s_sleep(8);
  }
  __syncthreads();
}

// ---------------------------------------------------------------------------
// phase 0a: weight preprocessing (items 0..416), identical math to the
// verified k_prepw minus the stats zeroing (done by hipMemsetAsync).
// ---------------------------------------------------------------------------
__device__ __forceinline__ void prep_body(
    SMem& sm, const int bb, const int tid,
    const float* __restrict__ wm1, const float* __restrict__ wm2,
    const float* __restrict__ wm3, const float* __restrict__ wp,
    const float* __restrict__ c2w, const float* __restrict__ c3w,
    ushort* __restrict__ wbf1t, ushort* __restrict__ wbf2t,
    ushort* __restrict__ wbf3t, ushort* __restrict__ wptbf,
    ushort* __restrict__ cwt2, ushort* __restrict__ cwt3)
{
  if (bb < 256) {
    auto& T = sm.prep.T;
    const int kc = bb >> 2, n0 = (bb & 3) << 6;
    const int kk = tid >> 2, np = (tid & 3) << 4;
    const float* srow = wm1 + (((size_t)(kk << 6) + kc) << 8) + n0 + np;
#pragma unroll
    for (int i = 0; i < 4; ++i) {
      const float4 v = *(const float4*)(srow + (i << 2));
      const int n = np + (i << 2);
      T[n + 0][kk] = f2bf(v.x); T[n + 1][kk] = f2bf(v.y);
      T[n + 2][kk] = f2bf(v.z); T[n + 3][kk] = f2bf(v.w);
    }
    __syncthreads();
    ushort* dst = wbf1t + ((size_t)kc << 14) + (n0 << 6);
    const int nl = tid >> 2, qk = (tid & 3) << 4;
    *(ushort8*)(dst + (nl << 6) + qk) = *(ushort8*)&T[nl][qk];
    *(ushort8*)(dst + (nl << 6) + qk + 8) = *(ushort8*)&T[nl][qk + 8];
    return;
  }
  if (bb < 320) {
    const int base = (((bb - 256) << 8) + tid) << 3;
    const int m = base >> 16;
    const int rem = base & 65535;
    const int kc = rem >> 14, within = rem & 16383;
    const int n = within >> 6, kk0 = within & 63;
    const float* src = m ? wm3 : wm2;
    ushort* dst = m ? wbf3t : wbf2t;
    ushort tmp[8];
#pragma unroll
    for (int j = 0; j < 8; ++j)
      tmp[j] = f2bf(src[(((kc << 6) | (kk0 + j)) << 8) + n]);
    *(ushort8*)&dst[rem] = *(ushort8*)&tmp[0];
    return;
  }
  if (bb == 320) {
    const int a = tid & 15, k0 = (tid >> 4) << 4;
    ushort tmp[16];
#pragma unroll
    for (int j = 0; j < 16; ++j) tmp[j] = f2bf(wp[((k0 + j) << 4) + a]);
    *(ushort8*)&wptbf[(a << 8) + k0] = *(ushort8*)&tmp[0];
    *(ushort8*)&wptbf[(a << 8) + k0 + 8] = *(ushort8*)&tmp[8];
    return;
  }
  // items 321..416: conv weights [o][c][kk] -> bf16 [o][kk*64+c]
  const int flat = (bb - 321) * 256 + tid;   // 0..24575
  const int m = flat >= 12288;
  const int idx = flat - (m ? 12288 : 0);
  const float* src = m ? c3w : c2w;
  ushort* dst = m ? cwt3 : cwt2;
  const int o = idx / 192, rem = idx - o * 192;
  const int kk = rem >> 6, cc = rem & 63;
  dst[idx] = f2bf(src[o * 192 + cc * 3 + kk]);
}

// ---------------------------------------------------------------------------
// phase 0b: EdgeConv for graph b (verified k_edge body).
// ---------------------------------------------------------------------------
__device__ __forceinline__ void edge_body(
    SMem& sm, const int b, const int tid,
    const float* __restrict__ x, const int* __restrict__ ei,
    const float* __restrict__ w1, const float* __restrict__ b1,
    const float* __restrict__ w2, const float* __restrict__ b2,
    ushort* __restrict__ out0, float* __restrict__ stats1)
{
  auto& E = sm.edge;
  const int w = tid >> 6;
  __syncthreads();                       // protect LDS union vs prior phase
  if (tid < 8) E.w1s[tid] = w1[tid];
  if (tid < 4) E.b1s[tid] = b1[tid];
  if (tid < 64) { E.xs[tid] = x[(b << 6) + tid]; E.b2s[tid] = b2[tid]; }
  E.w2s[tid] = w2[tid];
  for (int i = tid; i < 1440; i += 256) (&E.aggT[0][0][0])[i] = 0.f;
  __syncthreads();

  const int e0 = b * EPG;
  const int4 s4 = ((const int4*)(ei + e0))[tid];
  const int4 d4 = ((const int4*)(ei + NEDGE + e0))[tid];
  float* agw = &E.aggT[w][0][0];
  const int sls[4] = {s4.x & 63, s4.y & 63, s4.z & 63, s4.w & 63};
  const int dls[4] = {d4.x & 63, d4.y & 63, d4.z & 63, d4.w & 63};
#pragma unroll
  for (int e = 0; e < 4; ++e) {
    const int dl = dls[e];
    const float xi = E.xs[dl];
    const float dx = E.xs[sls[e]] - xi;
#pragma unroll
    for (int j = 0; j < 4; ++j) {
      float h = fmaxf(fmaf(xi, E.w1s[j], fmaf(dx, E.w1s[4 + j], E.b1s[j])), 0.f);
      atomicAdd(&agw[j * 72 + dl], h);
    }
    atomicAdd(&agw[4 * 72 + dl], 1.0f);
  }
  __syncthreads();

  if (tid < 64) {
    const int n = tid;
    const float a0 = E.aggT[0][0][n] + E.aggT[1][0][n] + E.aggT[2][0][n] + E.aggT[3][0][n];
    const float a1 = E.aggT[0][1][n] + E.aggT[1][1][n] + E.aggT[2][1][n] + E.aggT[3][1][n];
    const float a2 = E.aggT[0][2][n] + E.aggT[1][2][n] + E.aggT[2][2][n] + E.aggT[3][2][n];
    const float a3v = E.aggT[0][3][n] + E.aggT[1][3][n] + E.aggT[2][3][n] + E.aggT[3][3][n];
    const float dg = E.aggT[0][4][n] + E.aggT[1][4][n] + E.aggT[2][4][n] + E.aggT[3][4][n];
    *(float4*)&E.aggC[n][0] = make_float4(a0, a1, a2, a3v);
    E.aggC[n][4] = dg;
  }
  __syncthreads();

  const int c = tid & 63, qq = tid >> 6;
  const float wc0 = E.w2s[c], wc1 = E.w2s[64 + c], wc2 = E.w2s[128 + c], wc3 = E.w2s[192 + c];
  const float b2c = E.b2s[c];
  float s = 0.f, ss = 0.f;
  for (int n = qq; n < 64; n += 4) {
    const float4 a = *(const float4*)&E.aggC[n][0];
    const float dg = E.aggC[n][4];
    float v = a.x * wc0 + a.y * wc1 + a.z * wc2 + a.w * wc3 + dg * b2c;
    out0[(size_t)(((b << 6) + n) << 6) + c] = f2bf(v);
    s += v; ss += v * v;
  }
  E.rs[qq][c] = s; E.rss[qq][c] = ss;
  __syncthreads();
  if (tid < 64) {
    float* dst = stats1 + ((b & (REP - 1)) << 7);
    atomicAdd(&dst[tid], E.rs[0][tid] + E.rs[1][tid] + E.rs[2][tid] + E.rs[3][tid]);
    atomicAdd(&dst[64 + tid], E.rss[0][tid] + E.rss[1][tid] + E.rss[2][tid] + E.rss[3][tid]);
  }
}

// ---------------------------------------------------------------------------
// phases 1/2: BN + conv1d-as-MFMA for graph b (verified k_convm body).
// ---------------------------------------------------------------------------
__device__ __forceinline__ void conv_body(
    SMem& sm, const int b, const int tid,
    const ushort* __restrict__ in, const float* __restrict__ stats_in,
    const float* __restrict__ gamma, const float* __restrict__ beta,
    const ushort* __restrict__ cwt, const float* __restrict__ cb,
    ushort* __restrict__ out, float* __restrict__ stats_out)
{
  auto& C = sm.conv;
  __syncthreads();                       // protect LDS union vs prior phase
  if (tid < 64) {
    float smv = 0.f, sq = 0.f;
#pragma unroll 8
    for (int r = 0; r < REP; ++r) {
      smv += stats_in[(r << 7) + tid];
      sq += stats_in[(r << 7) + 64 + tid];
    }
    const float mean = smv * (1.0f / CNTF);
    const float var = sq * (1.0f / CNTF) - mean * mean;
    const float a = gamma[tid] * rsqrtf(var + EPSV);
    C.aco[tid] = a;
    C.bco[tid] = beta[tid] - mean * a;
    C.cbs[tid] = cb[tid];
    C.Yt[0][tid] = 0;
    C.Yt[65][tid] = 0;
  }
  __syncthreads();

  const size_t base = (size_t)b << 12;
  {
    const int lr = tid >> 2, p = (tid & 3) << 4;
    const ushort8 r0 = *(const ushort8*)&in[base + (lr << 6) + p];
    const ushort8 r1 = *(const ushort8*)&in[base + (lr << 6) + p + 8];
    ushort tmp[16];
#pragma unroll
    for (int j = 0; j < 8; ++j)
      tmp[j] = f2bf(fmaxf(fmaf(C.aco[p + j], bf2f(r0[j]), C.bco[p + j]), 0.f));
#pragma unroll
    for (int j = 0; j < 8; ++j)
      tmp[8 + j] = f2bf(fmaxf(fmaf(C.aco[p + 8 + j], bf2f(r1[j]), C.bco[p + 8 + j]), 0.f));
    *(ushort8*)&C.Yt[lr + 1][p] = *(ushort8*)&tmp[0];
    *(ushort8*)&C.Yt[lr + 1][p + 8] = *(ushort8*)&tmp[8];
  }
  {
    const ushort8* gw = (const ushort8*)cwt;
#pragma unroll
    for (int i = 0; i < 6; ++i) {
      const int e8 = (i << 8) + tid;
      const int o = e8 / 24, k8 = (e8 - o * 24) << 3;
      *(ushort8*)&C.As[o][k8] = gw[e8];
    }
  }
  __syncthreads();

  const int lane = tid & 63, w = tid >> 6;
  const int lm = lane & 15, q = lane >> 4;
  f32x4 acc[4];
#pragma unroll
  for (int nt = 0; nt < 4; ++nt) acc[nt] = (f32x4){0.f, 0.f, 0.f, 0.f};

#pragma unroll
  for (int kk = 0; kk < 3; ++kk) {
#pragma unroll
    for (int ks = 0; ks < 2; ++ks) {
      const short8 af = *(const short8*)&C.As[(w << 4) + lm][(kk << 6) + (ks << 5) + (q << 3)];
#pragma unroll
      for (int nt = 0; nt < 4; ++nt) {
        const short8 bfr = *(const short8*)&C.Yt[(nt << 4) + lm + kk][(ks << 5) + (q << 3)];
        acc[nt] = __builtin_amdgcn_mfma_f32_16x16x32_bf16(af, bfr, acc[nt], 0, 0, 0);
      }
    }
  }

  const int obase = (w << 4) + (q << 2);
  const float4 cb4 = *(const float4*)&C.cbs[obase];
  float s[4] = {0.f, 0.f, 0.f, 0.f}, ss[4] = {0.f, 0.f, 0.f, 0.f};
#pragma unroll
  for (int nt = 0; nt < 4; ++nt) {
    const int l = (nt << 4) + lm;
    float4 v = make_float4(acc[nt][0] + cb4.x, acc[nt][1] + cb4.y,
                           acc[nt][2] + cb4.z, acc[nt][3] + cb4.w);
    *(ushort4*)&out[base + (l << 6) + obase] =
        make_ushort4(f2bf(v.x), f2bf(v.y), f2bf(v.z), f2bf(v.w));
    s[0] += v.x; ss[0] += v.x * v.x;
    s[1] += v.y; ss[1] += v.y * v.y;
    s[2] += v.z; ss[2] += v.z * v.z;
    s[3] += v.w; ss[3] += v.w * v.w;
  }
#pragma unroll
  for (int i = 0; i < 4; ++i) {
#pragma unroll
    for (int off = 1; off < 16; off <<= 1) {
      s[i] += __shfl_xor(s[i], off);
      ss[i] += __shfl_xor(ss[i], off);
    }
    if (lm == 0) { C.ldsS[obase + i] = s[i]; C.ldsSS[obase + i] = ss[i]; }
  }
  __syncthreads();
  if (tid < 64) {
    float* dst = stats_out + ((b & (REP - 1)) << 7);
    atomicAdd(&dst[tid], C.ldsS[tid]);
    atomicAdd(&dst[64 + tid], C.ldsSS[tid]);
  }
}

// ---------------------------------------------------------------------------
// phase 3: mlp1 tiled as 1024 items: 32 M-tiles (32 graphs) x 4 N-tiles (64)
// x 8 K-splits. Same K order / fp32 partial layout as the verified k_mlp1.
// ---------------------------------------------------------------------------
__device__ __forceinline__ void mlp_body(
    SMem& sm, const int bid, const int tid,
    const ushort* __restrict__ z3, const float* __restrict__ stats3,
    const float* __restrict__ g3, const float* __restrict__ be3,
    const ushort* __restrict__ wbf1t, float* __restrict__ h1part)
{
  auto& M = sm.mlp;
  const int bz = bid >> 7;          // 0..7  K-split
  const int bx = (bid >> 2) & 31;   // 0..31 M-tile (32 graphs)
  const int by = bid & 3;           // 0..3  N-tile (64)
  __syncthreads();                  // protect LDS union vs prior phase
  if (tid < 64) {
    float sme = 0.f, sq = 0.f;
#pragma unroll 8
    for (int r = 0; r < REP; ++r) {
      sme += stats3[(r << 7) + tid];
      sq += stats3[(r << 7) + 64 + tid];
    }
    const float mean = sme * (1.0f / CNTF);
    const float var = sq * (1.0f / CNTF) - mean * mean;
    const float a = g3[tid] * rsqrtf(var + EPSV);
    M.a3s[tid] = a;
    M.b3s[tid] = be3[tid] - mean * a;
  }
  __syncthreads();

  const int lane = tid & 63, w = tid >> 6;
  const int lm = lane & 15, q = lane >> 4;
  const int wr = w >> 1, wc = w & 1;            // wave -> (M half, N half)
  const int gy = tid >> 3, py = (tid & 7) << 3; // Ys staging: 32 rows x 8
  const int nn = tid >> 2, pw = tid & 3;        // Ws staging: 64 rows x 16
  const int g0 = bx << 5, n0 = by << 6;

  f32x4 acc[2];
#pragma unroll
  for (int nt = 0; nt < 2; ++nt) acc[nt] = (f32x4){0.f, 0.f, 0.f, 0.f};

  const size_t ybase = ((size_t)(g0 + gy) << 12);

#pragma unroll 1
  for (int ck = 0; ck < 8; ++ck) {
    const int kc = (bz << 9) + (ck << 6);
    if (ck) __syncthreads();
    // --- stage Ys: BN3+ReLU on bf16 z3 (channel = within-chunk index)
    {
      const ushort8 r0 = *(const ushort8*)(z3 + ybase + kc + py);
      ushort tmp[8];
#pragma unroll
      for (int j = 0; j < 8; ++j)
        tmp[j] = f2bf(fmaxf(fmaf(M.a3s[py + j], bf2f(r0[j]), M.b3s[py + j]), 0.f));
      *(ushort8*)&M.Ys[gy][py] = *(ushort8*)&tmp[0];
    }
    // --- stage Ws: straight copies from chunk-major wbf1t
    {
      const ushort8* gw = (const ushort8*)(wbf1t + ((size_t)((bz << 3) + ck) << 14) + ((size_t)n0 << 6));
      *(ushort8*)&M.Ws[nn][pw << 4] = gw[(nn << 3) + (pw << 1)];
      *(ushort8*)&M.Ws[nn][(pw << 4) + 8] = gw[(nn << 3) + (pw << 1) + 1];
    }
    __syncthreads();
#pragma unroll
    for (int ks = 0; ks < 2; ++ks) {
      const short8 af = *(const short8*)&M.Ys[(wr << 4) + lm][(ks << 5) + (q << 3)];
#pragma unroll
      for (int nt = 0; nt < 2; ++nt) {
        const short8 bfr = *(const short8*)&M.Ws[(wc << 5) + (nt << 4) + lm][(ks << 5) + (q << 3)];
        acc[nt] = __builtin_amdgcn_mfma_f32_16x16x32_bf16(af, bfr, acc[nt], 0, 0, 0);
      }
    }
  }

  float* dst0 = h1part + ((size_t)bz << 18);
  const int gout = g0 + (wr << 4) + (q << 2);
#pragma unroll
  for (int nt = 0; nt < 2; ++nt) {
    const int col = n0 + (wc << 5) + (nt << 4) + lm;
#pragma unroll
    for (int i = 0; i < 4; ++i)
      dst0[((size_t)(gout + i) << 8) + col] = acc[nt][i];
  }
}

// ---------------------------------------------------------------------------
// phase 4: tail (items 0..63, 16 graphs each). GEMM2/GEMM3/logits read the
// B-operand directly from L2-hot global (no Ws LDS -> union stays small).
// ---------------------------------------------------------------------------
__device__ __forceinline__ void tail_body(
    SMem& sm, const int bid, const int tid,
    const float* __restrict__ h1part, const float* __restrict__ bm1,
    const ushort* __restrict__ wbf2t, const float* __restrict__ bm2,
    const ushort* __restrict__ wbf3t, const float* __restrict__ bm3,
    const ushort* __restrict__ wptbf, const float* __restrict__ bp,
    float* __restrict__ out)
{
  auto& T = sm.tail;
  const int g0 = bid << 4;
  const int lane = tid & 63, w = tid >> 6;
  const int lm = lane & 15, q = lane >> 4;
  const int gr = q << 2;

  __syncthreads();                  // protect LDS union vs prior phase
  {
    const int r = tid >> 4, c0 = (tid & 15) << 4;
    const float* srcb = h1part + ((size_t)(g0 + r) << 8) + c0;
#pragma unroll
    for (int i = 0; i < 4; ++i) {
      float4 vs = *(const float4*)(bm1 + c0 + (i << 2));
#pragma unroll
      for (int bz = 0; bz < 8; ++bz) {
        const float4 p = *(const float4*)(srcb + ((size_t)bz << 18) + (i << 2));
        vs.x += p.x; vs.y += p.y; vs.z += p.z; vs.w += p.w;
      }
      *(ushort4*)&T.h1s[r][c0 + (i << 2)] = make_ushort4(
          f2bf(fmaxf(vs.x, 0.f)), f2bf(fmaxf(vs.y, 0.f)),
          f2bf(fmaxf(vs.z, 0.f)), f2bf(fmaxf(vs.w, 0.f)));
    }
  }
  __syncthreads();

  // ---- GEMM2 (B direct from global)
  f32x4 acc[4];
#pragma unroll
  for (int nt = 0; nt < 4; ++nt) acc[nt] = (f32x4){0.f, 0.f, 0.f, 0.f};
#pragma unroll
  for (int ck = 0; ck < 4; ++ck) {
#pragma unroll
    for (int ks = 0; ks < 2; ++ks) {
      const short8 af = *(const short8*)&T.h1s[lm][(ck << 6) + (ks << 5) + (q << 3)];
#pragma unroll
      for (int nt = 0; nt < 4; ++nt) {
        const int n = (w << 6) + (nt << 4) + lm;
        const short8 bfr = *(const short8*)&wbf2t[((size_t)ck << 14) + (n << 6) + (ks << 5) + (q << 3)];
        acc[nt] = __builtin_amdgcn_mfma_f32_16x16x32_bf16(af, bfr, acc[nt], 0, 0, 0);
      }
    }
  }
#pragma unroll
  for (int nt = 0; nt < 4; ++nt) {
    const int col = (w << 6) + (nt << 4) + lm;
    const float bv = bm2[col];
#pragma unroll
    for (int i = 0; i < 4; ++i)
      T.h2s[gr + i][col] = f2bf(fmaxf(acc[nt][i] + bv, 0.f));
  }
  __syncthreads();

  // ---- GEMM3 (B direct from global)
  f32x4 acc2[4];
#pragma unroll
  for (int nt = 0; nt < 4; ++nt) acc2[nt] = (f32x4){0.f, 0.f, 0.f, 0.f};
#pragma unroll
  for (int ck = 0; ck < 4; ++ck) {
#pragma unroll
    for (int ks = 0; ks < 2; ++ks) {
      const short8 af = *(const short8*)&T.h2s[lm][(ck << 6) + (ks << 5) + (q << 3)];
#pragma unroll
      for (int nt = 0; nt < 4; ++nt) {
        const int n = (w << 6) + (nt << 4) + lm;
        const short8 bfr = *(const short8*)&wbf3t[((size_t)ck << 14) + (n << 6) + (ks << 5) + (q << 3)];
        acc2[nt] = __builtin_amdgcn_mfma_f32_16x16x32_bf16(af, bfr, acc2[nt], 0, 0, 0);
      }
    }
  }
  __syncthreads();                  // all h2s reads done before overwrite
#pragma unroll
  for (int nt = 0; nt < 4; ++nt) {
    const int col = (w << 6) + (nt << 4) + lm;
    const float bv = bm3[col];
#pragma unroll
    for (int i = 0; i < 4; ++i)
      T.h2s[gr + i][col] = f2bf(fmaxf(acc2[nt][i] + bv, 0.f));
  }
  __syncthreads();

  if (w == 0) {
    f32x4 lacc = (f32x4){0.f, 0.f, 0.f, 0.f};
#pragma unroll
    for (int ks = 0; ks < 8; ++ks) {
      const short8 af = *(const short8*)&T.h2s[lm][(ks << 5) + (q << 3)];
      const short8 bfr = *(const short8*)&wptbf[(lm << 8) + (ks << 5) + (q << 3)];
      lacc = __builtin_amdgcn_mfma_f32_16x16x32_bf16(af, bfr, lacc, 0, 0, 0);
    }
    const float bpv = bp[lm];
    float lg[4], mx[4], se[4];
#pragma unroll
    for (int i = 0; i < 4; ++i) {
      lg[i] = lacc[i] + bpv;
      float m = lg[i];
#pragma unroll
      for (int off = 1; off < 16; off <<= 1) m = fmaxf(m, __shfl_xor(m, off));
      mx[i] = m;
      float e = expf(lg[i] - m);
#pragma unroll
      for (int off = 1; off < 16; off <<= 1) e += __shfl_xor(e, off);
      se[i] = e;
    }
#pragma unroll
    for (int i = 0; i < 4; ++i)
      out[((g0 + gr + i) << 4) + lm] = (lg[i] - mx[i]) - logf(se[i]);
  }
}

// ---------------------------------------------------------------------------
// Fused persistent kernel: all 5 stages, 4 software grid barriers (3 BN
// batch-stat reductions + the h1part split-K reduction). Plain launch
// (capture-safe); grid sized by host occupancy query so every block is
// co-resident; persistent loops handle any nblk.
// ---------------------------------------------------------------------------
__global__ __launch_bounds__(256, 4) void k_all(
    const float* __restrict__ x, const int* __restrict__ ei,
    const float* __restrict__ w1, const float* __restrict__ b1,
    const float* __restrict__ w2, const float* __restrict__ b2,
    const float* __restrict__ c2w, const float* __restrict__ c2b,
    const float* __restrict__ c3w, const float* __restrict__ c3b,
    const float* __restrict__ g1, const float* __restrict__ be1,
    const float* __restrict__ g2, const float* __restrict__ be2,
    const float* __restrict__ g3, const float* __restrict__ be3,
    const float* __restrict__ wm1, const float* __restrict__ bm1,
    const float* __restrict__ wm2, const float* __restrict__ bm2,
    const float* __restrict__ wm3, const float* __restrict__ bm3,
    const float* __restrict__ wp, const float* __restrict__ bp,
    ushort* __restrict__ ubuf0, ushort* __restrict__ ubuf1,
    float* __restrict__ h1part,
    ushort* __restrict__ wbf1t, ushort* __restrict__ wbf2t,
    ushort* __restrict__ wbf3t, ushort* __restrict__ wptbf,
    ushort* __restrict__ cwt2, ushort* __restrict__ cwt3,
    float* __restrict__ stats, unsigned* __restrict__ bar,
    float* __restrict__ out, int nblk)
{
  __shared__ SMem sm;
  const int tid = threadIdx.x;
  const int bid = blockIdx.x;
  float* stats1 = stats;
  float* stats2 = stats + REP * 128;
  float* stats3 = stats + 2 * REP * 128;

  // phase 0: weight prep (items 0..416) + edge conv (items 417..1440)
  for (int it = bid; it < 417 + NB; it += nblk) {
    if (it < 417)
      prep_body(sm, it, tid, wm1, wm2, wm3, wp, c2w, c3w,
                wbf1t, wbf2t, wbf3t, wptbf, cwt2, cwt3);
    else
      edge_body(sm, it - 417, tid, x, ei, w1, b1, w2, b2, ubuf0, stats1);
  }
  gbar(bar, 0, bid, nblk, tid);
  // phase 1: BN1 + conv2
  for (int it = bid; it < NB; it += nblk)
    conv_body(sm, it, tid, ubuf0, stats1, g1, be1, cwt2, c2b, ubuf1, stats2);
  gbar(bar, 1, bid, nblk, tid);
  // phase 2: BN2 + conv3
  for (int it = bid; it < NB; it += nblk)
    conv_body(sm, it, tid, ubuf1, stats2, g2, be2, cwt3, c3b, ubuf0, stats3);
  gbar(bar, 2, bid, nblk, tid);
  // phase 3: BN3 + GEMM1 split-K partials
  for (int it = bid; it < NB; it += nblk)
    mlp_body(sm, it, tid, ubuf0, stats3, g3, be3, wbf1t, h1part);
  gbar(bar, 3, bid, nblk, tid);
  // phase 4: tail (items 0..63)
  for (int it = bid; it < 64; it += nblk)
    tail_body(sm, it, tid, h1part, bm1, wbf2t, bm2, wbf3t, bm3, wptbf, bp, out);
}

// ===========================================================================
// Fallback path: the previous verified 6-kernel chain (host-side if only;
// used if the occupancy query fails).
// ===========================================================================
__global__ __launch_bounds__(256) void k_prepw(
    const float* __restrict__ wm1, const float* __restrict__ wm2,
    const float* __restrict__ wm3, const float* __restrict__ wp,
    const float* __restrict__ c2w, const float* __restrict__ c3w,
    ushort* __restrict__ wbf1t, ushort* __restrict__ wbf2t,
    ushort* __restrict__ wbf3t, ushort* __restrict__ wptbf,
    ushort* __restrict__ cwt2, ushort* __restrict__ cwt3,
    float* __restrict__ stats)
{
  __shared__ SMem sm;
  const int tid = threadIdx.x;
  const int bb = blockIdx.x;
  if (bb == 417) {
    float4 z4 = make_float4(0.f, 0.f, 0.f, 0.f);
#pragma unroll
    for (int i = 0; i < 12; ++i) ((float4*)stats)[(i << 8) + tid] = z4;
    return;
  }
  prep_body(sm, bb, tid, wm1, wm2, wm3, wp, c2w, c3w,
            wbf1t, wbf2t, wbf3t, wptbf, cwt2, cwt3);
}

__global__ __launch_bounds__(256) void k_edge(
    const float* __restrict__ x, const int* __restrict__ ei,
    const float* __restrict__ w1, const float* __restrict__ b1,
    const float* __restrict__ w2, const float* __restrict__ b2,
    ushort* __restrict__ out0, float* __restrict__ stats1)
{
  __shared__ SMem sm;
  edge_body(sm, blockIdx.x, threadIdx.x, x, ei, w1, b1, w2, b2, out0, stats1);
}

__global__ __launch_bounds__(256) void k_convm(
    const ushort* __restrict__ in, const float* __restrict__ stats_in,
    const float* __restrict__ gamma, const float* __restrict__ beta,
    const ushort* __restrict__ cwt, const float* __restrict__ cb,
    ushort* __restrict__ out, float* __restrict__ stats_out)
{
  __shared__ SMem sm;
  conv_body(sm, blockIdx.x, threadIdx.x, in, stats_in, gamma, beta, cwt, cb,
            out, stats_out);
}

__global__ __launch_bounds__(256) void k_mlp1f(
    const ushort* __restrict__ z3, const float* __restrict__ stats3,
    const float* __restrict__ g3, const float* __restrict__ be3,
    const ushort* __restrict__ wbf1t, float* __restrict__ h1part)
{
  __shared__ SMem sm;
  mlp_body(sm, blockIdx.x, threadIdx.x, z3, stats3, g3, be3, wbf1t, h1part);
}

__global__ __launch_bounds__(256) void k_tailf(
    const float* __restrict__ h1part, const float* __restrict__ bm1,
    const ushort* __restrict__ wbf2t, const float* __restrict__ bm2,
    const ushort* __restrict__ wbf3t, const float* __restrict__ bm3,
    const ushort* __restrict__ wptbf, const float* __restrict__ bp,
    float* __restrict__ out)
{
  __shared__ SMem sm;
  tail_body(sm, blockIdx.x, threadIdx.x, h1part, bm1, wbf2t, bm2, wbf3t, bm3,
            wptbf, bp, out);
}

// ---------------------------------------------------------------------------
extern "C" void kernel_launch(void* const* d_in, const int* in_sizes, int n_in,
                              void* d_out, int out_size, void* d_ws, size_t ws_size,
                              hipStream_t stream)
{
  const float* x   = (const float*)d_in[0];
  const int*   ei  = (const int*)d_in[1];
  const float* w1  = (const float*)d_in[2];
  const float* b1  = (const float*)d_in[3];
  const float* w2  = (const float*)d_in[4];
  const float* b2  = (const float*)d_in[5];
  const float* c2w = (const float*)d_in[6];
  const float* c2b = (const float*)d_in[7];
  const float* c3w = (const float*)d_in[8];
  const float* c3b = (const float*)d_in[9];
  const float* g1  = (const float*)d_in[10];
  const float* be1 = (const float*)d_in[11];
  const float* g2  = (const float*)d_in[12];
  const float* be2 = (const float*)d_in[13];
  const float* g3  = (const float*)d_in[14];
  const float* be3 = (const float*)d_in[15];
  const float* wm1 = (const float*)d_in[16];
  const float* bm1 = (const float*)d_in[17];
  const float* wm2 = (const float*)d_in[18];
  const float* bm2 = (const float*)d_in[19];
  const float* wm3 = (const float*)d_in[20];
  const float* bm3 = (const float*)d_in[21];
  const float* wp  = (const float*)d_in[22];
  const float* bp  = (const float*)d_in[23];

  char* ws = (char*)d_ws;
  ushort* ubuf0 = (ushort*)ws;                          // 8 MiB: out0 -> z3 (bf16)
  ushort* ubuf1 = (ushort*)(ws + ((size_t)8 << 20));    // 8 MiB: z2 (bf16)
  float*  h1part = (float*)(ws + ((size_t)16 << 20));   // 8 MiB fp32 partials
  ushort* wbf1t = (ushort*)(ws + ((size_t)24 << 20));   // 2 MiB bf16 wm1^T
  ushort* wbf2t = (ushort*)(ws + ((size_t)26 << 20));               // 128 KiB
  ushort* wbf3t = (ushort*)(ws + ((size_t)26 << 20) + (128 << 10)); // 128 KiB
  ushort* wptbf = (ushort*)(ws + ((size_t)26 << 20) + (256 << 10)); // 8 KiB
  float* stats = (float*)(ws + ((size_t)27 << 20));     // 48 KiB [3][REP][128]
  float* stats1 = stats;
  float* stats2 = stats + REP * 128;
  float* stats3 = stats + 2 * REP * 128;
  unsigned* bar = (unsigned*)(ws + ((size_t)27 << 20) + 49152); // 33 KiB barriers
  ushort* cwt2 = (ushort*)d_out;          // d_out scratch, overwritten at tail
  ushort* cwt3 = (ushort*)d_out + 12288;
  float* outp = (float*)d_out;

  // Size the persistent grid once: guaranteed-co-resident block count.
  static int nblk_cached = -1;
  if (nblk_cached < 0) {
    int ncu = 0, maxb = 0;
    hipError_t e1 = hipDeviceGetAttribute(&ncu, hipDeviceAttributeMultiprocessorCount, 0);
    hipError_t e2 = hipOccupancyMaxActiveBlocksPerMultiprocessor(&maxb, k_all, 256, 0);
    if (e1 == hipSuccess && e2 == hipSuccess && ncu > 0 && maxb > 0) {
      long t = (long)ncu * (long)maxb;
      nblk_cached = (int)(t < MAXGRID ? t : MAXGRID);
    } else {
      nblk_cached = 0;   // occupancy unknown -> verified multi-kernel chain
    }
  }
  const int nblk = nblk_cached;

  if (nblk > 0) {
    // zero stats (48 KiB) + barrier counters (33 KiB); replayed with the graph
    hipMemsetAsync(stats, 0, 49152 + NPHASE * 33 * BARSLOT * 4, stream);
    k_all<<<dim3(nblk), dim3(256), 0, stream>>>(
        x, ei, w1, b1, w2, b2, c2w, c2b, c3w, c3b,
        g1, be1, g2, be2, g3, be3,
        wm1, bm1, wm2, bm2, wm3, bm3, wp, bp,
        ubuf0, ubuf1, h1part, wbf1t, wbf2t, wbf3t, wptbf,
        cwt2, cwt3, stats, bar, outp, nblk);
  } else {
    k_prepw<<<dim3(418), dim3(256), 0, stream>>>(
        wm1, wm2, wm3, wp, c2w, c3w,
        wbf1t, wbf2t, wbf3t, wptbf, cwt2, cwt3, stats);
    k_edge<<<dim3(NB), dim3(256), 0, stream>>>(x, ei, w1, b1, w2, b2, ubuf0, stats1);
    k_convm<<<dim3(NB), dim3(256), 0, stream>>>(ubuf0, stats1, g1, be1, cwt2, c2b, ubuf1, stats2);
    k_convm<<<dim3(NB), dim3(256), 0, stream>>>(ubuf1, stats2, g2, be2, cwt3, c3b, ubuf0, stats3);
    k_mlp1f<<<dim3(NB), dim3(256), 0, stream>>>(ubuf0, stats3, g3, be3, wbf1t, h1part);
    k_tailf<<<dim3(64), dim3(256), 0, stream>>>(h1part, bm1, wbf2t, bm2, wbf3t, bm3,
                                                wptbf, bp, outp);
  }
}

// Round 3
// 266.813 us; speedup vs baseline: 1.2693x; 1.2693x over previous
//
#include <hip/hip_runtime.h>
#include <cstdint>
#include <cstddef>

typedef __attribute__((ext_vector_type(8))) short short8;
typedef __attribute__((ext_vector_type(8))) unsigned short ushort8;
typedef __attribute__((ext_vector_type(4))) float f32x4;

#define EPSV 1e-5f
#define NB 1024
#define NEDGE 1048576
#define EPG 1024
#define CNTF 65536.0f
#define REP 32           // stats replica slots (contention spreading)
#define MAXGRID 1024     // never launch more than this (work max = 1441 items phase0)
#define BARSLOT 64       // u32 per barrier slot (256 B -> no line sharing)
#define NPHASE 4

__device__ __forceinline__ ushort f2bf(float f) {
  uint u = __float_as_uint(f);
  return (ushort)((u + 0x7FFFu + ((u >> 16) & 1u)) >> 16);
}
__device__ __forceinline__ float bf2f(ushort u) {
  return __uint_as_float((uint)u << 16);
}

// ---------------------------------------------------------------------------
// LDS union: per-phase layouts overlap. Max member = conv (36,384 B) -> with
// __launch_bounds__(256,4) (VGPR<=128) 4 blocks/CU fit (145.5 KB LDS/CU).
// ---------------------------------------------------------------------------
union __align__(16) SMem {
  struct { ushort T[64][72]; } prep;                                 //  9,216 B
  struct { float xs[64]; float aggT[4][5][72]; float aggC[64][8];
           float w1s[8], b1s[4], w2s[256], b2s[64];
           float rs[4][64], rss[4][64]; } edge;                      // ~11,424 B
  struct { ushort As[64][200]; ushort Yt[66][72];
           float aco[64], bco[64], cbs[64], ldsS[64], ldsSS[64]; } conv; // 36,384 B
  struct { ushort Ys[32][72]; ushort Ws[64][72];
           float a3s[64], b3s[64]; } mlp;                            // 14,336 B
  struct { ushort h1s[16][264]; ushort h2s[16][264]; } tail;         // 16,896 B
};

// ---------------------------------------------------------------------------
// Software grid barrier, cache-op-minimal version.
//
// Round-2 post-mortem: the ACQUIRE agent-scope load in the spin loop emitted
// a cache invalidate (buffer_inv sc1 -> XCD L2) on EVERY poll; 1024 pollers
// at barrier N+1 continuously nuked the L2s for blocks still in phase N ->
// every phase load at IF/HBM latency -> 402 us with all pipes <3% busy.
//
// New protocol (exactly 2 cache ops per block per barrier):
//   arrive:  fence(release, agent)   -- one L2 writeback; publishes the whole
//            block's stores (pre-barrier __syncthreads drained vmcnt first)
//            then RELAXED leaf/root fetch_adds (agent RMWs execute at the
//            coherence point regardless of ordering -> remotely visible).
//   spin:    RELAXED agent atomic load -- coherent/bypassing (observes the
//            root update; cannot deadlock) but NO invalidate per poll.
//   exit:    fence(acquire, agent)   -- one invalidate, right before
//            consuming other blocks' data.
// Stale (non-zero) counters (e.g. replay without memset) fall through
// (>= promote, < exit check); they can never deadlock.
// ---------------------------------------------------------------------------
__device__ __forceinline__ void gbar(unsigned* bar, int phase, int bid,
                                     int nblk, int tid)
{
  __syncthreads();
  if (tid == 0) {
    const int lf = bid & 31;
    unsigned* leaf = bar + (size_t)(phase * 33 + lf) * BARSLOT;
    unsigned* root = bar + (size_t)(phase * 33 + 32) * BARSLOT;
    const unsigned leafcnt = (unsigned)((nblk + 31 - lf) >> 5); // blocks on this leaf
    const unsigned nleaf = (unsigned)(nblk < 32 ? nblk : 32);
    __builtin_amdgcn_fence(__ATOMIC_RELEASE, "agent");   // wb L2 once
    unsigned old = __hip_atomic_fetch_add(leaf, 1u, __ATOMIC_RELAXED,
                                          __HIP_MEMORY_SCOPE_AGENT);
    if (old >= leafcnt - 1)
      __hip_atomic_fetch_add(root, 1u, __ATOMIC_RELAXED,
                             __HIP_MEMORY_SCOPE_AGENT);
    while (__hip_atomic_load(root, __ATOMIC_RELAXED,
                             __HIP_MEMORY_SCOPE_AGENT) < nleaf)
      __builtin_amdgcn_s_sleep(8);
    __builtin_amdgcn_fence(__ATOMIC_ACQUIRE, "agent");   // inv once
  }
  __syncthreads();
}

// ---------------------------------------------------------------------------
// phase 0a: weight preprocessing (items 0..416), identical math to the
// verified k_prepw minus the stats zeroing (done by hipMemsetAsync).
// ---------------------------------------------------------------------------
__device__ __forceinline__ void prep_body(
    SMem& sm, const int bb, const int tid,
    const float* __restrict__ wm1, const float* __restrict__ wm2,
    const float* __restrict__ wm3, const float* __restrict__ wp,
    const float* __restrict__ c2w, const float* __restrict__ c3w,
    ushort* __restrict__ wbf1t, ushort* __restrict__ wbf2t,
    ushort* __restrict__ wbf3t, ushort* __restrict__ wptbf,
    ushort* __restrict__ cwt2, ushort* __restrict__ cwt3)
{
  if (bb < 256) {
    auto& T = sm.prep.T;
    const int kc = bb >> 2, n0 = (bb & 3) << 6;
    const int kk = tid >> 2, np = (tid & 3) << 4;
    const float* srow = wm1 + (((size_t)(kk << 6) + kc) << 8) + n0 + np;
#pragma unroll
    for (int i = 0; i < 4; ++i) {
      const float4 v = *(const float4*)(srow + (i << 2));
      const int n = np + (i << 2);
      T[n + 0][kk] = f2bf(v.x); T[n + 1][kk] = f2bf(v.y);
      T[n + 2][kk] = f2bf(v.z); T[n + 3][kk] = f2bf(v.w);
    }
    __syncthreads();
    ushort* dst = wbf1t + ((size_t)kc << 14) + (n0 << 6);
    const int nl = tid >> 2, qk = (tid & 3) << 4;
    *(ushort8*)(dst + (nl << 6) + qk) = *(ushort8*)&T[nl][qk];
    *(ushort8*)(dst + (nl << 6) + qk + 8) = *(ushort8*)&T[nl][qk + 8];
    return;
  }
  if (bb < 320) {
    const int base = (((bb - 256) << 8) + tid) << 3;
    const int m = base >> 16;
    const int rem = base & 65535;
    const int kc = rem >> 14, within = rem & 16383;
    const int n = within >> 6, kk0 = within & 63;
    const float* src = m ? wm3 : wm2;
    ushort* dst = m ? wbf3t : wbf2t;
    ushort tmp[8];
#pragma unroll
    for (int j = 0; j < 8; ++j)
      tmp[j] = f2bf(src[(((kc << 6) | (kk0 + j)) << 8) + n]);
    *(ushort8*)&dst[rem] = *(ushort8*)&tmp[0];
    return;
  }
  if (bb == 320) {
    const int a = tid & 15, k0 = (tid >> 4) << 4;
    ushort tmp[16];
#pragma unroll
    for (int j = 0; j < 16; ++j) tmp[j] = f2bf(wp[((k0 + j) << 4) + a]);
    *(ushort8*)&wptbf[(a << 8) + k0] = *(ushort8*)&tmp[0];
    *(ushort8*)&wptbf[(a << 8) + k0 + 8] = *(ushort8*)&tmp[8];
    return;
  }
  // items 321..416: conv weights [o][c][kk] -> bf16 [o][kk*64+c]
  const int flat = (bb - 321) * 256 + tid;   // 0..24575
  const int m = flat >= 12288;
  const int idx = flat - (m ? 12288 : 0);
  const float* src = m ? c3w : c2w;
  ushort* dst = m ? cwt3 : cwt2;
  const int o = idx / 192, rem = idx - o * 192;
  const int kk = rem >> 6, cc = rem & 63;
  dst[idx] = f2bf(src[o * 192 + cc * 3 + kk]);
}

// ---------------------------------------------------------------------------
// phase 0b: EdgeConv for graph b (verified k_edge body).
// ---------------------------------------------------------------------------
__device__ __forceinline__ void edge_body(
    SMem& sm, const int b, const int tid,
    const float* __restrict__ x, const int* __restrict__ ei,
    const float* __restrict__ w1, const float* __restrict__ b1,
    const float* __restrict__ w2, const float* __restrict__ b2,
    ushort* __restrict__ out0, float* __restrict__ stats1)
{
  auto& E = sm.edge;
  const int w = tid >> 6;
  __syncthreads();                       // protect LDS union vs prior phase
  if (tid < 8) E.w1s[tid] = w1[tid];
  if (tid < 4) E.b1s[tid] = b1[tid];
  if (tid < 64) { E.xs[tid] = x[(b << 6) + tid]; E.b2s[tid] = b2[tid]; }
  E.w2s[tid] = w2[tid];
  for (int i = tid; i < 1440; i += 256) (&E.aggT[0][0][0])[i] = 0.f;
  __syncthreads();

  const int e0 = b * EPG;
  const int4 s4 = ((const int4*)(ei + e0))[tid];
  const int4 d4 = ((const int4*)(ei + NEDGE + e0))[tid];
  float* agw = &E.aggT[w][0][0];
  const int sls[4] = {s4.x & 63, s4.y & 63, s4.z & 63, s4.w & 63};
  const int dls[4] = {d4.x & 63, d4.y & 63, d4.z & 63, d4.w & 63};
#pragma unroll
  for (int e = 0; e < 4; ++e) {
    const int dl = dls[e];
    const float xi = E.xs[dl];
    const float dx = E.xs[sls[e]] - xi;
#pragma unroll
    for (int j = 0; j < 4; ++j) {
      float h = fmaxf(fmaf(xi, E.w1s[j], fmaf(dx, E.w1s[4 + j], E.b1s[j])), 0.f);
      atomicAdd(&agw[j * 72 + dl], h);
    }
    atomicAdd(&agw[4 * 72 + dl], 1.0f);
  }
  __syncthreads();

  if (tid < 64) {
    const int n = tid;
    const float a0 = E.aggT[0][0][n] + E.aggT[1][0][n] + E.aggT[2][0][n] + E.aggT[3][0][n];
    const float a1 = E.aggT[0][1][n] + E.aggT[1][1][n] + E.aggT[2][1][n] + E.aggT[3][1][n];
    const float a2 = E.aggT[0][2][n] + E.aggT[1][2][n] + E.aggT[2][2][n] + E.aggT[3][2][n];
    const float a3v = E.aggT[0][3][n] + E.aggT[1][3][n] + E.aggT[2][3][n] + E.aggT[3][3][n];
    const float dg = E.aggT[0][4][n] + E.aggT[1][4][n] + E.aggT[2][4][n] + E.aggT[3][4][n];
    *(float4*)&E.aggC[n][0] = make_float4(a0, a1, a2, a3v);
    E.aggC[n][4] = dg;
  }
  __syncthreads();

  const int c = tid & 63, qq = tid >> 6;
  const float wc0 = E.w2s[c], wc1 = E.w2s[64 + c], wc2 = E.w2s[128 + c], wc3 = E.w2s[192 + c];
  const float b2c = E.b2s[c];
  float s = 0.f, ss = 0.f;
  for (int n = qq; n < 64; n += 4) {
    const float4 a = *(const float4*)&E.aggC[n][0];
    const float dg = E.aggC[n][4];
    float v = a.x * wc0 + a.y * wc1 + a.z * wc2 + a.w * wc3 + dg * b2c;
    out0[(size_t)(((b << 6) + n) << 6) + c] = f2bf(v);
    s += v; ss += v * v;
  }
  E.rs[qq][c] = s; E.rss[qq][c] = ss;
  __syncthreads();
  if (tid < 64) {
    float* dst = stats1 + ((b & (REP - 1)) << 7);
    atomicAdd(&dst[tid], E.rs[0][tid] + E.rs[1][tid] + E.rs[2][tid] + E.rs[3][tid]);
    atomicAdd(&dst[64 + tid], E.rss[0][tid] + E.rss[1][tid] + E.rss[2][tid] + E.rss[3][tid]);
  }
}

// ---------------------------------------------------------------------------
// phases 1/2: BN + conv1d-as-MFMA for graph b (verified k_convm body).
// ---------------------------------------------------------------------------
__device__ __forceinline__ void conv_body(
    SMem& sm, const int b, const int tid,
    const ushort* __restrict__ in, const float* __restrict__ stats_in,
    const float* __restrict__ gamma, const float* __restrict__ beta,
    const ushort* __restrict__ cwt, const float* __restrict__ cb,
    ushort* __restrict__ out, float* __restrict__ stats_out)
{
  auto& C = sm.conv;
  __syncthreads();                       // protect LDS union vs prior phase
  if (tid < 64) {
    float smv = 0.f, sq = 0.f;
#pragma unroll 8
    for (int r = 0; r < REP; ++r) {
      smv += stats_in[(r << 7) + tid];
      sq += stats_in[(r << 7) + 64 + tid];
    }
    const float mean = smv * (1.0f / CNTF);
    const float var = sq * (1.0f / CNTF) - mean * mean;
    const float a = gamma[tid] * rsqrtf(var + EPSV);
    C.aco[tid] = a;
    C.bco[tid] = beta[tid] - mean * a;
    C.cbs[tid] = cb[tid];
    C.Yt[0][tid] = 0;
    C.Yt[65][tid] = 0;
  }
  __syncthreads();

  const size_t base = (size_t)b << 12;
  {
    const int lr = tid >> 2, p = (tid & 3) << 4;
    const ushort8 r0 = *(const ushort8*)&in[base + (lr << 6) + p];
    const ushort8 r1 = *(const ushort8*)&in[base + (lr << 6) + p + 8];
    ushort tmp[16];
#pragma unroll
    for (int j = 0; j < 8; ++j)
      tmp[j] = f2bf(fmaxf(fmaf(C.aco[p + j], bf2f(r0[j]), C.bco[p + j]), 0.f));
#pragma unroll
    for (int j = 0; j < 8; ++j)
      tmp[8 + j] = f2bf(fmaxf(fmaf(C.aco[p + 8 + j], bf2f(r1[j]), C.bco[p + 8 + j]), 0.f));
    *(ushort8*)&C.Yt[lr + 1][p] = *(ushort8*)&tmp[0];
    *(ushort8*)&C.Yt[lr + 1][p + 8] = *(ushort8*)&tmp[8];
  }
  {
    const ushort8* gw = (const ushort8*)cwt;
#pragma unroll
    for (int i = 0; i < 6; ++i) {
      const int e8 = (i << 8) + tid;
      const int o = e8 / 24, k8 = (e8 - o * 24) << 3;
      *(ushort8*)&C.As[o][k8] = gw[e8];
    }
  }
  __syncthreads();

  const int lane = tid & 63, w = tid >> 6;
  const int lm = lane & 15, q = lane >> 4;
  f32x4 acc[4];
#pragma unroll
  for (int nt = 0; nt < 4; ++nt) acc[nt] = (f32x4){0.f, 0.f, 0.f, 0.f};

#pragma unroll
  for (int kk = 0; kk < 3; ++kk) {
#pragma unroll
    for (int ks = 0; ks < 2; ++ks) {
      const short8 af = *(const short8*)&C.As[(w << 4) + lm][(kk << 6) + (ks << 5) + (q << 3)];
#pragma unroll
      for (int nt = 0; nt < 4; ++nt) {
        const short8 bfr = *(const short8*)&C.Yt[(nt << 4) + lm + kk][(ks << 5) + (q << 3)];
        acc[nt] = __builtin_amdgcn_mfma_f32_16x16x32_bf16(af, bfr, acc[nt], 0, 0, 0);
      }
    }
  }

  const int obase = (w << 4) + (q << 2);
  const float4 cb4 = *(const float4*)&C.cbs[obase];
  float s[4] = {0.f, 0.f, 0.f, 0.f}, ss[4] = {0.f, 0.f, 0.f, 0.f};
#pragma unroll
  for (int nt = 0; nt < 4; ++nt) {
    const int l = (nt << 4) + lm;
    float4 v = make_float4(acc[nt][0] + cb4.x, acc[nt][1] + cb4.y,
                           acc[nt][2] + cb4.z, acc[nt][3] + cb4.w);
    *(ushort4*)&out[base + (l << 6) + obase] =
        make_ushort4(f2bf(v.x), f2bf(v.y), f2bf(v.z), f2bf(v.w));
    s[0] += v.x; ss[0] += v.x * v.x;
    s[1] += v.y; ss[1] += v.y * v.y;
    s[2] += v.z; ss[2] += v.z * v.z;
    s[3] += v.w; ss[3] += v.w * v.w;
  }
#pragma unroll
  for (int i = 0; i < 4; ++i) {
#pragma unroll
    for (int off = 1; off < 16; off <<= 1) {
      s[i] += __shfl_xor(s[i], off);
      ss[i] += __shfl_xor(ss[i], off);
    }
    if (lm == 0) { C.ldsS[obase + i] = s[i]; C.ldsSS[obase + i] = ss[i]; }
  }
  __syncthreads();
  if (tid < 64) {
    float* dst = stats_out + ((b & (REP - 1)) << 7);
    atomicAdd(&dst[tid], C.ldsS[tid]);
    atomicAdd(&dst[64 + tid], C.ldsSS[tid]);
  }
}

// ---------------------------------------------------------------------------
// phase 3: mlp1 tiled as 1024 items: 32 M-tiles (32 graphs) x 4 N-tiles (64)
// x 8 K-splits. Same K order / fp32 partial layout as the verified k_mlp1.
// ---------------------------------------------------------------------------
__device__ __forceinline__ void mlp_body(
    SMem& sm, const int bid, const int tid,
    const ushort* __restrict__ z3, const float* __restrict__ stats3,
    const float* __restrict__ g3, const float* __restrict__ be3,
    const ushort* __restrict__ wbf1t, float* __restrict__ h1part)
{
  auto& M = sm.mlp;
  const int bz = bid >> 7;          // 0..7  K-split
  const int bx = (bid >> 2) & 31;   // 0..31 M-tile (32 graphs)
  const int by = bid & 3;           // 0..3  N-tile (64)
  __syncthreads();                  // protect LDS union vs prior phase
  if (tid < 64) {
    float sme = 0.f, sq = 0.f;
#pragma unroll 8
    for (int r = 0; r < REP; ++r) {
      sme += stats3[(r << 7) + tid];
      sq += stats3[(r << 7) + 64 + tid];
    }
    const float mean = sme * (1.0f / CNTF);
    const float var = sq * (1.0f / CNTF) - mean * mean;
    const float a = g3[tid] * rsqrtf(var + EPSV);
    M.a3s[tid] = a;
    M.b3s[tid] = be3[tid] - mean * a;
  }
  __syncthreads();

  const int lane = tid & 63, w = tid >> 6;
  const int lm = lane & 15, q = lane >> 4;
  const int wr = w >> 1, wc = w & 1;            // wave -> (M half, N half)
  const int gy = tid >> 3, py = (tid & 7) << 3; // Ys staging: 32 rows x 8
  const int nn = tid >> 2, pw = tid & 3;        // Ws staging: 64 rows x 16
  const int g0 = bx << 5, n0 = by << 6;

  f32x4 acc[2];
#pragma unroll
  for (int nt = 0; nt < 2; ++nt) acc[nt] = (f32x4){0.f, 0.f, 0.f, 0.f};

  const size_t ybase = ((size_t)(g0 + gy) << 12);

#pragma unroll 1
  for (int ck = 0; ck < 8; ++ck) {
    const int kc = (bz << 9) + (ck << 6);
    if (ck) __syncthreads();
    // --- stage Ys: BN3+ReLU on bf16 z3 (channel = within-chunk index)
    {
      const ushort8 r0 = *(const ushort8*)(z3 + ybase + kc + py);
      ushort tmp[8];
#pragma unroll
      for (int j = 0; j < 8; ++j)
        tmp[j] = f2bf(fmaxf(fmaf(M.a3s[py + j], bf2f(r0[j]), M.b3s[py + j]), 0.f));
      *(ushort8*)&M.Ys[gy][py] = *(ushort8*)&tmp[0];
    }
    // --- stage Ws: straight copies from chunk-major wbf1t
    {
      const ushort8* gw = (const ushort8*)(wbf1t + ((size_t)((bz << 3) + ck) << 14) + ((size_t)n0 << 6));
      *(ushort8*)&M.Ws[nn][pw << 4] = gw[(nn << 3) + (pw << 1)];
      *(ushort8*)&M.Ws[nn][(pw << 4) + 8] = gw[(nn << 3) + (pw << 1) + 1];
    }
    __syncthreads();
#pragma unroll
    for (int ks = 0; ks < 2; ++ks) {
      const short8 af = *(const short8*)&M.Ys[(wr << 4) + lm][(ks << 5) + (q << 3)];
#pragma unroll
      for (int nt = 0; nt < 2; ++nt) {
        const short8 bfr = *(const short8*)&M.Ws[(wc << 5) + (nt << 4) + lm][(ks << 5) + (q << 3)];
        acc[nt] = __builtin_amdgcn_mfma_f32_16x16x32_bf16(af, bfr, acc[nt], 0, 0, 0);
      }
    }
  }

  float* dst0 = h1part + ((size_t)bz << 18);
  const int gout = g0 + (wr << 4) + (q << 2);
#pragma unroll
  for (int nt = 0; nt < 2; ++nt) {
    const int col = n0 + (wc << 5) + (nt << 4) + lm;
#pragma unroll
    for (int i = 0; i < 4; ++i)
      dst0[((size_t)(gout + i) << 8) + col] = acc[nt][i];
  }
}

// ---------------------------------------------------------------------------
// phase 4: tail (items 0..63, 16 graphs each). GEMM2/GEMM3/logits read the
// B-operand directly from L2-hot global (no Ws LDS -> union stays small).
// ---------------------------------------------------------------------------
__device__ __forceinline__ void tail_body(
    SMem& sm, const int bid, const int tid,
    const float* __restrict__ h1part, const float* __restrict__ bm1,
    const ushort* __restrict__ wbf2t, const float* __restrict__ bm2,
    const ushort* __restrict__ wbf3t, const float* __restrict__ bm3,
    const ushort* __restrict__ wptbf, const float* __restrict__ bp,
    float* __restrict__ out)
{
  auto& T = sm.tail;
  const int g0 = bid << 4;
  const int lane = tid & 63, w = tid >> 6;
  const int lm = lane & 15, q = lane >> 4;
  const int gr = q << 2;

  __syncthreads();                  // protect LDS union vs prior phase
  {
    const int r = tid >> 4, c0 = (tid & 15) << 4;
    const float* srcb = h1part + ((size_t)(g0 + r) << 8) + c0;
#pragma unroll
    for (int i = 0; i < 4; ++i) {
      float4 vs = *(const float4*)(bm1 + c0 + (i << 2));
#pragma unroll
      for (int bz = 0; bz < 8; ++bz) {
        const float4 p = *(const float4*)(srcb + ((size_t)bz << 18) + (i << 2));
        vs.x += p.x; vs.y += p.y; vs.z += p.z; vs.w += p.w;
      }
      *(ushort4*)&T.h1s[r][c0 + (i << 2)] = make_ushort4(
          f2bf(fmaxf(vs.x, 0.f)), f2bf(fmaxf(vs.y, 0.f)),
          f2bf(fmaxf(vs.z, 0.f)), f2bf(fmaxf(vs.w, 0.f)));
    }
  }
  __syncthreads();

  // ---- GEMM2 (B direct from global)
  f32x4 acc[4];
#pragma unroll
  for (int nt = 0; nt < 4; ++nt) acc[nt] = (f32x4){0.f, 0.f, 0.f, 0.f};
#pragma unroll
  for (int ck = 0; ck < 4; ++ck) {
#pragma unroll
    for (int ks = 0; ks < 2; ++ks) {
      const short8 af = *(const short8*)&T.h1s[lm][(ck << 6) + (ks << 5) + (q << 3)];
#pragma unroll
      for (int nt = 0; nt < 4; ++nt) {
        const int n = (w << 6) + (nt << 4) + lm;
        const short8 bfr = *(const short8*)&wbf2t[((size_t)ck << 14) + (n << 6) + (ks << 5) + (q << 3)];
        acc[nt] = __builtin_amdgcn_mfma_f32_16x16x32_bf16(af, bfr, acc[nt], 0, 0, 0);
      }
    }
  }
#pragma unroll
  for (int nt = 0; nt < 4; ++nt) {
    const int col = (w << 6) + (nt << 4) + lm;
    const float bv = bm2[col];
#pragma unroll
    for (int i = 0; i < 4; ++i)
      T.h2s[gr + i][col] = f2bf(fmaxf(acc[nt][i] + bv, 0.f));
  }
  __syncthreads();

  // ---- GEMM3 (B direct from global)
  f32x4 acc2[4];
#pragma unroll
  for (int nt = 0; nt < 4; ++nt) acc2[nt] = (f32x4){0.f, 0.f, 0.f, 0.f};
#pragma unroll
  for (int ck = 0; ck < 4; ++ck) {
#pragma unroll
    for (int ks = 0; ks < 2; ++ks) {
      const short8 af = *(const short8*)&T.h2s[lm][(ck << 6) + (ks << 5) + (q << 3)];
#pragma unroll
      for (int nt = 0; nt < 4; ++nt) {
        const int n = (w << 6) + (nt << 4) + lm;
        const short8 bfr = *(const short8*)&wbf3t[((size_t)ck << 14) + (n << 6) + (ks << 5) + (q << 3)];
        acc2[nt] = __builtin_amdgcn_mfma_f32_16x16x32_bf16(af, bfr, acc2[nt], 0, 0, 0);
      }
    }
  }
  __syncthreads();                  // all h2s reads done before overwrite
#pragma unroll
  for (int nt = 0; nt < 4; ++nt) {
    const int col = (w << 6) + (nt << 4) + lm;
    const float bv = bm3[col];
#pragma unroll
    for (int i = 0; i < 4; ++i)
      T.h2s[gr + i][col] = f2bf(fmaxf(acc2[nt][i] + bv, 0.f));
  }
  __syncthreads();

  if (w == 0) {
    f32x4 lacc = (f32x4){0.f, 0.f, 0.f, 0.f};
#pragma unroll
    for (int ks = 0; ks < 8; ++ks) {
      const short8 af = *(const short8*)&T.h2s[lm][(ks << 5) + (q << 3)];
      const short8 bfr = *(const short8*)&wptbf[(lm << 8) + (ks << 5) + (q << 3)];
      lacc = __builtin_amdgcn_mfma_f32_16x16x32_bf16(af, bfr, lacc, 0, 0, 0);
    }
    const float bpv = bp[lm];
    float lg[4], mx[4], se[4];
#pragma unroll
    for (int i = 0; i < 4; ++i) {
      lg[i] = lacc[i] + bpv;
      float m = lg[i];
#pragma unroll
      for (int off = 1; off < 16; off <<= 1) m = fmaxf(m, __shfl_xor(m, off));
      mx[i] = m;
      float e = expf(lg[i] - m);
#pragma unroll
      for (int off = 1; off < 16; off <<= 1) e += __shfl_xor(e, off);
      se[i] = e;
    }
#pragma unroll
    for (int i = 0; i < 4; ++i)
      out[((g0 + gr + i) << 4) + lm] = (lg[i] - mx[i]) - logf(se[i]);
  }
}

// ---------------------------------------------------------------------------
// Fused persistent kernel: all 5 stages, 4 software grid barriers (3 BN
// batch-stat reductions + the h1part split-K reduction). Plain launch
// (capture-safe); grid sized by host occupancy query so every block is
// co-resident; persistent loops handle any nblk.
// ---------------------------------------------------------------------------
__global__ __launch_bounds__(256, 4) void k_all(
    const float* __restrict__ x, const int* __restrict__ ei,
    const float* __restrict__ w1, const float* __restrict__ b1,
    const float* __restrict__ w2, const float* __restrict__ b2,
    const float* __restrict__ c2w, const float* __restrict__ c2b,
    const float* __restrict__ c3w, const float* __restrict__ c3b,
    const float* __restrict__ g1, const float* __restrict__ be1,
    const float* __restrict__ g2, const float* __restrict__ be2,
    const float* __restrict__ g3, const float* __restrict__ be3,
    const float* __restrict__ wm1, const float* __restrict__ bm1,
    const float* __restrict__ wm2, const float* __restrict__ bm2,
    const float* __restrict__ wm3, const float* __restrict__ bm3,
    const float* __restrict__ wp, const float* __restrict__ bp,
    ushort* __restrict__ ubuf0, ushort* __restrict__ ubuf1,
    float* __restrict__ h1part,
    ushort* __restrict__ wbf1t, ushort* __restrict__ wbf2t,
    ushort* __restrict__ wbf3t, ushort* __restrict__ wptbf,
    ushort* __restrict__ cwt2, ushort* __restrict__ cwt3,
    float* __restrict__ stats, unsigned* __restrict__ bar,
    float* __restrict__ out, int nblk)
{
  __shared__ SMem sm;
  const int tid = threadIdx.x;
  const int bid = blockIdx.x;
  float* stats1 = stats;
  float* stats2 = stats + REP * 128;
  float* stats3 = stats + 2 * REP * 128;

  // phase 0: weight prep (items 0..416) + edge conv (items 417..1440)
  for (int it = bid; it < 417 + NB; it += nblk) {
    if (it < 417)
      prep_body(sm, it, tid, wm1, wm2, wm3, wp, c2w, c3w,
                wbf1t, wbf2t, wbf3t, wptbf, cwt2, cwt3);
    else
      edge_body(sm, it - 417, tid, x, ei, w1, b1, w2, b2, ubuf0, stats1);
  }
  gbar(bar, 0, bid, nblk, tid);
  // phase 1: BN1 + conv2
  for (int it = bid; it < NB; it += nblk)
    conv_body(sm, it, tid, ubuf0, stats1, g1, be1, cwt2, c2b, ubuf1, stats2);
  gbar(bar, 1, bid, nblk, tid);
  // phase 2: BN2 + conv3
  for (int it = bid; it < NB; it += nblk)
    conv_body(sm, it, tid, ubuf1, stats2, g2, be2, cwt3, c3b, ubuf0, stats3);
  gbar(bar, 2, bid, nblk, tid);
  // phase 3: BN3 + GEMM1 split-K partials
  for (int it = bid; it < NB; it += nblk)
    mlp_body(sm, it, tid, ubuf0, stats3, g3, be3, wbf1t, h1part);
  gbar(bar, 3, bid, nblk, tid);
  // phase 4: tail (items 0..63)
  for (int it = bid; it < 64; it += nblk)
    tail_body(sm, it, tid, h1part, bm1, wbf2t, bm2, wbf3t, bm3, wptbf, bp, out);
}

// ===========================================================================
// Fallback path: the previous verified 6-kernel chain (host-side if only;
// used if the occupancy query fails).
// ===========================================================================
__global__ __launch_bounds__(256) void k_prepw(
    const float* __restrict__ wm1, const float* __restrict__ wm2,
    const float* __restrict__ wm3, const float* __restrict__ wp,
    const float* __restrict__ c2w, const float* __restrict__ c3w,
    ushort* __restrict__ wbf1t, ushort* __restrict__ wbf2t,
    ushort* __restrict__ wbf3t, ushort* __restrict__ wptbf,
    ushort* __restrict__ cwt2, ushort* __restrict__ cwt3,
    float* __restrict__ stats)
{
  __shared__ SMem sm;
  const int tid = threadIdx.x;
  const int bb = blockIdx.x;
  if (bb == 417) {
    float4 z4 = make_float4(0.f, 0.f, 0.f, 0.f);
#pragma unroll
    for (int i = 0; i < 12; ++i) ((float4*)stats)[(i << 8) + tid] = z4;
    return;
  }
  prep_body(sm, bb, tid, wm1, wm2, wm3, wp, c2w, c3w,
            wbf1t, wbf2t, wbf3t, wptbf, cwt2, cwt3);
}

__global__ __launch_bounds__(256) void k_edge(
    const float* __restrict__ x, const int* __restrict__ ei,
    const float* __restrict__ w1, const float* __restrict__ b1,
    const float* __restrict__ w2, const float* __restrict__ b2,
    ushort* __restrict__ out0, float* __restrict__ stats1)
{
  __shared__ SMem sm;
  edge_body(sm, blockIdx.x, threadIdx.x, x, ei, w1, b1, w2, b2, out0, stats1);
}

__global__ __launch_bounds__(256) void k_convm(
    const ushort* __restrict__ in, const float* __restrict__ stats_in,
    const float* __restrict__ gamma, const float* __restrict__ beta,
    const ushort* __restrict__ cwt, const float* __restrict__ cb,
    ushort* __restrict__ out, float* __restrict__ stats_out)
{
  __shared__ SMem sm;
  conv_body(sm, blockIdx.x, threadIdx.x, in, stats_in, gamma, beta, cwt, cb,
            out, stats_out);
}

__global__ __launch_bounds__(256) void k_mlp1f(
    const ushort* __restrict__ z3, const float* __restrict__ stats3,
    const float* __restrict__ g3, const float* __restrict__ be3,
    const ushort* __restrict__ wbf1t, float* __restrict__ h1part)
{
  __shared__ SMem sm;
  mlp_body(sm, blockIdx.x, threadIdx.x, z3, stats3, g3, be3, wbf1t, h1part);
}

__global__ __launch_bounds__(256) void k_tailf(
    const float* __restrict__ h1part, const float* __restrict__ bm1,
    const ushort* __restrict__ wbf2t, const float* __restrict__ bm2,
    const ushort* __restrict__ wbf3t, const float* __restrict__ bm3,
    const ushort* __restrict__ wptbf, const float* __restrict__ bp,
    float* __restrict__ out)
{
  __shared__ SMem sm;
  tail_body(sm, blockIdx.x, threadIdx.x, h1part, bm1, wbf2t, bm2, wbf3t, bm3,
            wptbf, bp, out);
}

// ---------------------------------------------------------------------------
extern "C" void kernel_launch(void* const* d_in, const int* in_sizes, int n_in,
                              void* d_out, int out_size, void* d_ws, size_t ws_size,
                              hipStream_t stream)
{
  const float* x   = (const float*)d_in[0];
  const int*   ei  = (const int*)d_in[1];
  const float* w1  = (const float*)d_in[2];
  const float* b1  = (const float*)d_in[3];
  const float* w2  = (const float*)d_in[4];
  const float* b2  = (const float*)d_in[5];
  const float* c2w = (const float*)d_in[6];
  const float* c2b = (const float*)d_in[7];
  const float* c3w = (const float*)d_in[8];
  const float* c3b = (const float*)d_in[9];
  const float* g1  = (const float*)d_in[10];
  const float* be1 = (const float*)d_in[11];
  const float* g2  = (const float*)d_in[12];
  const float* be2 = (const float*)d_in[13];
  const float* g3  = (const float*)d_in[14];
  const float* be3 = (const float*)d_in[15];
  const float* wm1 = (const float*)d_in[16];
  const float* bm1 = (const float*)d_in[17];
  const float* wm2 = (const float*)d_in[18];
  const float* bm2 = (const float*)d_in[19];
  const float* wm3 = (const float*)d_in[20];
  const float* bm3 = (const float*)d_in[21];
  const float* wp  = (const float*)d_in[22];
  const float* bp  = (const float*)d_in[23];

  char* ws = (char*)d_ws;
  ushort* ubuf0 = (ushort*)ws;                          // 8 MiB: out0 -> z3 (bf16)
  ushort* ubuf1 = (ushort*)(ws + ((size_t)8 << 20));    // 8 MiB: z2 (bf16)
  float*  h1part = (float*)(ws + ((size_t)16 << 20));   // 8 MiB fp32 partials
  ushort* wbf1t = (ushort*)(ws + ((size_t)24 << 20));   // 2 MiB bf16 wm1^T
  ushort* wbf2t = (ushort*)(ws + ((size_t)26 << 20));               // 128 KiB
  ushort* wbf3t = (ushort*)(ws + ((size_t)26 << 20) + (128 << 10)); // 128 KiB
  ushort* wptbf = (ushort*)(ws + ((size_t)26 << 20) + (256 << 10)); // 8 KiB
  float* stats = (float*)(ws + ((size_t)27 << 20));     // 48 KiB [3][REP][128]
  float* stats1 = stats;
  float* stats2 = stats + REP * 128;
  float* stats3 = stats + 2 * REP * 128;
  unsigned* bar = (unsigned*)(ws + ((size_t)27 << 20) + 49152); // 33 KiB barriers
  ushort* cwt2 = (ushort*)d_out;          // d_out scratch, overwritten at tail
  ushort* cwt3 = (ushort*)d_out + 12288;
  float* outp = (float*)d_out;

  // Size the persistent grid once: guaranteed-co-resident block count.
  static int nblk_cached = -1;
  if (nblk_cached < 0) {
    int ncu = 0, maxb = 0;
    hipError_t e1 = hipDeviceGetAttribute(&ncu, hipDeviceAttributeMultiprocessorCount, 0);
    hipError_t e2 = hipOccupancyMaxActiveBlocksPerMultiprocessor(&maxb, k_all, 256, 0);
    if (e1 == hipSuccess && e2 == hipSuccess && ncu > 0 && maxb > 0) {
      long t = (long)ncu * (long)maxb;
      nblk_cached = (int)(t < MAXGRID ? t : MAXGRID);
    } else {
      nblk_cached = 0;   // occupancy unknown -> verified multi-kernel chain
    }
  }
  const int nblk = nblk_cached;

  if (nblk > 0) {
    // zero stats (48 KiB) + barrier counters (33 KiB); replayed with the graph
    hipMemsetAsync(stats, 0, 49152 + NPHASE * 33 * BARSLOT * 4, stream);
    k_all<<<dim3(nblk), dim3(256), 0, stream>>>(
        x, ei, w1, b1, w2, b2, c2w, c2b, c3w, c3b,
        g1, be1, g2, be2, g3, be3,
        wm1, bm1, wm2, bm2, wm3, bm3, wp, bp,
        ubuf0, ubuf1, h1part, wbf1t, wbf2t, wbf3t, wptbf,
        cwt2, cwt3, stats, bar, outp, nblk);
  } else {
    k_prepw<<<dim3(418), dim3(256), 0, stream>>>(
        wm1, wm2, wm3, wp, c2w, c3w,
        wbf1t, wbf2t, wbf3t, wptbf, cwt2, cwt3, stats);
    k_edge<<<dim3(NB), dim3(256), 0, stream>>>(x, ei, w1, b1, w2, b2, ubuf0, stats1);
    k_convm<<<dim3(NB), dim3(256), 0, stream>>>(ubuf0, stats1, g1, be1, cwt2, c2b, ubuf1, stats2);
    k_convm<<<dim3(NB), dim3(256), 0, stream>>>(ubuf1, stats2, g2, be2, cwt3, c3b, ubuf0, stats3);
    k_mlp1f<<<dim3(NB), dim3(256), 0, stream>>>(ubuf0, stats3, g3, be3, wbf1t, h1part);
    k_tailf<<<dim3(64), dim3(256), 0, stream>>>(h1part, bm1, wbf2t, bm2, wbf3t, bm3,
                                                wptbf, bp, outp);
  }
}

// Round 4
// 221.011 us; speedup vs baseline: 1.5323x; 1.2072x over previous
//
#include <hip/hip_runtime.h>
#include <cstdint>
#include <cstddef>

typedef __attribute__((ext_vector_type(8))) short short8;
typedef __attribute__((ext_vector_type(8))) unsigned short ushort8;
typedef __attribute__((ext_vector_type(4))) float f32x4;
typedef __attribute__((ext_vector_type(2))) unsigned int uint2v;

#define EPSV 1e-5f
#define NB 1024
#define NEDGE 1048576
#define EPG 1024
#define CNTF 65536.0f
#define REP 32           // stats replica slots (contention spreading)
#define MAXGRID 1024
#define BARSLOT 64       // u32 per barrier slot (256 B -> no line sharing)
#define NPHASE 4

__device__ __forceinline__ ushort f2bf(float f) {
  uint u = __float_as_uint(f);
  return (ushort)((u + 0x7FFFu + ((u >> 16) & 1u)) >> 16);
}
__device__ __forceinline__ float bf2f(ushort u) {
  return __uint_as_float((uint)u << 16);
}

// ---------------------------------------------------------------------------
// L2-BYPASS STORES (sc0 sc1 = system-coherent, write-through past L1+L2 to
// IF/L3; no dirty L2 lines anywhere). Producers use these for ALL cross-phase
// data; consumers use normal cached loads (each buffer is first-touched by
// its consumer phase, so no stale line can exist in any L2) -> NO fences
// needed at barriers, L2s stay warm across phases.
// ---------------------------------------------------------------------------
__device__ __forceinline__ void st_b128_sys(void* p, ushort8 v) {
  asm volatile("global_store_dwordx4 %0, %1, off sc0 sc1" :: "v"(p), "v"(v) : "memory");
}
__device__ __forceinline__ void st_b64_sys(void* p, uint2v v) {
  asm volatile("global_store_dwordx2 %0, %1, off sc0 sc1" :: "v"(p), "v"(v) : "memory");
}
__device__ __forceinline__ void st_b32_sys(void* p, float v) {
  asm volatile("global_store_dword %0, %1, off sc0 sc1" :: "v"(p), "v"(v) : "memory");
}
__device__ __forceinline__ void st_b16_sys(void* p, ushort v) {
  unsigned d = v;
  asm volatile("global_store_short %0, %1, off sc0 sc1" :: "v"(p), "v"(d) : "memory");
}
__device__ __forceinline__ float ld_f32_coh(const float* p) {
  return __hip_atomic_load((float*)p, __ATOMIC_RELAXED, __HIP_MEMORY_SCOPE_AGENT);
}

// ---------------------------------------------------------------------------
// LDS union: max member = conv (36,384 B) -> with __launch_bounds__(256,4)
// 4 blocks/CU (145.5 KB LDS/CU), 1024 co-resident blocks.
// ---------------------------------------------------------------------------
union __align__(16) SMem {
  struct { ushort T[64][72]; } prep;                                 //  9,216 B
  struct { float xs[64]; float aggT[4][5][72]; float aggC[64][8];
           float w1s[8], b1s[4], w2s[256], b2s[64];
           float rs[4][64], rss[4][64]; } edge;                      // ~11,424 B
  struct { ushort As[64][200]; ushort Yt[66][72];
           float aco[64], bco[64], cbs[64], ldsS[64], ldsSS[64]; } conv; // 36,384 B
  struct { ushort Ys[32][72]; ushort Ws[64][72];
           float a3s[64], b3s[64]; } mlp;                            // 14,336 B
  struct { ushort h1s[16][264]; ushort h2s[16][264]; } tail;         // 16,896 B
};

// ---------------------------------------------------------------------------
// Software grid barrier, ZERO-cache-op version.
// R3 post-mortem: per-block release(wbl2)+acquire(inv) = 2048 L2 cache ops
// per barrier, spread in time -> each late block's inv re-nuked L2 while
// early blocks re-warmed it -> ~45us/phase. With producers writing through
// to IF (st_*_sys) and stats read at the coherence point, the barrier needs
// NO fences at all:
//   all threads: s_waitcnt vmcnt(0)  (drain own asm stores; compiler does
//                not track inline-asm VMEM) -> __syncthreads
//   tid0: relaxed leaf fetch_add -> (last) relaxed root fetch_add ->
//         relaxed spin on root (coherent load, no cache ops) -> done.
// Stale (non-zero) counters fall through (>= promote, < exit); no deadlock.
// ---------------------------------------------------------------------------
__device__ __forceinline__ void gbar(unsigned* bar, int phase, int bid,
                                     int nblk, int tid)
{
  asm volatile("s_waitcnt vmcnt(0)" ::: "memory");
  __syncthreads();
  if (tid == 0) {
    const int lf = bid & 31;
    unsigned* leaf = bar + (size_t)(phase * 33 + lf) * BARSLOT;
    unsigned* root = bar + (size_t)(phase * 33 + 32) * BARSLOT;
    const unsigned leafcnt = (unsigned)((nblk + 31 - lf) >> 5);
    const unsigned nleaf = (unsigned)(nblk < 32 ? nblk : 32);
    unsigned old = __hip_atomic_fetch_add(leaf, 1u, __ATOMIC_RELAXED,
                                          __HIP_MEMORY_SCOPE_AGENT);
    if (old >= leafcnt - 1)
      __hip_atomic_fetch_add(root, 1u, __ATOMIC_RELAXED,
                             __HIP_MEMORY_SCOPE_AGENT);
    while (__hip_atomic_load(root, __ATOMIC_RELAXED,
                             __HIP_MEMORY_SCOPE_AGENT) < nleaf)
      __builtin_amdgcn_s_sleep(8);
  }
  __syncthreads();
}

// ---------------------------------------------------------------------------
// phase 0a: weight preprocessing (items 0..416). All outputs via bypass
// stores (consumed in later phases by other XCDs).
// ---------------------------------------------------------------------------
__device__ __forceinline__ void prep_body(
    SMem& sm, const int bb, const int tid,
    const float* __restrict__ wm1, const float* __restrict__ wm2,
    const float* __restrict__ wm3, const float* __restrict__ wp,
    const float* __restrict__ c2w, const float* __restrict__ c3w,
    ushort* __restrict__ wbf1t, ushort* __restrict__ wbf2t,
    ushort* __restrict__ wbf3t, ushort* __restrict__ wptbf,
    ushort* __restrict__ cwt2, ushort* __restrict__ cwt3)
{
  if (bb < 256) {
    auto& T = sm.prep.T;
    const int kc = bb >> 2, n0 = (bb & 3) << 6;
    const int kk = tid >> 2, np = (tid & 3) << 4;
    const float* srow = wm1 + (((size_t)(kk << 6) + kc) << 8) + n0 + np;
#pragma unroll
    for (int i = 0; i < 4; ++i) {
      const float4 v = *(const float4*)(srow + (i << 2));
      const int n = np + (i << 2);
      T[n + 0][kk] = f2bf(v.x); T[n + 1][kk] = f2bf(v.y);
      T[n + 2][kk] = f2bf(v.z); T[n + 3][kk] = f2bf(v.w);
    }
    __syncthreads();
    ushort* dst = wbf1t + ((size_t)kc << 14) + (n0 << 6);
    const int nl = tid >> 2, qk = (tid & 3) << 4;
    st_b128_sys(dst + (nl << 6) + qk, *(ushort8*)&T[nl][qk]);
    st_b128_sys(dst + (nl << 6) + qk + 8, *(ushort8*)&T[nl][qk + 8]);
    return;
  }
  if (bb < 320) {
    const int base = (((bb - 256) << 8) + tid) << 3;
    const int m = base >> 16;
    const int rem = base & 65535;
    const int kc = rem >> 14, within = rem & 16383;
    const int n = within >> 6, kk0 = within & 63;
    const float* src = m ? wm3 : wm2;
    ushort* dst = m ? wbf3t : wbf2t;
    ushort tmp[8];
#pragma unroll
    for (int j = 0; j < 8; ++j)
      tmp[j] = f2bf(src[(((kc << 6) | (kk0 + j)) << 8) + n]);
    st_b128_sys(&dst[rem], *(ushort8*)&tmp[0]);
    return;
  }
  if (bb == 320) {
    const int a = tid & 15, k0 = (tid >> 4) << 4;
    ushort tmp[16];
#pragma unroll
    for (int j = 0; j < 16; ++j) tmp[j] = f2bf(wp[((k0 + j) << 4) + a]);
    st_b128_sys(&wptbf[(a << 8) + k0], *(ushort8*)&tmp[0]);
    st_b128_sys(&wptbf[(a << 8) + k0 + 8], *(ushort8*)&tmp[8]);
    return;
  }
  // items 321..416: conv weights [o][c][kk] -> bf16 [o][kk*64+c]
  const int flat = (bb - 321) * 256 + tid;   // 0..24575
  const int m = flat >= 12288;
  const int idx = flat - (m ? 12288 : 0);
  const float* src = m ? c3w : c2w;
  ushort* dst = m ? cwt3 : cwt2;
  const int o = idx / 192, rem = idx - o * 192;
  const int kk = rem >> 6, cc = rem & 63;
  st_b16_sys(&dst[idx], f2bf(src[o * 192 + cc * 3 + kk]));
}

// ---------------------------------------------------------------------------
// phase 0b: EdgeConv for graph b. out0 via bypass stores; stats via atomics.
// ---------------------------------------------------------------------------
__device__ __forceinline__ void edge_body(
    SMem& sm, const int b, const int tid,
    const float* __restrict__ x, const int* __restrict__ ei,
    const float* __restrict__ w1, const float* __restrict__ b1,
    const float* __restrict__ w2, const float* __restrict__ b2,
    ushort* __restrict__ out0, float* __restrict__ stats1)
{
  auto& E = sm.edge;
  const int w = tid >> 6;
  __syncthreads();                       // protect LDS union vs prior phase
  if (tid < 8) E.w1s[tid] = w1[tid];
  if (tid < 4) E.b1s[tid] = b1[tid];
  if (tid < 64) { E.xs[tid] = x[(b << 6) + tid]; E.b2s[tid] = b2[tid]; }
  E.w2s[tid] = w2[tid];
  for (int i = tid; i < 1440; i += 256) (&E.aggT[0][0][0])[i] = 0.f;
  __syncthreads();

  const int e0 = b * EPG;
  const int4 s4 = ((const int4*)(ei + e0))[tid];
  const int4 d4 = ((const int4*)(ei + NEDGE + e0))[tid];
  float* agw = &E.aggT[w][0][0];
  const int sls[4] = {s4.x & 63, s4.y & 63, s4.z & 63, s4.w & 63};
  const int dls[4] = {d4.x & 63, d4.y & 63, d4.z & 63, d4.w & 63};
#pragma unroll
  for (int e = 0; e < 4; ++e) {
    const int dl = dls[e];
    const float xi = E.xs[dl];
    const float dx = E.xs[sls[e]] - xi;
#pragma unroll
    for (int j = 0; j < 4; ++j) {
      float h = fmaxf(fmaf(xi, E.w1s[j], fmaf(dx, E.w1s[4 + j], E.b1s[j])), 0.f);
      atomicAdd(&agw[j * 72 + dl], h);
    }
    atomicAdd(&agw[4 * 72 + dl], 1.0f);
  }
  __syncthreads();

  if (tid < 64) {
    const int n = tid;
    const float a0 = E.aggT[0][0][n] + E.aggT[1][0][n] + E.aggT[2][0][n] + E.aggT[3][0][n];
    const float a1 = E.aggT[0][1][n] + E.aggT[1][1][n] + E.aggT[2][1][n] + E.aggT[3][1][n];
    const float a2 = E.aggT[0][2][n] + E.aggT[1][2][n] + E.aggT[2][2][n] + E.aggT[3][2][n];
    const float a3v = E.aggT[0][3][n] + E.aggT[1][3][n] + E.aggT[2][3][n] + E.aggT[3][3][n];
    const float dg = E.aggT[0][4][n] + E.aggT[1][4][n] + E.aggT[2][4][n] + E.aggT[3][4][n];
    *(float4*)&E.aggC[n][0] = make_float4(a0, a1, a2, a3v);
    E.aggC[n][4] = dg;
  }
  __syncthreads();

  const int c = tid & 63, qq = tid >> 6;
  const float wc0 = E.w2s[c], wc1 = E.w2s[64 + c], wc2 = E.w2s[128 + c], wc3 = E.w2s[192 + c];
  const float b2c = E.b2s[c];
  float s = 0.f, ss = 0.f;
  for (int n = qq; n < 64; n += 4) {
    const float4 a = *(const float4*)&E.aggC[n][0];
    const float dg = E.aggC[n][4];
    float v = a.x * wc0 + a.y * wc1 + a.z * wc2 + a.w * wc3 + dg * b2c;
    st_b16_sys(&out0[(size_t)(((b << 6) + n) << 6) + c], f2bf(v));
    s += v; ss += v * v;
  }
  E.rs[qq][c] = s; E.rss[qq][c] = ss;
  __syncthreads();
  if (tid < 64) {
    float* dst = stats1 + ((b & (REP - 1)) << 7);
    atomicAdd(&dst[tid], E.rs[0][tid] + E.rs[1][tid] + E.rs[2][tid] + E.rs[3][tid]);
    atomicAdd(&dst[64 + tid], E.rss[0][tid] + E.rss[1][tid] + E.rss[2][tid] + E.rss[3][tid]);
  }
}

// ---------------------------------------------------------------------------
// phases 1/2: BN + conv1d-as-MFMA. Stats read at coherence point; activation
// input via normal cached loads (first touch); output via bypass stores.
// ---------------------------------------------------------------------------
__device__ __forceinline__ void conv_body(
    SMem& sm, const int b, const int tid,
    const ushort* __restrict__ in, const float* __restrict__ stats_in,
    const float* __restrict__ gamma, const float* __restrict__ beta,
    const ushort* __restrict__ cwt, const float* __restrict__ cb,
    ushort* __restrict__ out, float* __restrict__ stats_out)
{
  auto& C = sm.conv;
  __syncthreads();                       // protect LDS union vs prior phase
  if (tid < 64) {
    float smv = 0.f, sq = 0.f;
#pragma unroll 8
    for (int r = 0; r < REP; ++r) {
      smv += ld_f32_coh(&stats_in[(r << 7) + tid]);
      sq += ld_f32_coh(&stats_in[(r << 7) + 64 + tid]);
    }
    const float mean = smv * (1.0f / CNTF);
    const float var = sq * (1.0f / CNTF) - mean * mean;
    const float a = gamma[tid] * rsqrtf(var + EPSV);
    C.aco[tid] = a;
    C.bco[tid] = beta[tid] - mean * a;
    C.cbs[tid] = cb[tid];
    C.Yt[0][tid] = 0;
    C.Yt[65][tid] = 0;
  }
  __syncthreads();

  const size_t base = (size_t)b << 12;
  {
    const int lr = tid >> 2, p = (tid & 3) << 4;
    const ushort8 r0 = *(const ushort8*)&in[base + (lr << 6) + p];
    const ushort8 r1 = *(const ushort8*)&in[base + (lr << 6) + p + 8];
    ushort tmp[16];
#pragma unroll
    for (int j = 0; j < 8; ++j)
      tmp[j] = f2bf(fmaxf(fmaf(C.aco[p + j], bf2f(r0[j]), C.bco[p + j]), 0.f));
#pragma unroll
    for (int j = 0; j < 8; ++j)
      tmp[8 + j] = f2bf(fmaxf(fmaf(C.aco[p + 8 + j], bf2f(r1[j]), C.bco[p + 8 + j]), 0.f));
    *(ushort8*)&C.Yt[lr + 1][p] = *(ushort8*)&tmp[0];
    *(ushort8*)&C.Yt[lr + 1][p + 8] = *(ushort8*)&tmp[8];
  }
  {
    const ushort8* gw = (const ushort8*)cwt;
#pragma unroll
    for (int i = 0; i < 6; ++i) {
      const int e8 = (i << 8) + tid;
      const int o = e8 / 24, k8 = (e8 - o * 24) << 3;
      *(ushort8*)&C.As[o][k8] = gw[e8];
    }
  }
  __syncthreads();

  const int lane = tid & 63, w = tid >> 6;
  const int lm = lane & 15, q = lane >> 4;
  f32x4 acc[4];
#pragma unroll
  for (int nt = 0; nt < 4; ++nt) acc[nt] = (f32x4){0.f, 0.f, 0.f, 0.f};

#pragma unroll
  for (int kk = 0; kk < 3; ++kk) {
#pragma unroll
    for (int ks = 0; ks < 2; ++ks) {
      const short8 af = *(const short8*)&C.As[(w << 4) + lm][(kk << 6) + (ks << 5) + (q << 3)];
#pragma unroll
      for (int nt = 0; nt < 4; ++nt) {
        const short8 bfr = *(const short8*)&C.Yt[(nt << 4) + lm + kk][(ks << 5) + (q << 3)];
        acc[nt] = __builtin_amdgcn_mfma_f32_16x16x32_bf16(af, bfr, acc[nt], 0, 0, 0);
      }
    }
  }

  const int obase = (w << 4) + (q << 2);
  const float4 cb4 = *(const float4*)&C.cbs[obase];
  float s[4] = {0.f, 0.f, 0.f, 0.f}, ss[4] = {0.f, 0.f, 0.f, 0.f};
#pragma unroll
  for (int nt = 0; nt < 4; ++nt) {
    const int l = (nt << 4) + lm;
    float4 v = make_float4(acc[nt][0] + cb4.x, acc[nt][1] + cb4.y,
                           acc[nt][2] + cb4.z, acc[nt][3] + cb4.w);
    const uint u0 = (uint)f2bf(v.x) | ((uint)f2bf(v.y) << 16);
    const uint u1 = (uint)f2bf(v.z) | ((uint)f2bf(v.w) << 16);
    uint2v pk; pk.x = u0; pk.y = u1;
    st_b64_sys(&out[base + (l << 6) + obase], pk);
    s[0] += v.x; ss[0] += v.x * v.x;
    s[1] += v.y; ss[1] += v.y * v.y;
    s[2] += v.z; ss[2] += v.z * v.z;
    s[3] += v.w; ss[3] += v.w * v.w;
  }
#pragma unroll
  for (int i = 0; i < 4; ++i) {
#pragma unroll
    for (int off = 1; off < 16; off <<= 1) {
      s[i] += __shfl_xor(s[i], off);
      ss[i] += __shfl_xor(ss[i], off);
    }
    if (lm == 0) { C.ldsS[obase + i] = s[i]; C.ldsSS[obase + i] = ss[i]; }
  }
  __syncthreads();
  if (tid < 64) {
    float* dst = stats_out + ((b & (REP - 1)) << 7);
    atomicAdd(&dst[tid], C.ldsS[tid]);
    atomicAdd(&dst[64 + tid], C.ldsSS[tid]);
  }
}

// ---------------------------------------------------------------------------
// phase 3: mlp1, 1024 items: 32 M x 4 N x 8 K-splits. h1part via bypass.
// ---------------------------------------------------------------------------
__device__ __forceinline__ void mlp_body(
    SMem& sm, const int bid, const int tid,
    const ushort* __restrict__ z3, const float* __restrict__ stats3,
    const float* __restrict__ g3, const float* __restrict__ be3,
    const ushort* __restrict__ wbf1t, float* __restrict__ h1part)
{
  auto& M = sm.mlp;
  const int bz = bid >> 7;          // 0..7  K-split
  const int bx = (bid >> 2) & 31;   // 0..31 M-tile (32 graphs)
  const int by = bid & 3;           // 0..3  N-tile (64)
  __syncthreads();                  // protect LDS union vs prior phase
  if (tid < 64) {
    float sme = 0.f, sq = 0.f;
#pragma unroll 8
    for (int r = 0; r < REP; ++r) {
      sme += ld_f32_coh(&stats3[(r << 7) + tid]);
      sq += ld_f32_coh(&stats3[(r << 7) + 64 + tid]);
    }
    const float mean = sme * (1.0f / CNTF);
    const float var = sq * (1.0f / CNTF) - mean * mean;
    const float a = g3[tid] * rsqrtf(var + EPSV);
    M.a3s[tid] = a;
    M.b3s[tid] = be3[tid] - mean * a;
  }
  __syncthreads();

  const int lane = tid & 63, w = tid >> 6;
  const int lm = lane & 15, q = lane >> 4;
  const int wr = w >> 1, wc = w & 1;            // wave -> (M half, N half)
  const int gy = tid >> 3, py = (tid & 7) << 3; // Ys staging: 32 rows x 8
  const int nn = tid >> 2, pw = tid & 3;        // Ws staging: 64 rows x 16
  const int g0 = bx << 5, n0 = by << 6;

  f32x4 acc[2];
#pragma unroll
  for (int nt = 0; nt < 2; ++nt) acc[nt] = (f32x4){0.f, 0.f, 0.f, 0.f};

  const size_t ybase = ((size_t)(g0 + gy) << 12);

#pragma unroll 1
  for (int ck = 0; ck < 8; ++ck) {
    const int kc = (bz << 9) + (ck << 6);
    if (ck) __syncthreads();
    // --- stage Ys: BN3+ReLU on bf16 z3 (channel = within-chunk index)
    {
      const ushort8 r0 = *(const ushort8*)(z3 + ybase + kc + py);
      ushort tmp[8];
#pragma unroll
      for (int j = 0; j < 8; ++j)
        tmp[j] = f2bf(fmaxf(fmaf(M.a3s[py + j], bf2f(r0[j]), M.b3s[py + j]), 0.f));
      *(ushort8*)&M.Ys[gy][py] = *(ushort8*)&tmp[0];
    }
    // --- stage Ws: straight copies from chunk-major wbf1t
    {
      const ushort8* gw = (const ushort8*)(wbf1t + ((size_t)((bz << 3) + ck) << 14) + ((size_t)n0 << 6));
      *(ushort8*)&M.Ws[nn][pw << 4] = gw[(nn << 3) + (pw << 1)];
      *(ushort8*)&M.Ws[nn][(pw << 4) + 8] = gw[(nn << 3) + (pw << 1) + 1];
    }
    __syncthreads();
#pragma unroll
    for (int ks = 0; ks < 2; ++ks) {
      const short8 af = *(const short8*)&M.Ys[(wr << 4) + lm][(ks << 5) + (q << 3)];
#pragma unroll
      for (int nt = 0; nt < 2; ++nt) {
        const short8 bfr = *(const short8*)&M.Ws[(wc << 5) + (nt << 4) + lm][(ks << 5) + (q << 3)];
        acc[nt] = __builtin_amdgcn_mfma_f32_16x16x32_bf16(af, bfr, acc[nt], 0, 0, 0);
      }
    }
  }

  float* dst0 = h1part + ((size_t)bz << 18);
  const int gout = g0 + (wr << 4) + (q << 2);
#pragma unroll
  for (int nt = 0; nt < 2; ++nt) {
    const int col = n0 + (wc << 5) + (nt << 4) + lm;
#pragma unroll
    for (int i = 0; i < 4; ++i)
      st_b32_sys(&dst0[((size_t)(gout + i) << 8) + col], acc[nt][i]);
  }
}

// ---------------------------------------------------------------------------
// phase 4: tail (items 0..63). h1part read = first touch (cached ok).
// Final logits via normal stores (kernel-end release publishes d_out).
// ---------------------------------------------------------------------------
__device__ __forceinline__ void tail_body(
    SMem& sm, const int bid, const int tid,
    const float* __restrict__ h1part, const float* __restrict__ bm1,
    const ushort* __restrict__ wbf2t, const float* __restrict__ bm2,
    const ushort* __restrict__ wbf3t, const float* __restrict__ bm3,
    const ushort* __restrict__ wptbf, const float* __restrict__ bp,
    float* __restrict__ out)
{
  auto& T = sm.tail;
  const int g0 = bid << 4;
  const int lane = tid & 63, w = tid >> 6;
  const int lm = lane & 15, q = lane >> 4;
  const int gr = q << 2;

  __syncthreads();                  // protect LDS union vs prior phase
  {
    const int r = tid >> 4, c0 = (tid & 15) << 4;
    const float* srcb = h1part + ((size_t)(g0 + r) << 8) + c0;
#pragma unroll
    for (int i = 0; i < 4; ++i) {
      float4 vs = *(const float4*)(bm1 + c0 + (i << 2));
#pragma unroll
      for (int bz = 0; bz < 8; ++bz) {
        const float4 p = *(const float4*)(srcb + ((size_t)bz << 18) + (i << 2));
        vs.x += p.x; vs.y += p.y; vs.z += p.z; vs.w += p.w;
      }
      *(ushort4*)&T.h1s[r][c0 + (i << 2)] = make_ushort4(
          f2bf(fmaxf(vs.x, 0.f)), f2bf(fmaxf(vs.y, 0.f)),
          f2bf(fmaxf(vs.z, 0.f)), f2bf(fmaxf(vs.w, 0.f)));
    }
  }
  __syncthreads();

  // ---- GEMM2 (B direct from global)
  f32x4 acc[4];
#pragma unroll
  for (int nt = 0; nt < 4; ++nt) acc[nt] = (f32x4){0.f, 0.f, 0.f, 0.f};
#pragma unroll
  for (int ck = 0; ck < 4; ++ck) {
#pragma unroll
    for (int ks = 0; ks < 2; ++ks) {
      const short8 af = *(const short8*)&T.h1s[lm][(ck << 6) + (ks << 5) + (q << 3)];
#pragma unroll
      for (int nt = 0; nt < 4; ++nt) {
        const int n = (w << 6) + (nt << 4) + lm;
        const short8 bfr = *(const short8*)&wbf2t[((size_t)ck << 14) + (n << 6) + (ks << 5) + (q << 3)];
        acc[nt] = __builtin_amdgcn_mfma_f32_16x16x32_bf16(af, bfr, acc[nt], 0, 0, 0);
      }
    }
  }
#pragma unroll
  for (int nt = 0; nt < 4; ++nt) {
    const int col = (w << 6) + (nt << 4) + lm;
    const float bv = bm2[col];
#pragma unroll
    for (int i = 0; i < 4; ++i)
      T.h2s[gr + i][col] = f2bf(fmaxf(acc[nt][i] + bv, 0.f));
  }
  __syncthreads();

  // ---- GEMM3 (B direct from global)
  f32x4 acc2[4];
#pragma unroll
  for (int nt = 0; nt < 4; ++nt) acc2[nt] = (f32x4){0.f, 0.f, 0.f, 0.f};
#pragma unroll
  for (int ck = 0; ck < 4; ++ck) {
#pragma unroll
    for (int ks = 0; ks < 2; ++ks) {
      const short8 af = *(const short8*)&T.h2s[lm][(ck << 6) + (ks << 5) + (q << 3)];
#pragma unroll
      for (int nt = 0; nt < 4; ++nt) {
        const int n = (w << 6) + (nt << 4) + lm;
        const short8 bfr = *(const short8*)&wbf3t[((size_t)ck << 14) + (n << 6) + (ks << 5) + (q << 3)];
        acc2[nt] = __builtin_amdgcn_mfma_f32_16x16x32_bf16(af, bfr, acc2[nt], 0, 0, 0);
      }
    }
  }
  __syncthreads();                  // all h2s reads done before overwrite
#pragma unroll
  for (int nt = 0; nt < 4; ++nt) {
    const int col = (w << 6) + (nt << 4) + lm;
    const float bv = bm3[col];
#pragma unroll
    for (int i = 0; i < 4; ++i)
      T.h2s[gr + i][col] = f2bf(fmaxf(acc2[nt][i] + bv, 0.f));
  }
  __syncthreads();

  if (w == 0) {
    f32x4 lacc = (f32x4){0.f, 0.f, 0.f, 0.f};
#pragma unroll
    for (int ks = 0; ks < 8; ++ks) {
      const short8 af = *(const short8*)&T.h2s[lm][(ks << 5) + (q << 3)];
      const short8 bfr = *(const short8*)&wptbf[(lm << 8) + (ks << 5) + (q << 3)];
      lacc = __builtin_amdgcn_mfma_f32_16x16x32_bf16(af, bfr, lacc, 0, 0, 0);
    }
    const float bpv = bp[lm];
    float lg[4], mx[4], se[4];
#pragma unroll
    for (int i = 0; i < 4; ++i) {
      lg[i] = lacc[i] + bpv;
      float m = lg[i];
#pragma unroll
      for (int off = 1; off < 16; off <<= 1) m = fmaxf(m, __shfl_xor(m, off));
      mx[i] = m;
      float e = expf(lg[i] - m);
#pragma unroll
      for (int off = 1; off < 16; off <<= 1) e += __shfl_xor(e, off);
      se[i] = e;
    }
#pragma unroll
    for (int i = 0; i < 4; ++i)
      out[((g0 + gr + i) << 4) + lm] = (lg[i] - mx[i]) - logf(se[i]);
  }
}

// ---------------------------------------------------------------------------
// Fused persistent kernel, fence-free cross-phase coherence:
//   producers write through to IF (st_*_sys), consumers first-touch with
//   cached loads, stats at coherence point, barriers are pure counters.
// z3 goes to a FRESH ubuf2 (ubuf0 reuse would leave stale clean lines in
// consumer L2s from phase 1).
// ---------------------------------------------------------------------------
__global__ __launch_bounds__(256, 4) void k_all(
    const float* __restrict__ x, const int* __restrict__ ei,
    const float* __restrict__ w1, const float* __restrict__ b1,
    const float* __restrict__ w2, const float* __restrict__ b2,
    const float* __restrict__ c2w, const float* __restrict__ c2b,
    const float* __restrict__ c3w, const float* __restrict__ c3b,
    const float* __restrict__ g1, const float* __restrict__ be1,
    const float* __restrict__ g2, const float* __restrict__ be2,
    const float* __restrict__ g3, const float* __restrict__ be3,
    const float* __restrict__ wm1, const float* __restrict__ bm1,
    const float* __restrict__ wm2, const float* __restrict__ bm2,
    const float* __restrict__ wm3, const float* __restrict__ bm3,
    const float* __restrict__ wp, const float* __restrict__ bp,
    ushort* __restrict__ ubuf0, ushort* __restrict__ ubuf1,
    ushort* __restrict__ ubuf2, float* __restrict__ h1part,
    ushort* __restrict__ wbf1t, ushort* __restrict__ wbf2t,
    ushort* __restrict__ wbf3t, ushort* __restrict__ wptbf,
    ushort* __restrict__ cwt2, ushort* __restrict__ cwt3,
    float* __restrict__ stats, unsigned* __restrict__ bar,
    float* __restrict__ out, int nblk)
{
  __shared__ SMem sm;
  const int tid = threadIdx.x;
  const int bid = blockIdx.x;
  float* stats1 = stats;
  float* stats2 = stats + REP * 128;
  float* stats3 = stats + 2 * REP * 128;

  // phase 0: weight prep (items 0..416) + edge conv (items 417..1440)
  for (int it = bid; it < 417 + NB; it += nblk) {
    if (it < 417)
      prep_body(sm, it, tid, wm1, wm2, wm3, wp, c2w, c3w,
                wbf1t, wbf2t, wbf3t, wptbf, cwt2, cwt3);
    else
      edge_body(sm, it - 417, tid, x, ei, w1, b1, w2, b2, ubuf0, stats1);
  }
  gbar(bar, 0, bid, nblk, tid);
  // phase 1: BN1 + conv2  (ubuf0 -> ubuf1)
  for (int it = bid; it < NB; it += nblk)
    conv_body(sm, it, tid, ubuf0, stats1, g1, be1, cwt2, c2b, ubuf1, stats2);
  gbar(bar, 1, bid, nblk, tid);
  // phase 2: BN2 + conv3  (ubuf1 -> ubuf2, fresh buffer)
  for (int it = bid; it < NB; it += nblk)
    conv_body(sm, it, tid, ubuf1, stats2, g2, be2, cwt3, c3b, ubuf2, stats3);
  gbar(bar, 2, bid, nblk, tid);
  // phase 3: BN3 + GEMM1 split-K partials (ubuf2 -> h1part)
  for (int it = bid; it < NB; it += nblk)
    mlp_body(sm, it, tid, ubuf2, stats3, g3, be3, wbf1t, h1part);
  gbar(bar, 3, bid, nblk, tid);
  // phase 4: tail (items 0..63)
  for (int it = bid; it < 64; it += nblk)
    tail_body(sm, it, tid, h1part, bm1, wbf2t, bm2, wbf3t, bm3, wptbf, bp, out);
}

// ===========================================================================
// Fallback path: verified multi-kernel chain (used only if occupancy query
// fails). Kernel boundaries provide coherence; bypass stores remain correct.
// ===========================================================================
__global__ __launch_bounds__(256) void k_prepw(
    const float* __restrict__ wm1, const float* __restrict__ wm2,
    const float* __restrict__ wm3, const float* __restrict__ wp,
    const float* __restrict__ c2w, const float* __restrict__ c3w,
    ushort* __restrict__ wbf1t, ushort* __restrict__ wbf2t,
    ushort* __restrict__ wbf3t, ushort* __restrict__ wptbf,
    ushort* __restrict__ cwt2, ushort* __restrict__ cwt3,
    float* __restrict__ stats)
{
  __shared__ SMem sm;
  const int tid = threadIdx.x;
  const int bb = blockIdx.x;
  if (bb == 417) {
    float4 z4 = make_float4(0.f, 0.f, 0.f, 0.f);
#pragma unroll
    for (int i = 0; i < 12; ++i) ((float4*)stats)[(i << 8) + tid] = z4;
    return;
  }
  prep_body(sm, bb, tid, wm1, wm2, wm3, wp, c2w, c3w,
            wbf1t, wbf2t, wbf3t, wptbf, cwt2, cwt3);
}

__global__ __launch_bounds__(256) void k_edge(
    const float* __restrict__ x, const int* __restrict__ ei,
    const float* __restrict__ w1, const float* __restrict__ b1,
    const float* __restrict__ w2, const float* __restrict__ b2,
    ushort* __restrict__ out0, float* __restrict__ stats1)
{
  __shared__ SMem sm;
  edge_body(sm, blockIdx.x, threadIdx.x, x, ei, w1, b1, w2, b2, out0, stats1);
}

__global__ __launch_bounds__(256) void k_convm(
    const ushort* __restrict__ in, const float* __restrict__ stats_in,
    const float* __restrict__ gamma, const float* __restrict__ beta,
    const ushort* __restrict__ cwt, const float* __restrict__ cb,
    ushort* __restrict__ out, float* __restrict__ stats_out)
{
  __shared__ SMem sm;
  conv_body(sm, blockIdx.x, threadIdx.x, in, stats_in, gamma, beta, cwt, cb,
            out, stats_out);
}

__global__ __launch_bounds__(256) void k_mlp1f(
    const ushort* __restrict__ z3, const float* __restrict__ stats3,
    const float* __restrict__ g3, const float* __restrict__ be3,
    const ushort* __restrict__ wbf1t, float* __restrict__ h1part)
{
  __shared__ SMem sm;
  mlp_body(sm, blockIdx.x, threadIdx.x, z3, stats3, g3, be3, wbf1t, h1part);
}

__global__ __launch_bounds__(256) void k_tailf(
    const float* __restrict__ h1part, const float* __restrict__ bm1,
    const ushort* __restrict__ wbf2t, const float* __restrict__ bm2,
    const ushort* __restrict__ wbf3t, const float* __restrict__ bm3,
    const ushort* __restrict__ wptbf, const float* __restrict__ bp,
    float* __restrict__ out)
{
  __shared__ SMem sm;
  tail_body(sm, blockIdx.x, threadIdx.x, h1part, bm1, wbf2t, bm2, wbf3t, bm3,
            wptbf, bp, out);
}

// ---------------------------------------------------------------------------
extern "C" void kernel_launch(void* const* d_in, const int* in_sizes, int n_in,
                              void* d_out, int out_size, void* d_ws, size_t ws_size,
                              hipStream_t stream)
{
  const float* x   = (const float*)d_in[0];
  const int*   ei  = (const int*)d_in[1];
  const float* w1  = (const float*)d_in[2];
  const float* b1  = (const float*)d_in[3];
  const float* w2  = (const float*)d_in[4];
  const float* b2  = (const float*)d_in[5];
  const float* c2w = (const float*)d_in[6];
  const float* c2b = (const float*)d_in[7];
  const float* c3w = (const float*)d_in[8];
  const float* c3b = (const float*)d_in[9];
  const float* g1  = (const float*)d_in[10];
  const float* be1 = (const float*)d_in[11];
  const float* g2  = (const float*)d_in[12];
  const float* be2 = (const float*)d_in[13];
  const float* g3  = (const float*)d_in[14];
  const float* be3 = (const float*)d_in[15];
  const float* wm1 = (const float*)d_in[16];
  const float* bm1 = (const float*)d_in[17];
  const float* wm2 = (const float*)d_in[18];
  const float* bm2 = (const float*)d_in[19];
  const float* wm3 = (const float*)d_in[20];
  const float* bm3 = (const float*)d_in[21];
  const float* wp  = (const float*)d_in[22];
  const float* bp  = (const float*)d_in[23];

  char* ws = (char*)d_ws;
  ushort* ubuf0 = (ushort*)ws;                          // 8 MiB: out0 (bf16)
  ushort* ubuf1 = (ushort*)(ws + ((size_t)8 << 20));    // 8 MiB: z2 (bf16)
  float*  h1part = (float*)(ws + ((size_t)16 << 20));   // 8 MiB fp32 partials
  ushort* wbf1t = (ushort*)(ws + ((size_t)24 << 20));   // 2 MiB bf16 wm1^T
  ushort* wbf2t = (ushort*)(ws + ((size_t)26 << 20));               // 128 KiB
  ushort* wbf3t = (ushort*)(ws + ((size_t)26 << 20) + (128 << 10)); // 128 KiB
  ushort* wptbf = (ushort*)(ws + ((size_t)26 << 20) + (256 << 10)); // 8 KiB
  float* stats = (float*)(ws + ((size_t)27 << 20));     // 48 KiB [3][REP][128]
  float* stats1 = stats;
  float* stats2 = stats + REP * 128;
  float* stats3 = stats + 2 * REP * 128;
  unsigned* bar = (unsigned*)(ws + ((size_t)27 << 20) + 49152); // 33 KiB barriers
  ushort* ubuf2 = (ushort*)(ws + ((size_t)32 << 20));   // 8 MiB: z3 (fresh buffer)
  ushort* cwt2 = (ushort*)d_out;          // d_out scratch, overwritten at tail
  ushort* cwt3 = (ushort*)d_out + 12288;
  float* outp = (float*)d_out;

  // Size the persistent grid once: guaranteed-co-resident block count.
  static int nblk_cached = -1;
  if (nblk_cached < 0) {
    int ncu = 0, maxb = 0;
    hipError_t e1 = hipDeviceGetAttribute(&ncu, hipDeviceAttributeMultiprocessorCount, 0);
    hipError_t e2 = hipOccupancyMaxActiveBlocksPerMultiprocessor(&maxb, k_all, 256, 0);
    if (e1 == hipSuccess && e2 == hipSuccess && ncu > 0 && maxb > 0) {
      long t = (long)ncu * (long)maxb;
      nblk_cached = (int)(t < MAXGRID ? t : MAXGRID);
    } else {
      nblk_cached = 0;   // occupancy unknown -> verified multi-kernel chain
    }
  }
  const int nblk = nblk_cached;

  if (nblk > 0) {
    // zero stats (48 KiB) + barrier counters (33 KiB); replayed with the graph
    hipMemsetAsync(stats, 0, 49152 + NPHASE * 33 * BARSLOT * 4, stream);
    k_all<<<dim3(nblk), dim3(256), 0, stream>>>(
        x, ei, w1, b1, w2, b2, c2w, c2b, c3w, c3b,
        g1, be1, g2, be2, g3, be3,
        wm1, bm1, wm2, bm2, wm3, bm3, wp, bp,
        ubuf0, ubuf1, ubuf2, h1part, wbf1t, wbf2t, wbf3t, wptbf,
        cwt2, cwt3, stats, bar, outp, nblk);
  } else {
    k_prepw<<<dim3(418), dim3(256), 0, stream>>>(
        wm1, wm2, wm3, wp, c2w, c3w,
        wbf1t, wbf2t, wbf3t, wptbf, cwt2, cwt3, stats);
    k_edge<<<dim3(NB), dim3(256), 0, stream>>>(x, ei, w1, b1, w2, b2, ubuf0, stats1);
    k_convm<<<dim3(NB), dim3(256), 0, stream>>>(ubuf0, stats1, g1, be1, cwt2, c2b, ubuf1, stats2);
    k_convm<<<dim3(NB), dim3(256), 0, stream>>>(ubuf1, stats2, g2, be2, cwt3, c3b, ubuf2, stats3);
    k_mlp1f<<<dim3(NB), dim3(256), 0, stream>>>(ubuf2, stats3, g3, be3, wbf1t, h1part);
    k_tailf<<<dim3(64), dim3(256), 0, stream>>>(h1part, bm1, wbf2t, bm2, wbf3t, bm3,
                                                wptbf, bp, outp);
  }
}

// Round 5
// 218.546 us; speedup vs baseline: 1.5496x; 1.0113x over previous
//
#include <hip/hip_runtime.h>
#include <cstdint>
#include <cstddef>

typedef __attribute__((ext_vector_type(8))) short short8;
typedef __attribute__((ext_vector_type(8))) unsigned short ushort8;
typedef __attribute__((ext_vector_type(4))) float f32x4;
typedef __attribute__((ext_vector_type(2))) unsigned int uint2v;

#define EPSV 1e-5f
#define NB 1024
#define NEDGE 1048576
#define EPG 1024
#define CNTF 65536.0f
#define REP 32           // stats replica slots (contention spreading)
#define MAXGRID 1024
#define BARSLOT 64       // u32 per barrier slot (256 B -> no line sharing)
#define NPHASE 4
#define NSLOT 65         // per phase: 32 arrival + 32 release + 1 root

__device__ __forceinline__ ushort f2bf(float f) {
  uint u = __float_as_uint(f);
  return (ushort)((u + 0x7FFFu + ((u >> 16) & 1u)) >> 16);
}
__device__ __forceinline__ float bf2f(ushort u) {
  return __uint_as_float((uint)u << 16);
}

// ---------------------------------------------------------------------------
// L2-BYPASS STORES (sc0 sc1 = write-through past L1+L2 to IF/L3; no dirty L2
// lines). Producers use these for ALL cross-phase data; consumers use normal
// cached loads (first touch in consumer phase -> no stale line can exist).
// ---------------------------------------------------------------------------
__device__ __forceinline__ void st_b128_sys(void* p, ushort8 v) {
  asm volatile("global_store_dwordx4 %0, %1, off sc0 sc1" :: "v"(p), "v"(v) : "memory");
}
__device__ __forceinline__ void st_b64_sys(void* p, uint2v v) {
  asm volatile("global_store_dwordx2 %0, %1, off sc0 sc1" :: "v"(p), "v"(v) : "memory");
}
__device__ __forceinline__ void st_b32_sys(void* p, float v) {
  asm volatile("global_store_dword %0, %1, off sc0 sc1" :: "v"(p), "v"(v) : "memory");
}
__device__ __forceinline__ void st_b16_sys(void* p, ushort v) {
  unsigned d = v;
  asm volatile("global_store_short %0, %1, off sc0 sc1" :: "v"(p), "v"(d) : "memory");
}
__device__ __forceinline__ float ld_f32_coh(const float* p) {
  return __hip_atomic_load((float*)p, __ATOMIC_RELAXED, __HIP_MEMORY_SCOPE_AGENT);
}

// ---------------------------------------------------------------------------
// LDS union: max member = conv (36,384 B) -> with __launch_bounds__(256,4)
// 4 blocks/CU (145.5 KB LDS/CU), 1024 co-resident blocks.
// ---------------------------------------------------------------------------
union __align__(16) SMem {
  struct { ushort T[64][72]; } prep;                                 //  9,216 B
  struct { float xs[64]; float aggT[4][5][72]; float aggC[64][8];
           float w1s[8], b1s[4], w2s[256], b2s[64];
           float rs[4][64], rss[4][64]; } edge;                      // ~11,424 B
  struct { ushort As[64][200]; ushort Yt[66][72];
           float aco[64], bco[64], cbs[64], ldsS[64], ldsSS[64]; } conv; // 36,384 B
  struct { ushort Ys[32][72]; ushort Ws[64][72];
           float a3s[64], b3s[64]; } mlp;                            // 14,336 B
  struct { ushort h1s[16][264]; ushort h2s[16][264]; } tail;         // 16,896 B
};

// ---------------------------------------------------------------------------
// Software grid barrier v3: zero cache ops + BOUNDED POLL FAN-IN.
//
// R4 post-mortem: barriers cost ~15us each. All 1024 tid0s polled the single
// root word at its coherence point; the request queue saturated, so the
// promoting fetch_add queued behind thousands of polls and the release had
// to drain the same queue -> multi-us per barrier.
//
// v3 protocol (max 32 pollers per address):
//   arrive:  vmcnt(0) drain + __syncthreads; relaxed leaf fetch_add.
//   last-per-leaf (promoter): relaxed root fetch_add; poll root (32 pollers,
//            s_sleep(2)); when root==nleaf, store 1 to this leaf's RELEASE
//            slot (relaxed agent store, coherence-point visible).
//   others:  poll their leaf's release slot (<=31 pollers, s_sleep(8)).
// Release propagates root -> 32 leaves -> blocks in ~2 coherence hops.
// Counters zeroed by the pre-launch memset; stale garbage falls through
// (>= promote, ==0 spin exit on nonzero); no deadlock possible.
// ---------------------------------------------------------------------------
__device__ __forceinline__ void gbar(unsigned* bar, int phase, int bid,
                                     int nblk, int tid)
{
  asm volatile("s_waitcnt vmcnt(0)" ::: "memory");
  __syncthreads();
  if (tid == 0) {
    const int lf = bid & 31;
    unsigned* leaf = bar + (size_t)(phase * NSLOT + lf) * BARSLOT;
    unsigned* rls  = bar + (size_t)(phase * NSLOT + 32 + lf) * BARSLOT;
    unsigned* root = bar + (size_t)(phase * NSLOT + 64) * BARSLOT;
    const unsigned leafcnt = (unsigned)((nblk + 31 - lf) >> 5);
    const unsigned nleaf = (unsigned)(nblk < 32 ? nblk : 32);
    unsigned old = __hip_atomic_fetch_add(leaf, 1u, __ATOMIC_RELAXED,
                                          __HIP_MEMORY_SCOPE_AGENT);
    if (old >= leafcnt - 1) {
      // promoter: bump root, wait for all leaves, then release own leaf
      __hip_atomic_fetch_add(root, 1u, __ATOMIC_RELAXED,
                             __HIP_MEMORY_SCOPE_AGENT);
      while (__hip_atomic_load(root, __ATOMIC_RELAXED,
                               __HIP_MEMORY_SCOPE_AGENT) < nleaf)
        __builtin_amdgcn_s_sleep(2);
      __hip_atomic_store(rls, 1u, __ATOMIC_RELAXED,
                         __HIP_MEMORY_SCOPE_AGENT);
    } else {
      while (__hip_atomic_load(rls, __ATOMIC_RELAXED,
                               __HIP_MEMORY_SCOPE_AGENT) == 0u)
        __builtin_amdgcn_s_sleep(8);
    }
  }
  __syncthreads();
}

// ---------------------------------------------------------------------------
// phase 0a: weight preprocessing (items 0..416). Outputs via bypass stores.
// ---------------------------------------------------------------------------
__device__ __forceinline__ void prep_body(
    SMem& sm, const int bb, const int tid,
    const float* __restrict__ wm1, const float* __restrict__ wm2,
    const float* __restrict__ wm3, const float* __restrict__ wp,
    const float* __restrict__ c2w, const float* __restrict__ c3w,
    ushort* __restrict__ wbf1t, ushort* __restrict__ wbf2t,
    ushort* __restrict__ wbf3t, ushort* __restrict__ wptbf,
    ushort* __restrict__ cwt2, ushort* __restrict__ cwt3)
{
  if (bb < 256) {
    auto& T = sm.prep.T;
    const int kc = bb >> 2, n0 = (bb & 3) << 6;
    const int kk = tid >> 2, np = (tid & 3) << 4;
    const float* srow = wm1 + (((size_t)(kk << 6) + kc) << 8) + n0 + np;
#pragma unroll
    for (int i = 0; i < 4; ++i) {
      const float4 v = *(const float4*)(srow + (i << 2));
      const int n = np + (i << 2);
      T[n + 0][kk] = f2bf(v.x); T[n + 1][kk] = f2bf(v.y);
      T[n + 2][kk] = f2bf(v.z); T[n + 3][kk] = f2bf(v.w);
    }
    __syncthreads();
    ushort* dst = wbf1t + ((size_t)kc << 14) + (n0 << 6);
    const int nl = tid >> 2, qk = (tid & 3) << 4;
    st_b128_sys(dst + (nl << 6) + qk, *(ushort8*)&T[nl][qk]);
    st_b128_sys(dst + (nl << 6) + qk + 8, *(ushort8*)&T[nl][qk + 8]);
    return;
  }
  if (bb < 320) {
    const int base = (((bb - 256) << 8) + tid) << 3;
    const int m = base >> 16;
    const int rem = base & 65535;
    const int kc = rem >> 14, within = rem & 16383;
    const int n = within >> 6, kk0 = within & 63;
    const float* src = m ? wm3 : wm2;
    ushort* dst = m ? wbf3t : wbf2t;
    ushort tmp[8];
#pragma unroll
    for (int j = 0; j < 8; ++j)
      tmp[j] = f2bf(src[(((kc << 6) | (kk0 + j)) << 8) + n]);
    st_b128_sys(&dst[rem], *(ushort8*)&tmp[0]);
    return;
  }
  if (bb == 320) {
    const int a = tid & 15, k0 = (tid >> 4) << 4;
    ushort tmp[16];
#pragma unroll
    for (int j = 0; j < 16; ++j) tmp[j] = f2bf(wp[((k0 + j) << 4) + a]);
    st_b128_sys(&wptbf[(a << 8) + k0], *(ushort8*)&tmp[0]);
    st_b128_sys(&wptbf[(a << 8) + k0 + 8], *(ushort8*)&tmp[8]);
    return;
  }
  // items 321..416: conv weights [o][c][kk] -> bf16 [o][kk*64+c]
  const int flat = (bb - 321) * 256 + tid;   // 0..24575
  const int m = flat >= 12288;
  const int idx = flat - (m ? 12288 : 0);
  const float* src = m ? c3w : c2w;
  ushort* dst = m ? cwt3 : cwt2;
  const int o = idx / 192, rem = idx - o * 192;
  const int kk = rem >> 6, cc = rem & 63;
  st_b16_sys(&dst[idx], f2bf(src[o * 192 + cc * 3 + kk]));
}

// ---------------------------------------------------------------------------
// phase 0b: EdgeConv for graph b. out0 via bypass stores; stats via atomics.
// ---------------------------------------------------------------------------
__device__ __forceinline__ void edge_body(
    SMem& sm, const int b, const int tid,
    const float* __restrict__ x, const int* __restrict__ ei,
    const float* __restrict__ w1, const float* __restrict__ b1,
    const float* __restrict__ w2, const float* __restrict__ b2,
    ushort* __restrict__ out0, float* __restrict__ stats1)
{
  auto& E = sm.edge;
  const int w = tid >> 6;
  __syncthreads();                       // protect LDS union vs prior phase
  if (tid < 8) E.w1s[tid] = w1[tid];
  if (tid < 4) E.b1s[tid] = b1[tid];
  if (tid < 64) { E.xs[tid] = x[(b << 6) + tid]; E.b2s[tid] = b2[tid]; }
  E.w2s[tid] = w2[tid];
  for (int i = tid; i < 1440; i += 256) (&E.aggT[0][0][0])[i] = 0.f;
  __syncthreads();

  const int e0 = b * EPG;
  const int4 s4 = ((const int4*)(ei + e0))[tid];
  const int4 d4 = ((const int4*)(ei + NEDGE + e0))[tid];
  float* agw = &E.aggT[w][0][0];
  const int sls[4] = {s4.x & 63, s4.y & 63, s4.z & 63, s4.w & 63};
  const int dls[4] = {d4.x & 63, d4.y & 63, d4.z & 63, d4.w & 63};
#pragma unroll
  for (int e = 0; e < 4; ++e) {
    const int dl = dls[e];
    const float xi = E.xs[dl];
    const float dx = E.xs[sls[e]] - xi;
#pragma unroll
    for (int j = 0; j < 4; ++j) {
      float h = fmaxf(fmaf(xi, E.w1s[j], fmaf(dx, E.w1s[4 + j], E.b1s[j])), 0.f);
      atomicAdd(&agw[j * 72 + dl], h);
    }
    atomicAdd(&agw[4 * 72 + dl], 1.0f);
  }
  __syncthreads();

  if (tid < 64) {
    const int n = tid;
    const float a0 = E.aggT[0][0][n] + E.aggT[1][0][n] + E.aggT[2][0][n] + E.aggT[3][0][n];
    const float a1 = E.aggT[0][1][n] + E.aggT[1][1][n] + E.aggT[2][1][n] + E.aggT[3][1][n];
    const float a2 = E.aggT[0][2][n] + E.aggT[1][2][n] + E.aggT[2][2][n] + E.aggT[3][2][n];
    const float a3v = E.aggT[0][3][n] + E.aggT[1][3][n] + E.aggT[2][3][n] + E.aggT[3][3][n];
    const float dg = E.aggT[0][4][n] + E.aggT[1][4][n] + E.aggT[2][4][n] + E.aggT[3][4][n];
    *(float4*)&E.aggC[n][0] = make_float4(a0, a1, a2, a3v);
    E.aggC[n][4] = dg;
  }
  __syncthreads();

  const int c = tid & 63, qq = tid >> 6;
  const float wc0 = E.w2s[c], wc1 = E.w2s[64 + c], wc2 = E.w2s[128 + c], wc3 = E.w2s[192 + c];
  const float b2c = E.b2s[c];
  float s = 0.f, ss = 0.f;
  for (int n = qq; n < 64; n += 4) {
    const float4 a = *(const float4*)&E.aggC[n][0];
    const float dg = E.aggC[n][4];
    float v = a.x * wc0 + a.y * wc1 + a.z * wc2 + a.w * wc3 + dg * b2c;
    st_b16_sys(&out0[(size_t)(((b << 6) + n) << 6) + c], f2bf(v));
    s += v; ss += v * v;
  }
  E.rs[qq][c] = s; E.rss[qq][c] = ss;
  __syncthreads();
  if (tid < 64) {
    float* dst = stats1 + ((b & (REP - 1)) << 7);
    atomicAdd(&dst[tid], E.rs[0][tid] + E.rs[1][tid] + E.rs[2][tid] + E.rs[3][tid]);
    atomicAdd(&dst[64 + tid], E.rss[0][tid] + E.rss[1][tid] + E.rss[2][tid] + E.rss[3][tid]);
  }
}

// ---------------------------------------------------------------------------
// phases 1/2: BN + conv1d-as-MFMA. Stats at coherence point; activation
// input cached (first touch); output via bypass stores.
// ---------------------------------------------------------------------------
__device__ __forceinline__ void conv_body(
    SMem& sm, const int b, const int tid,
    const ushort* __restrict__ in, const float* __restrict__ stats_in,
    const float* __restrict__ gamma, const float* __restrict__ beta,
    const ushort* __restrict__ cwt, const float* __restrict__ cb,
    ushort* __restrict__ out, float* __restrict__ stats_out)
{
  auto& C = sm.conv;
  __syncthreads();                       // protect LDS union vs prior phase
  if (tid < 64) {
    float smv = 0.f, sq = 0.f;
#pragma unroll 8
    for (int r = 0; r < REP; ++r) {
      smv += ld_f32_coh(&stats_in[(r << 7) + tid]);
      sq += ld_f32_coh(&stats_in[(r << 7) + 64 + tid]);
    }
    const float mean = smv * (1.0f / CNTF);
    const float var = sq * (1.0f / CNTF) - mean * mean;
    const float a = gamma[tid] * rsqrtf(var + EPSV);
    C.aco[tid] = a;
    C.bco[tid] = beta[tid] - mean * a;
    C.cbs[tid] = cb[tid];
    C.Yt[0][tid] = 0;
    C.Yt[65][tid] = 0;
  }
  __syncthreads();

  const size_t base = (size_t)b << 12;
  {
    const int lr = tid >> 2, p = (tid & 3) << 4;
    const ushort8 r0 = *(const ushort8*)&in[base + (lr << 6) + p];
    const ushort8 r1 = *(const ushort8*)&in[base + (lr << 6) + p + 8];
    ushort tmp[16];
#pragma unroll
    for (int j = 0; j < 8; ++j)
      tmp[j] = f2bf(fmaxf(fmaf(C.aco[p + j], bf2f(r0[j]), C.bco[p + j]), 0.f));
#pragma unroll
    for (int j = 0; j < 8; ++j)
      tmp[8 + j] = f2bf(fmaxf(fmaf(C.aco[p + 8 + j], bf2f(r1[j]), C.bco[p + 8 + j]), 0.f));
    *(ushort8*)&C.Yt[lr + 1][p] = *(ushort8*)&tmp[0];
    *(ushort8*)&C.Yt[lr + 1][p + 8] = *(ushort8*)&tmp[8];
  }
  {
    const ushort8* gw = (const ushort8*)cwt;
#pragma unroll
    for (int i = 0; i < 6; ++i) {
      const int e8 = (i << 8) + tid;
      const int o = e8 / 24, k8 = (e8 - o * 24) << 3;
      *(ushort8*)&C.As[o][k8] = gw[e8];
    }
  }
  __syncthreads();

  const int lane = tid & 63, w = tid >> 6;
  const int lm = lane & 15, q = lane >> 4;
  f32x4 acc[4];
#pragma unroll
  for (int nt = 0; nt < 4; ++nt) acc[nt] = (f32x4){0.f, 0.f, 0.f, 0.f};

#pragma unroll
  for (int kk = 0; kk < 3; ++kk) {
#pragma unroll
    for (int ks = 0; ks < 2; ++ks) {
      const short8 af = *(const short8*)&C.As[(w << 4) + lm][(kk << 6) + (ks << 5) + (q << 3)];
#pragma unroll
      for (int nt = 0; nt < 4; ++nt) {
        const short8 bfr = *(const short8*)&C.Yt[(nt << 4) + lm + kk][(ks << 5) + (q << 3)];
        acc[nt] = __builtin_amdgcn_mfma_f32_16x16x32_bf16(af, bfr, acc[nt], 0, 0, 0);
      }
    }
  }

  const int obase = (w << 4) + (q << 2);
  const float4 cb4 = *(const float4*)&C.cbs[obase];
  float s[4] = {0.f, 0.f, 0.f, 0.f}, ss[4] = {0.f, 0.f, 0.f, 0.f};
#pragma unroll
  for (int nt = 0; nt < 4; ++nt) {
    const int l = (nt << 4) + lm;
    float4 v = make_float4(acc[nt][0] + cb4.x, acc[nt][1] + cb4.y,
                           acc[nt][2] + cb4.z, acc[nt][3] + cb4.w);
    const uint u0 = (uint)f2bf(v.x) | ((uint)f2bf(v.y) << 16);
    const uint u1 = (uint)f2bf(v.z) | ((uint)f2bf(v.w) << 16);
    uint2v pk; pk.x = u0; pk.y = u1;
    st_b64_sys(&out[base + (l << 6) + obase], pk);
    s[0] += v.x; ss[0] += v.x * v.x;
    s[1] += v.y; ss[1] += v.y * v.y;
    s[2] += v.z; ss[2] += v.z * v.z;
    s[3] += v.w; ss[3] += v.w * v.w;
  }
#pragma unroll
  for (int i = 0; i < 4; ++i) {
#pragma unroll
    for (int off = 1; off < 16; off <<= 1) {
      s[i] += __shfl_xor(s[i], off);
      ss[i] += __shfl_xor(ss[i], off);
    }
    if (lm == 0) { C.ldsS[obase + i] = s[i]; C.ldsSS[obase + i] = ss[i]; }
  }
  __syncthreads();
  if (tid < 64) {
    float* dst = stats_out + ((b & (REP - 1)) << 7);
    atomicAdd(&dst[tid], C.ldsS[tid]);
    atomicAdd(&dst[64 + tid], C.ldsSS[tid]);
  }
}

// ---------------------------------------------------------------------------
// phase 3: mlp1, 1024 items: 32 M x 4 N x 8 K-splits. h1part via bypass.
// ---------------------------------------------------------------------------
__device__ __forceinline__ void mlp_body(
    SMem& sm, const int bid, const int tid,
    const ushort* __restrict__ z3, const float* __restrict__ stats3,
    const float* __restrict__ g3, const float* __restrict__ be3,
    const ushort* __restrict__ wbf1t, float* __restrict__ h1part)
{
  auto& M = sm.mlp;
  const int bz = bid >> 7;          // 0..7  K-split
  const int bx = (bid >> 2) & 31;   // 0..31 M-tile (32 graphs)
  const int by = bid & 3;           // 0..3  N-tile (64)
  __syncthreads();                  // protect LDS union vs prior phase
  if (tid < 64) {
    float sme = 0.f, sq = 0.f;
#pragma unroll 8
    for (int r = 0; r < REP; ++r) {
      sme += ld_f32_coh(&stats3[(r << 7) + tid]);
      sq += ld_f32_coh(&stats3[(r << 7) + 64 + tid]);
    }
    const float mean = sme * (1.0f / CNTF);
    const float var = sq * (1.0f / CNTF) - mean * mean;
    const float a = g3[tid] * rsqrtf(var + EPSV);
    M.a3s[tid] = a;
    M.b3s[tid] = be3[tid] - mean * a;
  }
  __syncthreads();

  const int lane = tid & 63, w = tid >> 6;
  const int lm = lane & 15, q = lane >> 4;
  const int wr = w >> 1, wc = w & 1;            // wave -> (M half, N half)
  const int gy = tid >> 3, py = (tid & 7) << 3; // Ys staging: 32 rows x 8
  const int nn = tid >> 2, pw = tid & 3;        // Ws staging: 64 rows x 16
  const int g0 = bx << 5, n0 = by << 6;

  f32x4 acc[2];
#pragma unroll
  for (int nt = 0; nt < 2; ++nt) acc[nt] = (f32x4){0.f, 0.f, 0.f, 0.f};

  const size_t ybase = ((size_t)(g0 + gy) << 12);

#pragma unroll 1
  for (int ck = 0; ck < 8; ++ck) {
    const int kc = (bz << 9) + (ck << 6);
    if (ck) __syncthreads();
    // --- stage Ys: BN3+ReLU on bf16 z3 (channel = within-chunk index)
    {
      const ushort8 r0 = *(const ushort8*)(z3 + ybase + kc + py);
      ushort tmp[8];
#pragma unroll
      for (int j = 0; j < 8; ++j)
        tmp[j] = f2bf(fmaxf(fmaf(M.a3s[py + j], bf2f(r0[j]), M.b3s[py + j]), 0.f));
      *(ushort8*)&M.Ys[gy][py] = *(ushort8*)&tmp[0];
    }
    // --- stage Ws: straight copies from chunk-major wbf1t
    {
      const ushort8* gw = (const ushort8*)(wbf1t + ((size_t)((bz << 3) + ck) << 14) + ((size_t)n0 << 6));
      *(ushort8*)&M.Ws[nn][pw << 4] = gw[(nn << 3) + (pw << 1)];
      *(ushort8*)&M.Ws[nn][(pw << 4) + 8] = gw[(nn << 3) + (pw << 1) + 1];
    }
    __syncthreads();
#pragma unroll
    for (int ks = 0; ks < 2; ++ks) {
      const short8 af = *(const short8*)&M.Ys[(wr << 4) + lm][(ks << 5) + (q << 3)];
#pragma unroll
      for (int nt = 0; nt < 2; ++nt) {
        const short8 bfr = *(const short8*)&M.Ws[(wc << 5) + (nt << 4) + lm][(ks << 5) + (q << 3)];
        acc[nt] = __builtin_amdgcn_mfma_f32_16x16x32_bf16(af, bfr, acc[nt], 0, 0, 0);
      }
    }
  }

  float* dst0 = h1part + ((size_t)bz << 18);
  const int gout = g0 + (wr << 4) + (q << 2);
#pragma unroll
  for (int nt = 0; nt < 2; ++nt) {
    const int col = n0 + (wc << 5) + (nt << 4) + lm;
#pragma unroll
    for (int i = 0; i < 4; ++i)
      st_b32_sys(&dst0[((size_t)(gout + i) << 8) + col], acc[nt][i]);
  }
}

// ---------------------------------------------------------------------------
// phase 4: tail (items 0..63). h1part read = first touch (cached ok).
// ---------------------------------------------------------------------------
__device__ __forceinline__ void tail_body(
    SMem& sm, const int bid, const int tid,
    const float* __restrict__ h1part, const float* __restrict__ bm1,
    const ushort* __restrict__ wbf2t, const float* __restrict__ bm2,
    const ushort* __restrict__ wbf3t, const float* __restrict__ bm3,
    const ushort* __restrict__ wptbf, const float* __restrict__ bp,
    float* __restrict__ out)
{
  auto& T = sm.tail;
  const int g0 = bid << 4;
  const int lane = tid & 63, w = tid >> 6;
  const int lm = lane & 15, q = lane >> 4;
  const int gr = q << 2;

  __syncthreads();                  // protect LDS union vs prior phase
  {
    const int r = tid >> 4, c0 = (tid & 15) << 4;
    const float* srcb = h1part + ((size_t)(g0 + r) << 8) + c0;
#pragma unroll
    for (int i = 0; i < 4; ++i) {
      float4 vs = *(const float4*)(bm1 + c0 + (i << 2));
#pragma unroll
      for (int bz = 0; bz < 8; ++bz) {
        const float4 p = *(const float4*)(srcb + ((size_t)bz << 18) + (i << 2));
        vs.x += p.x; vs.y += p.y; vs.z += p.z; vs.w += p.w;
      }
      *(ushort4*)&T.h1s[r][c0 + (i << 2)] = make_ushort4(
          f2bf(fmaxf(vs.x, 0.f)), f2bf(fmaxf(vs.y, 0.f)),
          f2bf(fmaxf(vs.z, 0.f)), f2bf(fmaxf(vs.w, 0.f)));
    }
  }
  __syncthreads();

  // ---- GEMM2 (B direct from global)
  f32x4 acc[4];
#pragma unroll
  for (int nt = 0; nt < 4; ++nt) acc[nt] = (f32x4){0.f, 0.f, 0.f, 0.f};
#pragma unroll
  for (int ck = 0; ck < 4; ++ck) {
#pragma unroll
    for (int ks = 0; ks < 2; ++ks) {
      const short8 af = *(const short8*)&T.h1s[lm][(ck << 6) + (ks << 5) + (q << 3)];
#pragma unroll
      for (int nt = 0; nt < 4; ++nt) {
        const int n = (w << 6) + (nt << 4) + lm;
        const short8 bfr = *(const short8*)&wbf2t[((size_t)ck << 14) + (n << 6) + (ks << 5) + (q << 3)];
        acc[nt] = __builtin_amdgcn_mfma_f32_16x16x32_bf16(af, bfr, acc[nt], 0, 0, 0);
      }
    }
  }
#pragma unroll
  for (int nt = 0; nt < 4; ++nt) {
    const int col = (w << 6) + (nt << 4) + lm;
    const float bv = bm2[col];
#pragma unroll
    for (int i = 0; i < 4; ++i)
      T.h2s[gr + i][col] = f2bf(fmaxf(acc[nt][i] + bv, 0.f));
  }
  __syncthreads();

  // ---- GEMM3 (B direct from global)
  f32x4 acc2[4];
#pragma unroll
  for (int nt = 0; nt < 4; ++nt) acc2[nt] = (f32x4){0.f, 0.f, 0.f, 0.f};
#pragma unroll
  for (int ck = 0; ck < 4; ++ck) {
#pragma unroll
    for (int ks = 0; ks < 2; ++ks) {
      const short8 af = *(const short8*)&T.h2s[lm][(ck << 6) + (ks << 5) + (q << 3)];
#pragma unroll
      for (int nt = 0; nt < 4; ++nt) {
        const int n = (w << 6) + (nt << 4) + lm;
        const short8 bfr = *(const short8*)&wbf3t[((size_t)ck << 14) + (n << 6) + (ks << 5) + (q << 3)];
        acc2[nt] = __builtin_amdgcn_mfma_f32_16x16x32_bf16(af, bfr, acc2[nt], 0, 0, 0);
      }
    }
  }
  __syncthreads();                  // all h2s reads done before overwrite
#pragma unroll
  for (int nt = 0; nt < 4; ++nt) {
    const int col = (w << 6) + (nt << 4) + lm;
    const float bv = bm3[col];
#pragma unroll
    for (int i = 0; i < 4; ++i)
      T.h2s[gr + i][col] = f2bf(fmaxf(acc2[nt][i] + bv, 0.f));
  }
  __syncthreads();

  if (w == 0) {
    f32x4 lacc = (f32x4){0.f, 0.f, 0.f, 0.f};
#pragma unroll
    for (int ks = 0; ks < 8; ++ks) {
      const short8 af = *(const short8*)&T.h2s[lm][(ks << 5) + (q << 3)];
      const short8 bfr = *(const short8*)&wptbf[(lm << 8) + (ks << 5) + (q << 3)];
      lacc = __builtin_amdgcn_mfma_f32_16x16x32_bf16(af, bfr, lacc, 0, 0, 0);
    }
    const float bpv = bp[lm];
    float lg[4], mx[4], se[4];
#pragma unroll
    for (int i = 0; i < 4; ++i) {
      lg[i] = lacc[i] + bpv;
      float m = lg[i];
#pragma unroll
      for (int off = 1; off < 16; off <<= 1) m = fmaxf(m, __shfl_xor(m, off));
      mx[i] = m;
      float e = expf(lg[i] - m);
#pragma unroll
      for (int off = 1; off < 16; off <<= 1) e += __shfl_xor(e, off);
      se[i] = e;
    }
#pragma unroll
    for (int i = 0; i < 4; ++i)
      out[((g0 + gr + i) << 4) + lm] = (lg[i] - mx[i]) - logf(se[i]);
  }
}

// ---------------------------------------------------------------------------
// Fused persistent kernel, fence-free cross-phase coherence + tree barrier.
// ---------------------------------------------------------------------------
__global__ __launch_bounds__(256, 4) void k_all(
    const float* __restrict__ x, const int* __restrict__ ei,
    const float* __restrict__ w1, const float* __restrict__ b1,
    const float* __restrict__ w2, const float* __restrict__ b2,
    const float* __restrict__ c2w, const float* __restrict__ c2b,
    const float* __restrict__ c3w, const float* __restrict__ c3b,
    const float* __restrict__ g1, const float* __restrict__ be1,
    const float* __restrict__ g2, const float* __restrict__ be2,
    const float* __restrict__ g3, const float* __restrict__ be3,
    const float* __restrict__ wm1, const float* __restrict__ bm1,
    const float* __restrict__ wm2, const float* __restrict__ bm2,
    const float* __restrict__ wm3, const float* __restrict__ bm3,
    const float* __restrict__ wp, const float* __restrict__ bp,
    ushort* __restrict__ ubuf0, ushort* __restrict__ ubuf1,
    ushort* __restrict__ ubuf2, float* __restrict__ h1part,
    ushort* __restrict__ wbf1t, ushort* __restrict__ wbf2t,
    ushort* __restrict__ wbf3t, ushort* __restrict__ wptbf,
    ushort* __restrict__ cwt2, ushort* __restrict__ cwt3,
    float* __restrict__ stats, unsigned* __restrict__ bar,
    float* __restrict__ out, int nblk)
{
  __shared__ SMem sm;
  const int tid = threadIdx.x;
  const int bid = blockIdx.x;
  float* stats1 = stats;
  float* stats2 = stats + REP * 128;
  float* stats3 = stats + 2 * REP * 128;

  // phase 0: weight prep (items 0..416) + edge conv (items 417..1440)
  for (int it = bid; it < 417 + NB; it += nblk) {
    if (it < 417)
      prep_body(sm, it, tid, wm1, wm2, wm3, wp, c2w, c3w,
                wbf1t, wbf2t, wbf3t, wptbf, cwt2, cwt3);
    else
      edge_body(sm, it - 417, tid, x, ei, w1, b1, w2, b2, ubuf0, stats1);
  }
  gbar(bar, 0, bid, nblk, tid);
  // phase 1: BN1 + conv2  (ubuf0 -> ubuf1)
  for (int it = bid; it < NB; it += nblk)
    conv_body(sm, it, tid, ubuf0, stats1, g1, be1, cwt2, c2b, ubuf1, stats2);
  gbar(bar, 1, bid, nblk, tid);
  // phase 2: BN2 + conv3  (ubuf1 -> ubuf2, fresh buffer)
  for (int it = bid; it < NB; it += nblk)
    conv_body(sm, it, tid, ubuf1, stats2, g2, be2, cwt3, c3b, ubuf2, stats3);
  gbar(bar, 2, bid, nblk, tid);
  // phase 3: BN3 + GEMM1 split-K partials (ubuf2 -> h1part)
  for (int it = bid; it < NB; it += nblk)
    mlp_body(sm, it, tid, ubuf2, stats3, g3, be3, wbf1t, h1part);
  gbar(bar, 3, bid, nblk, tid);
  // phase 4: tail (items 0..63)
  for (int it = bid; it < 64; it += nblk)
    tail_body(sm, it, tid, h1part, bm1, wbf2t, bm2, wbf3t, bm3, wptbf, bp, out);
}

// ===========================================================================
// Fallback path: verified multi-kernel chain (used only if occupancy query
// fails). Kernel boundaries provide coherence; bypass stores remain correct.
// ===========================================================================
__global__ __launch_bounds__(256) void k_prepw(
    const float* __restrict__ wm1, const float* __restrict__ wm2,
    const float* __restrict__ wm3, const float* __restrict__ wp,
    const float* __restrict__ c2w, const float* __restrict__ c3w,
    ushort* __restrict__ wbf1t, ushort* __restrict__ wbf2t,
    ushort* __restrict__ wbf3t, ushort* __restrict__ wptbf,
    ushort* __restrict__ cwt2, ushort* __restrict__ cwt3,
    float* __restrict__ stats)
{
  __shared__ SMem sm;
  const int tid = threadIdx.x;
  const int bb = blockIdx.x;
  if (bb == 417) {
    float4 z4 = make_float4(0.f, 0.f, 0.f, 0.f);
#pragma unroll
    for (int i = 0; i < 12; ++i) ((float4*)stats)[(i << 8) + tid] = z4;
    return;
  }
  prep_body(sm, bb, tid, wm1, wm2, wm3, wp, c2w, c3w,
            wbf1t, wbf2t, wbf3t, wptbf, cwt2, cwt3);
}

__global__ __launch_bounds__(256) void k_edge(
    const float* __restrict__ x, const int* __restrict__ ei,
    const float* __restrict__ w1, const float* __restrict__ b1,
    const float* __restrict__ w2, const float* __restrict__ b2,
    ushort* __restrict__ out0, float* __restrict__ stats1)
{
  __shared__ SMem sm;
  edge_body(sm, blockIdx.x, threadIdx.x, x, ei, w1, b1, w2, b2, out0, stats1);
}

__global__ __launch_bounds__(256) void k_convm(
    const ushort* __restrict__ in, const float* __restrict__ stats_in,
    const float* __restrict__ gamma, const float* __restrict__ beta,
    const ushort* __restrict__ cwt, const float* __restrict__ cb,
    ushort* __restrict__ out, float* __restrict__ stats_out)
{
  __shared__ SMem sm;
  conv_body(sm, blockIdx.x, threadIdx.x, in, stats_in, gamma, beta, cwt, cb,
            out, stats_out);
}

__global__ __launch_bounds__(256) void k_mlp1f(
    const ushort* __restrict__ z3, const float* __restrict__ stats3,
    const float* __restrict__ g3, const float* __restrict__ be3,
    const ushort* __restrict__ wbf1t, float* __restrict__ h1part)
{
  __shared__ SMem sm;
  mlp_body(sm, blockIdx.x, threadIdx.x, z3, stats3, g3, be3, wbf1t, h1part);
}

__global__ __launch_bounds__(256) void k_tailf(
    const float* __restrict__ h1part, const float* __restrict__ bm1,
    const ushort* __restrict__ wbf2t, const float* __restrict__ bm2,
    const ushort* __restrict__ wbf3t, const float* __restrict__ bm3,
    const ushort* __restrict__ wptbf, const float* __restrict__ bp,
    float* __restrict__ out)
{
  __shared__ SMem sm;
  tail_body(sm, blockIdx.x, threadIdx.x, h1part, bm1, wbf2t, bm2, wbf3t, bm3,
            wptbf, bp, out);
}

// ---------------------------------------------------------------------------
extern "C" void kernel_launch(void* const* d_in, const int* in_sizes, int n_in,
                              void* d_out, int out_size, void* d_ws, size_t ws_size,
                              hipStream_t stream)
{
  const float* x   = (const float*)d_in[0];
  const int*   ei  = (const int*)d_in[1];
  const float* w1  = (const float*)d_in[2];
  const float* b1  = (const float*)d_in[3];
  const float* w2  = (const float*)d_in[4];
  const float* b2  = (const float*)d_in[5];
  const float* c2w = (const float*)d_in[6];
  const float* c2b = (const float*)d_in[7];
  const float* c3w = (const float*)d_in[8];
  const float* c3b = (const float*)d_in[9];
  const float* g1  = (const float*)d_in[10];
  const float* be1 = (const float*)d_in[11];
  const float* g2  = (const float*)d_in[12];
  const float* be2 = (const float*)d_in[13];
  const float* g3  = (const float*)d_in[14];
  const float* be3 = (const float*)d_in[15];
  const float* wm1 = (const float*)d_in[16];
  const float* bm1 = (const float*)d_in[17];
  const float* wm2 = (const float*)d_in[18];
  const float* bm2 = (const float*)d_in[19];
  const float* wm3 = (const float*)d_in[20];
  const float* bm3 = (const float*)d_in[21];
  const float* wp  = (const float*)d_in[22];
  const float* bp  = (const float*)d_in[23];

  char* ws = (char*)d_ws;
  ushort* ubuf0 = (ushort*)ws;                          // 8 MiB: out0 (bf16)
  ushort* ubuf1 = (ushort*)(ws + ((size_t)8 << 20));    // 8 MiB: z2 (bf16)
  float*  h1part = (float*)(ws + ((size_t)16 << 20));   // 8 MiB fp32 partials
  ushort* wbf1t = (ushort*)(ws + ((size_t)24 << 20));   // 2 MiB bf16 wm1^T
  ushort* wbf2t = (ushort*)(ws + ((size_t)26 << 20));               // 128 KiB
  ushort* wbf3t = (ushort*)(ws + ((size_t)26 << 20) + (128 << 10)); // 128 KiB
  ushort* wptbf = (ushort*)(ws + ((size_t)26 << 20) + (256 << 10)); // 8 KiB
  float* stats = (float*)(ws + ((size_t)27 << 20));     // 48 KiB [3][REP][128]
  float* stats1 = stats;
  float* stats2 = stats + REP * 128;
  float* stats3 = stats + 2 * REP * 128;
  unsigned* bar = (unsigned*)(ws + ((size_t)27 << 20) + 49152); // 65 KiB barriers
  ushort* ubuf2 = (ushort*)(ws + ((size_t)32 << 20));   // 8 MiB: z3 (fresh buffer)
  ushort* cwt2 = (ushort*)d_out;          // d_out scratch, overwritten at tail
  ushort* cwt3 = (ushort*)d_out + 12288;
  float* outp = (float*)d_out;

  // Size the persistent grid once: guaranteed-co-resident block count.
  static int nblk_cached = -1;
  if (nblk_cached < 0) {
    int ncu = 0, maxb = 0;
    hipError_t e1 = hipDeviceGetAttribute(&ncu, hipDeviceAttributeMultiprocessorCount, 0);
    hipError_t e2 = hipOccupancyMaxActiveBlocksPerMultiprocessor(&maxb, k_all, 256, 0);
    if (e1 == hipSuccess && e2 == hipSuccess && ncu > 0 && maxb > 0) {
      long t = (long)ncu * (long)maxb;
      nblk_cached = (int)(t < MAXGRID ? t : MAXGRID);
    } else {
      nblk_cached = 0;   // occupancy unknown -> verified multi-kernel chain
    }
  }
  const int nblk = nblk_cached;

  if (nblk > 0) {
    // zero stats (48 KiB) + barrier counters (65 KiB); replayed with the graph
    hipMemsetAsync(stats, 0, 49152 + NPHASE * NSLOT * BARSLOT * 4, stream);
    k_all<<<dim3(nblk), dim3(256), 0, stream>>>(
        x, ei, w1, b1, w2, b2, c2w, c2b, c3w, c3b,
        g1, be1, g2, be2, g3, be3,
        wm1, bm1, wm2, bm2, wm3, bm3, wp, bp,
        ubuf0, ubuf1, ubuf2, h1part, wbf1t, wbf2t, wbf3t, wptbf,
        cwt2, cwt3, stats, bar, outp, nblk);
  } else {
    k_prepw<<<dim3(418), dim3(256), 0, stream>>>(
        wm1, wm2, wm3, wp, c2w, c3w,
        wbf1t, wbf2t, wbf3t, wptbf, cwt2, cwt3, stats);
    k_edge<<<dim3(NB), dim3(256), 0, stream>>>(x, ei, w1, b1, w2, b2, ubuf0, stats1);
    k_convm<<<dim3(NB), dim3(256), 0, stream>>>(ubuf0, stats1, g1, be1, cwt2, c2b, ubuf1, stats2);
    k_convm<<<dim3(NB), dim3(256), 0, stream>>>(ubuf1, stats2, g2, be2, cwt3, c3b, ubuf2, stats3);
    k_mlp1f<<<dim3(NB), dim3(256), 0, stream>>>(ubuf2, stats3, g3, be3, wbf1t, h1part);
    k_tailf<<<dim3(64), dim3(256), 0, stream>>>(h1part, bm1, wbf2t, bm2, wbf3t, bm3,
                                                wptbf, bp, outp);
  }
}

// Round 6
// 213.614 us; speedup vs baseline: 1.5854x; 1.0231x over previous
//
#include <hip/hip_runtime.h>
#include <cstdint>
#include <cstddef>

typedef __attribute__((ext_vector_type(8))) short short8;
typedef __attribute__((ext_vector_type(8))) unsigned short ushort8;
typedef __attribute__((ext_vector_type(4))) float f32x4;
typedef __attribute__((ext_vector_type(2))) unsigned int uint2v;

#define EPSV 1e-5f
#define NB 1024
#define NEDGE 1048576
#define EPG 1024
#define CNTF 65536.0f
#define REP 32           // stats replica slots (contention spreading)
#define MAXGRID 1024
#define BARSLOT 64       // u32 per barrier slot (256 B -> no line sharing)
#define NPHASE 4
#define NSLOT 65         // per phase: 32 arrival + 32 release + 1 root

__device__ __forceinline__ ushort f2bf(float f) {
  uint u = __float_as_uint(f);
  return (ushort)((u + 0x7FFFu + ((u >> 16) & 1u)) >> 16);
}
__device__ __forceinline__ float bf2f(ushort u) {
  return __uint_as_float((uint)u << 16);
}

// ---------------------------------------------------------------------------
// L2-BYPASS STORES (sc0 sc1 = write-through past L1+L2 to IF/L3; no dirty L2
// lines). Producers use these for ALL cross-phase data; consumers use normal
// cached loads (first touch in consumer phase -> no stale line can exist).
//
// STATS COHERENCE NOTE (R5 post-mortem): stats are produced by device-scope
// atomicAdd (executes at the IF coherence point, allocates no L1/L2 line —
// required for the cross-XCD sum to be correct, which it observably is).
// No block reads a stats buffer before its consuming phase, and each phase
// reads a distinct buffer -> first-touch-after-barrier -> PLAIN CACHED loads
// are safe. The previous agent-scope atomic loads caused 4.2M coherence-point
// requests per BN phase (1024 blk x 64 lanes x 64 words) — the R5 bottleneck.
// ---------------------------------------------------------------------------
__device__ __forceinline__ void st_b128_sys(void* p, ushort8 v) {
  asm volatile("global_store_dwordx4 %0, %1, off sc0 sc1" :: "v"(p), "v"(v) : "memory");
}
__device__ __forceinline__ void st_b64_sys(void* p, uint2v v) {
  asm volatile("global_store_dwordx2 %0, %1, off sc0 sc1" :: "v"(p), "v"(v) : "memory");
}
__device__ __forceinline__ void st_b32_sys(void* p, float v) {
  asm volatile("global_store_dword %0, %1, off sc0 sc1" :: "v"(p), "v"(v) : "memory");
}
__device__ __forceinline__ void st_b16_sys(void* p, ushort v) {
  unsigned d = v;
  asm volatile("global_store_short %0, %1, off sc0 sc1" :: "v"(p), "v"(d) : "memory");
}

// ---------------------------------------------------------------------------
// LDS union: max member = conv (36,384 B) -> with __launch_bounds__(256,4)
// 4 blocks/CU (145.5 KB LDS/CU), 1024 co-resident blocks.
// ---------------------------------------------------------------------------
union __align__(16) SMem {
  struct { ushort T[64][72]; } prep;                                 //  9,216 B
  struct { float xs[64]; float aggT[4][5][72]; float aggC[64][8];
           float w1s[8], b1s[4], w2s[256], b2s[64];
           float rs[4][64], rss[4][64]; } edge;                      // ~11,424 B
  struct { ushort As[64][200]; ushort Yt[66][72];
           float aco[64], bco[64], cbs[64], ldsS[64], ldsSS[64]; } conv; // 36,384 B
  struct { ushort Ys[32][72]; ushort Ws[64][72];
           float a3s[64], b3s[64]; } mlp;                            // 14,336 B
  struct { ushort h1s[16][264]; ushort h2s[16][264]; } tail;         // 16,896 B
};

// ---------------------------------------------------------------------------
// Software grid barrier v3 (unchanged from R5): zero cache ops + bounded
// poll fan-in (max 32 pollers/address). Stale counters fall through;
// no deadlock possible.
// ---------------------------------------------------------------------------
__device__ __forceinline__ void gbar(unsigned* bar, int phase, int bid,
                                     int nblk, int tid)
{
  asm volatile("s_waitcnt vmcnt(0)" ::: "memory");
  __syncthreads();
  if (tid == 0) {
    const int lf = bid & 31;
    unsigned* leaf = bar + (size_t)(phase * NSLOT + lf) * BARSLOT;
    unsigned* rls  = bar + (size_t)(phase * NSLOT + 32 + lf) * BARSLOT;
    unsigned* root = bar + (size_t)(phase * NSLOT + 64) * BARSLOT;
    const unsigned leafcnt = (unsigned)((nblk + 31 - lf) >> 5);
    const unsigned nleaf = (unsigned)(nblk < 32 ? nblk : 32);
    unsigned old = __hip_atomic_fetch_add(leaf, 1u, __ATOMIC_RELAXED,
                                          __HIP_MEMORY_SCOPE_AGENT);
    if (old >= leafcnt - 1) {
      __hip_atomic_fetch_add(root, 1u, __ATOMIC_RELAXED,
                             __HIP_MEMORY_SCOPE_AGENT);
      while (__hip_atomic_load(root, __ATOMIC_RELAXED,
                               __HIP_MEMORY_SCOPE_AGENT) < nleaf)
        __builtin_amdgcn_s_sleep(2);
      __hip_atomic_store(rls, 1u, __ATOMIC_RELAXED,
                         __HIP_MEMORY_SCOPE_AGENT);
    } else {
      while (__hip_atomic_load(rls, __ATOMIC_RELAXED,
                               __HIP_MEMORY_SCOPE_AGENT) == 0u)
        __builtin_amdgcn_s_sleep(8);
    }
  }
  __syncthreads();
}

// ---------------------------------------------------------------------------
// phase 0a: weight preprocessing (items 0..416). Outputs via bypass stores.
// ---------------------------------------------------------------------------
__device__ __forceinline__ void prep_body(
    SMem& sm, const int bb, const int tid,
    const float* __restrict__ wm1, const float* __restrict__ wm2,
    const float* __restrict__ wm3, const float* __restrict__ wp,
    const float* __restrict__ c2w, const float* __restrict__ c3w,
    ushort* __restrict__ wbf1t, ushort* __restrict__ wbf2t,
    ushort* __restrict__ wbf3t, ushort* __restrict__ wptbf,
    ushort* __restrict__ cwt2, ushort* __restrict__ cwt3)
{
  if (bb < 256) {
    auto& T = sm.prep.T;
    const int kc = bb >> 2, n0 = (bb & 3) << 6;
    const int kk = tid >> 2, np = (tid & 3) << 4;
    const float* srow = wm1 + (((size_t)(kk << 6) + kc) << 8) + n0 + np;
#pragma unroll
    for (int i = 0; i < 4; ++i) {
      const float4 v = *(const float4*)(srow + (i << 2));
      const int n = np + (i << 2);
      T[n + 0][kk] = f2bf(v.x); T[n + 1][kk] = f2bf(v.y);
      T[n + 2][kk] = f2bf(v.z); T[n + 3][kk] = f2bf(v.w);
    }
    __syncthreads();
    ushort* dst = wbf1t + ((size_t)kc << 14) + (n0 << 6);
    const int nl = tid >> 2, qk = (tid & 3) << 4;
    st_b128_sys(dst + (nl << 6) + qk, *(ushort8*)&T[nl][qk]);
    st_b128_sys(dst + (nl << 6) + qk + 8, *(ushort8*)&T[nl][qk + 8]);
    return;
  }
  if (bb < 320) {
    const int base = (((bb - 256) << 8) + tid) << 3;
    const int m = base >> 16;
    const int rem = base & 65535;
    const int kc = rem >> 14, within = rem & 16383;
    const int n = within >> 6, kk0 = within & 63;
    const float* src = m ? wm3 : wm2;
    ushort* dst = m ? wbf3t : wbf2t;
    ushort tmp[8];
#pragma unroll
    for (int j = 0; j < 8; ++j)
      tmp[j] = f2bf(src[(((kc << 6) | (kk0 + j)) << 8) + n]);
    st_b128_sys(&dst[rem], *(ushort8*)&tmp[0]);
    return;
  }
  if (bb == 320) {
    const int a = tid & 15, k0 = (tid >> 4) << 4;
    ushort tmp[16];
#pragma unroll
    for (int j = 0; j < 16; ++j) tmp[j] = f2bf(wp[((k0 + j) << 4) + a]);
    st_b128_sys(&wptbf[(a << 8) + k0], *(ushort8*)&tmp[0]);
    st_b128_sys(&wptbf[(a << 8) + k0 + 8], *(ushort8*)&tmp[8]);
    return;
  }
  // items 321..416: conv weights [o][c][kk] -> bf16 [o][kk*64+c]
  const int flat = (bb - 321) * 256 + tid;   // 0..24575
  const int m = flat >= 12288;
  const int idx = flat - (m ? 12288 : 0);
  const float* src = m ? c3w : c2w;
  ushort* dst = m ? cwt3 : cwt2;
  const int o = idx / 192, rem = idx - o * 192;
  const int kk = rem >> 6, cc = rem & 63;
  st_b16_sys(&dst[idx], f2bf(src[o * 192 + cc * 3 + kk]));
}

// ---------------------------------------------------------------------------
// phase 0b: EdgeConv for graph b. out0 via bypass stores; stats via atomics.
// ---------------------------------------------------------------------------
__device__ __forceinline__ void edge_body(
    SMem& sm, const int b, const int tid,
    const float* __restrict__ x, const int* __restrict__ ei,
    const float* __restrict__ w1, const float* __restrict__ b1,
    const float* __restrict__ w2, const float* __restrict__ b2,
    ushort* __restrict__ out0, float* __restrict__ stats1)
{
  auto& E = sm.edge;
  const int w = tid >> 6;
  __syncthreads();                       // protect LDS union vs prior phase
  if (tid < 8) E.w1s[tid] = w1[tid];
  if (tid < 4) E.b1s[tid] = b1[tid];
  if (tid < 64) { E.xs[tid] = x[(b << 6) + tid]; E.b2s[tid] = b2[tid]; }
  E.w2s[tid] = w2[tid];
  for (int i = tid; i < 1440; i += 256) (&E.aggT[0][0][0])[i] = 0.f;
  __syncthreads();

  const int e0 = b * EPG;
  const int4 s4 = ((const int4*)(ei + e0))[tid];
  const int4 d4 = ((const int4*)(ei + NEDGE + e0))[tid];
  float* agw = &E.aggT[w][0][0];
  const int sls[4] = {s4.x & 63, s4.y & 63, s4.z & 63, s4.w & 63};
  const int dls[4] = {d4.x & 63, d4.y & 63, d4.z & 63, d4.w & 63};
#pragma unroll
  for (int e = 0; e < 4; ++e) {
    const int dl = dls[e];
    const float xi = E.xs[dl];
    const float dx = E.xs[sls[e]] - xi;
#pragma unroll
    for (int j = 0; j < 4; ++j) {
      float h = fmaxf(fmaf(xi, E.w1s[j], fmaf(dx, E.w1s[4 + j], E.b1s[j])), 0.f);
      atomicAdd(&agw[j * 72 + dl], h);
    }
    atomicAdd(&agw[4 * 72 + dl], 1.0f);
  }
  __syncthreads();

  if (tid < 64) {
    const int n = tid;
    const float a0 = E.aggT[0][0][n] + E.aggT[1][0][n] + E.aggT[2][0][n] + E.aggT[3][0][n];
    const float a1 = E.aggT[0][1][n] + E.aggT[1][1][n] + E.aggT[2][1][n] + E.aggT[3][1][n];
    const float a2 = E.aggT[0][2][n] + E.aggT[1][2][n] + E.aggT[2][2][n] + E.aggT[3][2][n];
    const float a3v = E.aggT[0][3][n] + E.aggT[1][3][n] + E.aggT[2][3][n] + E.aggT[3][3][n];
    const float dg = E.aggT[0][4][n] + E.aggT[1][4][n] + E.aggT[2][4][n] + E.aggT[3][4][n];
    *(float4*)&E.aggC[n][0] = make_float4(a0, a1, a2, a3v);
    E.aggC[n][4] = dg;
  }
  __syncthreads();

  const int c = tid & 63, qq = tid >> 6;
  const float wc0 = E.w2s[c], wc1 = E.w2s[64 + c], wc2 = E.w2s[128 + c], wc3 = E.w2s[192 + c];
  const float b2c = E.b2s[c];
  float s = 0.f, ss = 0.f;
  for (int n = qq; n < 64; n += 4) {
    const float4 a = *(const float4*)&E.aggC[n][0];
    const float dg = E.aggC[n][4];
    float v = a.x * wc0 + a.y * wc1 + a.z * wc2 + a.w * wc3 + dg * b2c;
    st_b16_sys(&out0[(size_t)(((b << 6) + n) << 6) + c], f2bf(v));
    s += v; ss += v * v;
  }
  E.rs[qq][c] = s; E.rss[qq][c] = ss;
  __syncthreads();
  if (tid < 64) {
    float* dst = stats1 + ((b & (REP - 1)) << 7);
    atomicAdd(&dst[tid], E.rs[0][tid] + E.rs[1][tid] + E.rs[2][tid] + E.rs[3][tid]);
    atomicAdd(&dst[64 + tid], E.rss[0][tid] + E.rss[1][tid] + E.rss[2][tid] + E.rss[3][tid]);
  }
}

// ---------------------------------------------------------------------------
// phases 1/2: BN + conv1d-as-MFMA. Stats via PLAIN CACHED loads (first touch
// after barrier; atomic producers left no cache lines -> safe, and L2-hit
// for all but the first toucher per XCD). Output via bypass stores.
// ---------------------------------------------------------------------------
__device__ __forceinline__ void conv_body(
    SMem& sm, const int b, const int tid,
    const ushort* __restrict__ in, const float* __restrict__ stats_in,
    const float* __restrict__ gamma, const float* __restrict__ beta,
    const ushort* __restrict__ cwt, const float* __restrict__ cb,
    ushort* __restrict__ out, float* __restrict__ stats_out)
{
  auto& C = sm.conv;
  __syncthreads();                       // protect LDS union vs prior phase
  if (tid < 64) {
    float smv = 0.f, sq = 0.f;
#pragma unroll 8
    for (int r = 0; r < REP; ++r) {
      smv += stats_in[(r << 7) + tid];
      sq += stats_in[(r << 7) + 64 + tid];
    }
    const float mean = smv * (1.0f / CNTF);
    const float var = sq * (1.0f / CNTF) - mean * mean;
    const float a = gamma[tid] * rsqrtf(var + EPSV);
    C.aco[tid] = a;
    C.bco[tid] = beta[tid] - mean * a;
    C.cbs[tid] = cb[tid];
    C.Yt[0][tid] = 0;
    C.Yt[65][tid] = 0;
  }
  __syncthreads();

  const size_t base = (size_t)b << 12;
  {
    const int lr = tid >> 2, p = (tid & 3) << 4;
    const ushort8 r0 = *(const ushort8*)&in[base + (lr << 6) + p];
    const ushort8 r1 = *(const ushort8*)&in[base + (lr << 6) + p + 8];
    ushort tmp[16];
#pragma unroll
    for (int j = 0; j < 8; ++j)
      tmp[j] = f2bf(fmaxf(fmaf(C.aco[p + j], bf2f(r0[j]), C.bco[p + j]), 0.f));
#pragma unroll
    for (int j = 0; j < 8; ++j)
      tmp[8 + j] = f2bf(fmaxf(fmaf(C.aco[p + 8 + j], bf2f(r1[j]), C.bco[p + 8 + j]), 0.f));
    *(ushort8*)&C.Yt[lr + 1][p] = *(ushort8*)&tmp[0];
    *(ushort8*)&C.Yt[lr + 1][p + 8] = *(ushort8*)&tmp[8];
  }
  {
    const ushort8* gw = (const ushort8*)cwt;
#pragma unroll
    for (int i = 0; i < 6; ++i) {
      const int e8 = (i << 8) + tid;
      const int o = e8 / 24, k8 = (e8 - o * 24) << 3;
      *(ushort8*)&C.As[o][k8] = gw[e8];
    }
  }
  __syncthreads();

  const int lane = tid & 63, w = tid >> 6;
  const int lm = lane & 15, q = lane >> 4;
  f32x4 acc[4];
#pragma unroll
  for (int nt = 0; nt < 4; ++nt) acc[nt] = (f32x4){0.f, 0.f, 0.f, 0.f};

#pragma unroll
  for (int kk = 0; kk < 3; ++kk) {
#pragma unroll
    for (int ks = 0; ks < 2; ++ks) {
      const short8 af = *(const short8*)&C.As[(w << 4) + lm][(kk << 6) + (ks << 5) + (q << 3)];
#pragma unroll
      for (int nt = 0; nt < 4; ++nt) {
        const short8 bfr = *(const short8*)&C.Yt[(nt << 4) + lm + kk][(ks << 5) + (q << 3)];
        acc[nt] = __builtin_amdgcn_mfma_f32_16x16x32_bf16(af, bfr, acc[nt], 0, 0, 0);
      }
    }
  }

  const int obase = (w << 4) + (q << 2);
  const float4 cb4 = *(const float4*)&C.cbs[obase];
  float s[4] = {0.f, 0.f, 0.f, 0.f}, ss[4] = {0.f, 0.f, 0.f, 0.f};
#pragma unroll
  for (int nt = 0; nt < 4; ++nt) {
    const int l = (nt << 4) + lm;
    float4 v = make_float4(acc[nt][0] + cb4.x, acc[nt][1] + cb4.y,
                           acc[nt][2] + cb4.z, acc[nt][3] + cb4.w);
    const uint u0 = (uint)f2bf(v.x) | ((uint)f2bf(v.y) << 16);
    const uint u1 = (uint)f2bf(v.z) | ((uint)f2bf(v.w) << 16);
    uint2v pk; pk.x = u0; pk.y = u1;
    st_b64_sys(&out[base + (l << 6) + obase], pk);
    s[0] += v.x; ss[0] += v.x * v.x;
    s[1] += v.y; ss[1] += v.y * v.y;
    s[2] += v.z; ss[2] += v.z * v.z;
    s[3] += v.w; ss[3] += v.w * v.w;
  }
#pragma unroll
  for (int i = 0; i < 4; ++i) {
#pragma unroll
    for (int off = 1; off < 16; off <<= 1) {
      s[i] += __shfl_xor(s[i], off);
      ss[i] += __shfl_xor(ss[i], off);
    }
    if (lm == 0) { C.ldsS[obase + i] = s[i]; C.ldsSS[obase + i] = ss[i]; }
  }
  __syncthreads();
  if (tid < 64) {
    float* dst = stats_out + ((b & (REP - 1)) << 7);
    atomicAdd(&dst[tid], C.ldsS[tid]);
    atomicAdd(&dst[64 + tid], C.ldsSS[tid]);
  }
}

// ---------------------------------------------------------------------------
// phase 3: mlp1, 1024 items: 32 M x 4 N x 8 K-splits. Stats cached (same
// safety argument). h1part via bypass.
// ---------------------------------------------------------------------------
__device__ __forceinline__ void mlp_body(
    SMem& sm, const int bid, const int tid,
    const ushort* __restrict__ z3, const float* __restrict__ stats3,
    const float* __restrict__ g3, const float* __restrict__ be3,
    const ushort* __restrict__ wbf1t, float* __restrict__ h1part)
{
  auto& M = sm.mlp;
  const int bz = bid >> 7;          // 0..7  K-split
  const int bx = (bid >> 2) & 31;   // 0..31 M-tile (32 graphs)
  const int by = bid & 3;           // 0..3  N-tile (64)
  __syncthreads();                  // protect LDS union vs prior phase
  if (tid < 64) {
    float sme = 0.f, sq = 0.f;
#pragma unroll 8
    for (int r = 0; r < REP; ++r) {
      sme += stats3[(r << 7) + tid];
      sq += stats3[(r << 7) + 64 + tid];
    }
    const float mean = sme * (1.0f / CNTF);
    const float var = sq * (1.0f / CNTF) - mean * mean;
    const float a = g3[tid] * rsqrtf(var + EPSV);
    M.a3s[tid] = a;
    M.b3s[tid] = be3[tid] - mean * a;
  }
  __syncthreads();

  const int lane = tid & 63, w = tid >> 6;
  const int lm = lane & 15, q = lane >> 4;
  const int wr = w >> 1, wc = w & 1;            // wave -> (M half, N half)
  const int gy = tid >> 3, py = (tid & 7) << 3; // Ys staging: 32 rows x 8
  const int nn = tid >> 2, pw = tid & 3;        // Ws staging: 64 rows x 16
  const int g0 = bx << 5, n0 = by << 6;

  f32x4 acc[2];
#pragma unroll
  for (int nt = 0; nt < 2; ++nt) acc[nt] = (f32x4){0.f, 0.f, 0.f, 0.f};

  const size_t ybase = ((size_t)(g0 + gy) << 12);

#pragma unroll 1
  for (int ck = 0; ck < 8; ++ck) {
    const int kc = (bz << 9) + (ck << 6);
    if (ck) __syncthreads();
    // --- stage Ys: BN3+ReLU on bf16 z3 (channel = within-chunk index)
    {
      const ushort8 r0 = *(const ushort8*)(z3 + ybase + kc + py);
      ushort tmp[8];
#pragma unroll
      for (int j = 0; j < 8; ++j)
        tmp[j] = f2bf(fmaxf(fmaf(M.a3s[py + j], bf2f(r0[j]), M.b3s[py + j]), 0.f));
      *(ushort8*)&M.Ys[gy][py] = *(ushort8*)&tmp[0];
    }
    // --- stage Ws: straight copies from chunk-major wbf1t
    {
      const ushort8* gw = (const ushort8*)(wbf1t + ((size_t)((bz << 3) + ck) << 14) + ((size_t)n0 << 6));
      *(ushort8*)&M.Ws[nn][pw << 4] = gw[(nn << 3) + (pw << 1)];
      *(ushort8*)&M.Ws[nn][(pw << 4) + 8] = gw[(nn << 3) + (pw << 1) + 1];
    }
    __syncthreads();
#pragma unroll
    for (int ks = 0; ks < 2; ++ks) {
      const short8 af = *(const short8*)&M.Ys[(wr << 4) + lm][(ks << 5) + (q << 3)];
#pragma unroll
      for (int nt = 0; nt < 2; ++nt) {
        const short8 bfr = *(const short8*)&M.Ws[(wc << 5) + (nt << 4) + lm][(ks << 5) + (q << 3)];
        acc[nt] = __builtin_amdgcn_mfma_f32_16x16x32_bf16(af, bfr, acc[nt], 0, 0, 0);
      }
    }
  }

  float* dst0 = h1part + ((size_t)bz << 18);
  const int gout = g0 + (wr << 4) + (q << 2);
#pragma unroll
  for (int nt = 0; nt < 2; ++nt) {
    const int col = n0 + (wc << 5) + (nt << 4) + lm;
#pragma unroll
    for (int i = 0; i < 4; ++i)
      st_b32_sys(&dst0[((size_t)(gout + i) << 8) + col], acc[nt][i]);
  }
}

// ---------------------------------------------------------------------------
// phase 4: tail (items 0..63). h1part read = first touch (cached ok).
// ---------------------------------------------------------------------------
__device__ __forceinline__ void tail_body(
    SMem& sm, const int bid, const int tid,
    const float* __restrict__ h1part, const float* __restrict__ bm1,
    const ushort* __restrict__ wbf2t, const float* __restrict__ bm2,
    const ushort* __restrict__ wbf3t, const float* __restrict__ bm3,
    const ushort* __restrict__ wptbf, const float* __restrict__ bp,
    float* __restrict__ out)
{
  auto& T = sm.tail;
  const int g0 = bid << 4;
  const int lane = tid & 63, w = tid >> 6;
  const int lm = lane & 15, q = lane >> 4;
  const int gr = q << 2;

  __syncthreads();                  // protect LDS union vs prior phase
  {
    const int r = tid >> 4, c0 = (tid & 15) << 4;
    const float* srcb = h1part + ((size_t)(g0 + r) << 8) + c0;
#pragma unroll
    for (int i = 0; i < 4; ++i) {
      float4 vs = *(const float4*)(bm1 + c0 + (i << 2));
#pragma unroll
      for (int bz = 0; bz < 8; ++bz) {
        const float4 p = *(const float4*)(srcb + ((size_t)bz << 18) + (i << 2));
        vs.x += p.x; vs.y += p.y; vs.z += p.z; vs.w += p.w;
      }
      *(ushort4*)&T.h1s[r][c0 + (i << 2)] = make_ushort4(
          f2bf(fmaxf(vs.x, 0.f)), f2bf(fmaxf(vs.y, 0.f)),
          f2bf(fmaxf(vs.z, 0.f)), f2bf(fmaxf(vs.w, 0.f)));
    }
  }
  __syncthreads();

  // ---- GEMM2 (B direct from global)
  f32x4 acc[4];
#pragma unroll
  for (int nt = 0; nt < 4; ++nt) acc[nt] = (f32x4){0.f, 0.f, 0.f, 0.f};
#pragma unroll
  for (int ck = 0; ck < 4; ++ck) {
#pragma unroll
    for (int ks = 0; ks < 2; ++ks) {
      const short8 af = *(const short8*)&T.h1s[lm][(ck << 6) + (ks << 5) + (q << 3)];
#pragma unroll
      for (int nt = 0; nt < 4; ++nt) {
        const int n = (w << 6) + (nt << 4) + lm;
        const short8 bfr = *(const short8*)&wbf2t[((size_t)ck << 14) + (n << 6) + (ks << 5) + (q << 3)];
        acc[nt] = __builtin_amdgcn_mfma_f32_16x16x32_bf16(af, bfr, acc[nt], 0, 0, 0);
      }
    }
  }
#pragma unroll
  for (int nt = 0; nt < 4; ++nt) {
    const int col = (w << 6) + (nt << 4) + lm;
    const float bv = bm2[col];
#pragma unroll
    for (int i = 0; i < 4; ++i)
      T.h2s[gr + i][col] = f2bf(fmaxf(acc[nt][i] + bv, 0.f));
  }
  __syncthreads();

  // ---- GEMM3 (B direct from global)
  f32x4 acc2[4];
#pragma unroll
  for (int nt = 0; nt < 4; ++nt) acc2[nt] = (f32x4){0.f, 0.f, 0.f, 0.f};
#pragma unroll
  for (int ck = 0; ck < 4; ++ck) {
#pragma unroll
    for (int ks = 0; ks < 2; ++ks) {
      const short8 af = *(const short8*)&T.h2s[lm][(ck << 6) + (ks << 5) + (q << 3)];
#pragma unroll
      for (int nt = 0; nt < 4; ++nt) {
        const int n = (w << 6) + (nt << 4) + lm;
        const short8 bfr = *(const short8*)&wbf3t[((size_t)ck << 14) + (n << 6) + (ks << 5) + (q << 3)];
        acc2[nt] = __builtin_amdgcn_mfma_f32_16x16x32_bf16(af, bfr, acc2[nt], 0, 0, 0);
      }
    }
  }
  __syncthreads();                  // all h2s reads done before overwrite
#pragma unroll
  for (int nt = 0; nt < 4; ++nt) {
    const int col = (w << 6) + (nt << 4) + lm;
    const float bv = bm3[col];
#pragma unroll
    for (int i = 0; i < 4; ++i)
      T.h2s[gr + i][col] = f2bf(fmaxf(acc2[nt][i] + bv, 0.f));
  }
  __syncthreads();

  if (w == 0) {
    f32x4 lacc = (f32x4){0.f, 0.f, 0.f, 0.f};
#pragma unroll
    for (int ks = 0; ks < 8; ++ks) {
      const short8 af = *(const short8*)&T.h2s[lm][(ks << 5) + (q << 3)];
      const short8 bfr = *(const short8*)&wptbf[(lm << 8) + (ks << 5) + (q << 3)];
      lacc = __builtin_amdgcn_mfma_f32_16x16x32_bf16(af, bfr, lacc, 0, 0, 0);
    }
    const float bpv = bp[lm];
    float lg[4], mx[4], se[4];
#pragma unroll
    for (int i = 0; i < 4; ++i) {
      lg[i] = lacc[i] + bpv;
      float m = lg[i];
#pragma unroll
      for (int off = 1; off < 16; off <<= 1) m = fmaxf(m, __shfl_xor(m, off));
      mx[i] = m;
      float e = expf(lg[i] - m);
#pragma unroll
      for (int off = 1; off < 16; off <<= 1) e += __shfl_xor(e, off);
      se[i] = e;
    }
#pragma unroll
    for (int i = 0; i < 4; ++i)
      out[((g0 + gr + i) << 4) + lm] = (lg[i] - mx[i]) - logf(se[i]);
  }
}

// ---------------------------------------------------------------------------
// Fused persistent kernel, fence-free cross-phase coherence + tree barrier.
// ---------------------------------------------------------------------------
__global__ __launch_bounds__(256, 4) void k_all(
    const float* __restrict__ x, const int* __restrict__ ei,
    const float* __restrict__ w1, const float* __restrict__ b1,
    const float* __restrict__ w2, const float* __restrict__ b2,
    const float* __restrict__ c2w, const float* __restrict__ c2b,
    const float* __restrict__ c3w, const float* __restrict__ c3b,
    const float* __restrict__ g1, const float* __restrict__ be1,
    const float* __restrict__ g2, const float* __restrict__ be2,
    const float* __restrict__ g3, const float* __restrict__ be3,
    const float* __restrict__ wm1, const float* __restrict__ bm1,
    const float* __restrict__ wm2, const float* __restrict__ bm2,
    const float* __restrict__ wm3, const float* __restrict__ bm3,
    const float* __restrict__ wp, const float* __restrict__ bp,
    ushort* __restrict__ ubuf0, ushort* __restrict__ ubuf1,
    ushort* __restrict__ ubuf2, float* __restrict__ h1part,
    ushort* __restrict__ wbf1t, ushort* __restrict__ wbf2t,
    ushort* __restrict__ wbf3t, ushort* __restrict__ wptbf,
    ushort* __restrict__ cwt2, ushort* __restrict__ cwt3,
    float* __restrict__ stats, unsigned* __restrict__ bar,
    float* __restrict__ out, int nblk)
{
  __shared__ SMem sm;
  const int tid = threadIdx.x;
  const int bid = blockIdx.x;
  float* stats1 = stats;
  float* stats2 = stats + REP * 128;
  float* stats3 = stats + 2 * REP * 128;

  // phase 0: weight prep (items 0..416) + edge conv (items 417..1440)
  for (int it = bid; it < 417 + NB; it += nblk) {
    if (it < 417)
      prep_body(sm, it, tid, wm1, wm2, wm3, wp, c2w, c3w,
                wbf1t, wbf2t, wbf3t, wptbf, cwt2, cwt3);
    else
      edge_body(sm, it - 417, tid, x, ei, w1, b1, w2, b2, ubuf0, stats1);
  }
  gbar(bar, 0, bid, nblk, tid);
  // phase 1: BN1 + conv2  (ubuf0 -> ubuf1)
  for (int it = bid; it < NB; it += nblk)
    conv_body(sm, it, tid, ubuf0, stats1, g1, be1, cwt2, c2b, ubuf1, stats2);
  gbar(bar, 1, bid, nblk, tid);
  // phase 2: BN2 + conv3  (ubuf1 -> ubuf2, fresh buffer)
  for (int it = bid; it < NB; it += nblk)
    conv_body(sm, it, tid, ubuf1, stats2, g2, be2, cwt3, c3b, ubuf2, stats3);
  gbar(bar, 2, bid, nblk, tid);
  // phase 3: BN3 + GEMM1 split-K partials (ubuf2 -> h1part)
  for (int it = bid; it < NB; it += nblk)
    mlp_body(sm, it, tid, ubuf2, stats3, g3, be3, wbf1t, h1part);
  gbar(bar, 3, bid, nblk, tid);
  // phase 4: tail (items 0..63)
  for (int it = bid; it < 64; it += nblk)
    tail_body(sm, it, tid, h1part, bm1, wbf2t, bm2, wbf3t, bm3, wptbf, bp, out);
}

// ===========================================================================
// Fallback path: verified multi-kernel chain (used only if occupancy query
// fails). Kernel boundaries provide coherence; bypass stores remain correct.
// ===========================================================================
__global__ __launch_bounds__(256) void k_prepw(
    const float* __restrict__ wm1, const float* __restrict__ wm2,
    const float* __restrict__ wm3, const float* __restrict__ wp,
    const float* __restrict__ c2w, const float* __restrict__ c3w,
    ushort* __restrict__ wbf1t, ushort* __restrict__ wbf2t,
    ushort* __restrict__ wbf3t, ushort* __restrict__ wptbf,
    ushort* __restrict__ cwt2, ushort* __restrict__ cwt3,
    float* __restrict__ stats)
{
  __shared__ SMem sm;
  const int tid = threadIdx.x;
  const int bb = blockIdx.x;
  if (bb == 417) {
    float4 z4 = make_float4(0.f, 0.f, 0.f, 0.f);
#pragma unroll
    for (int i = 0; i < 12; ++i) ((float4*)stats)[(i << 8) + tid] = z4;
    return;
  }
  prep_body(sm, bb, tid, wm1, wm2, wm3, wp, c2w, c3w,
            wbf1t, wbf2t, wbf3t, wptbf, cwt2, cwt3);
}

__global__ __launch_bounds__(256) void k_edge(
    const float* __restrict__ x, const int* __restrict__ ei,
    const float* __restrict__ w1, const float* __restrict__ b1,
    const float* __restrict__ w2, const float* __restrict__ b2,
    ushort* __restrict__ out0, float* __restrict__ stats1)
{
  __shared__ SMem sm;
  edge_body(sm, blockIdx.x, threadIdx.x, x, ei, w1, b1, w2, b2, out0, stats1);
}

__global__ __launch_bounds__(256) void k_convm(
    const ushort* __restrict__ in, const float* __restrict__ stats_in,
    const float* __restrict__ gamma, const float* __restrict__ beta,
    const ushort* __restrict__ cwt, const float* __restrict__ cb,
    ushort* __restrict__ out, float* __restrict__ stats_out)
{
  __shared__ SMem sm;
  conv_body(sm, blockIdx.x, threadIdx.x, in, stats_in, gamma, beta, cwt, cb,
            out, stats_out);
}

__global__ __launch_bounds__(256) void k_mlp1f(
    const ushort* __restrict__ z3, const float* __restrict__ stats3,
    const float* __restrict__ g3, const float* __restrict__ be3,
    const ushort* __restrict__ wbf1t, float* __restrict__ h1part)
{
  __shared__ SMem sm;
  mlp_body(sm, blockIdx.x, threadIdx.x, z3, stats3, g3, be3, wbf1t, h1part);
}

__global__ __launch_bounds__(256) void k_tailf(
    const float* __restrict__ h1part, const float* __restrict__ bm1,
    const ushort* __restrict__ wbf2t, const float* __restrict__ bm2,
    const ushort* __restrict__ wbf3t, const float* __restrict__ bm3,
    const ushort* __restrict__ wptbf, const float* __restrict__ bp,
    float* __restrict__ out)
{
  __shared__ SMem sm;
  tail_body(sm, blockIdx.x, threadIdx.x, h1part, bm1, wbf2t, bm2, wbf3t, bm3,
            wptbf, bp, out);
}

// ---------------------------------------------------------------------------
extern "C" void kernel_launch(void* const* d_in, const int* in_sizes, int n_in,
                              void* d_out, int out_size, void* d_ws, size_t ws_size,
                              hipStream_t stream)
{
  const float* x   = (const float*)d_in[0];
  const int*   ei  = (const int*)d_in[1];
  const float* w1  = (const float*)d_in[2];
  const float* b1  = (const float*)d_in[3];
  const float* w2  = (const float*)d_in[4];
  const float* b2  = (const float*)d_in[5];
  const float* c2w = (const float*)d_in[6];
  const float* c2b = (const float*)d_in[7];
  const float* c3w = (const float*)d_in[8];
  const float* c3b = (const float*)d_in[9];
  const float* g1  = (const float*)d_in[10];
  const float* be1 = (const float*)d_in[11];
  const float* g2  = (const float*)d_in[12];
  const float* be2 = (const float*)d_in[13];
  const float* g3  = (const float*)d_in[14];
  const float* be3 = (const float*)d_in[15];
  const float* wm1 = (const float*)d_in[16];
  const float* bm1 = (const float*)d_in[17];
  const float* wm2 = (const float*)d_in[18];
  const float* bm2 = (const float*)d_in[19];
  const float* wm3 = (const float*)d_in[20];
  const float* bm3 = (const float*)d_in[21];
  const float* wp  = (const float*)d_in[22];
  const float* bp  = (const float*)d_in[23];

  char* ws = (char*)d_ws;
  ushort* ubuf0 = (ushort*)ws;                          // 8 MiB: out0 (bf16)
  ushort* ubuf1 = (ushort*)(ws + ((size_t)8 << 20));    // 8 MiB: z2 (bf16)
  float*  h1part = (float*)(ws + ((size_t)16 << 20));   // 8 MiB fp32 partials
  ushort* wbf1t = (ushort*)(ws + ((size_t)24 << 20));   // 2 MiB bf16 wm1^T
  ushort* wbf2t = (ushort*)(ws + ((size_t)26 << 20));               // 128 KiB
  ushort* wbf3t = (ushort*)(ws + ((size_t)26 << 20) + (128 << 10)); // 128 KiB
  ushort* wptbf = (ushort*)(ws + ((size_t)26 << 20) + (256 << 10)); // 8 KiB
  float* stats = (float*)(ws + ((size_t)27 << 20));     // 48 KiB [3][REP][128]
  float* stats1 = stats;
  float* stats2 = stats + REP * 128;
  float* stats3 = stats + 2 * REP * 128;
  unsigned* bar = (unsigned*)(ws + ((size_t)27 << 20) + 49152); // 65 KiB barriers
  ushort* ubuf2 = (ushort*)(ws + ((size_t)32 << 20));   // 8 MiB: z3 (fresh buffer)
  ushort* cwt2 = (ushort*)d_out;          // d_out scratch, overwritten at tail
  ushort* cwt3 = (ushort*)d_out + 12288;
  float* outp = (float*)d_out;

  // Size the persistent grid once: guaranteed-co-resident block count.
  static int nblk_cached = -1;
  if (nblk_cached < 0) {
    int ncu = 0, maxb = 0;
    hipError_t e1 = hipDeviceGetAttribute(&ncu, hipDeviceAttributeMultiprocessorCount, 0);
    hipError_t e2 = hipOccupancyMaxActiveBlocksPerMultiprocessor(&maxb, k_all, 256, 0);
    if (e1 == hipSuccess && e2 == hipSuccess && ncu > 0 && maxb > 0) {
      long t = (long)ncu * (long)maxb;
      nblk_cached = (int)(t < MAXGRID ? t : MAXGRID);
    } else {
      nblk_cached = 0;   // occupancy unknown -> verified multi-kernel chain
    }
  }
  const int nblk = nblk_cached;

  if (nblk > 0) {
    // zero stats (48 KiB) + barrier counters (65 KiB); replayed with the graph
    hipMemsetAsync(stats, 0, 49152 + NPHASE * NSLOT * BARSLOT * 4, stream);
    k_all<<<dim3(nblk), dim3(256), 0, stream>>>(
        x, ei, w1, b1, w2, b2, c2w, c2b, c3w, c3b,
        g1, be1, g2, be2, g3, be3,
        wm1, bm1, wm2, bm2, wm3, bm3, wp, bp,
        ubuf0, ubuf1, ubuf2, h1part, wbf1t, wbf2t, wbf3t, wptbf,
        cwt2, cwt3, stats, bar, outp, nblk);
  } else {
    k_prepw<<<dim3(418), dim3(256), 0, stream>>>(
        wm1, wm2, wm3, wp, c2w, c3w,
        wbf1t, wbf2t, wbf3t, wptbf, cwt2, cwt3, stats);
    k_edge<<<dim3(NB), dim3(256), 0, stream>>>(x, ei, w1, b1, w2, b2, ubuf0, stats1);
    k_convm<<<dim3(NB), dim3(256), 0, stream>>>(ubuf0, stats1, g1, be1, cwt2, c2b, ubuf1, stats2);
    k_convm<<<dim3(NB), dim3(256), 0, stream>>>(ubuf1, stats2, g2, be2, cwt3, c3b, ubuf2, stats3);
    k_mlp1f<<<dim3(NB), dim3(256), 0, stream>>>(ubuf2, stats3, g3, be3, wbf1t, h1part);
    k_tailf<<<dim3(64), dim3(256), 0, stream>>>(h1part, bm1, wbf2t, bm2, wbf3t, bm3,
                                                wptbf, bp, outp);
  }
}

// Round 7
// 204.932 us; speedup vs baseline: 1.6526x; 1.0424x over previous
//
#include <hip/hip_runtime.h>
#include <cstdint>
#include <cstddef>

typedef __attribute__((ext_vector_type(8))) short short8;
typedef __attribute__((ext_vector_type(8))) unsigned short ushort8;
typedef __attribute__((ext_vector_type(4))) float f32x4;
typedef __attribute__((ext_vector_type(2))) unsigned int uint2v;

#define EPSV 1e-5f
#define NB 1024
#define NEDGE 1048576
#define EPG 1024
#define CNTF 65536.0f
#define REP 32           // stats replica slots (contention spreading)

__device__ __forceinline__ ushort f2bf(float f) {
  uint u = __float_as_uint(f);
  return (ushort)((u + 0x7FFFu + ((u >> 16) & 1u)) >> 16);
}
__device__ __forceinline__ float bf2f(ushort u) {
  return __uint_as_float((uint)u << 16);
}

// ---------------------------------------------------------------------------
// L2-bypass stores (sc0 sc1 = write-through to IF/L3, no dirty L2 lines).
// Used for all cross-kernel data: reduces end-of-kernel writeback drain and
// is correct across kernel boundaries (dispatch-end release + consumer
// first-touch). Validated R4-R6.
// ---------------------------------------------------------------------------
__device__ __forceinline__ void st_b128_sys(void* p, ushort8 v) {
  asm volatile("global_store_dwordx4 %0, %1, off sc0 sc1" :: "v"(p), "v"(v) : "memory");
}
__device__ __forceinline__ void st_b64_sys(void* p, uint2v v) {
  asm volatile("global_store_dwordx2 %0, %1, off sc0 sc1" :: "v"(p), "v"(v) : "memory");
}
__device__ __forceinline__ void st_b32_sys(void* p, float v) {
  asm volatile("global_store_dword %0, %1, off sc0 sc1" :: "v"(p), "v"(v) : "memory");
}
__device__ __forceinline__ void st_b16_sys(void* p, ushort v) {
  unsigned d = v;
  asm volatile("global_store_short %0, %1, off sc0 sc1" :: "v"(p), "v"(d) : "memory");
}

// ---------------------------------------------------------------------------
// Per-kernel LDS structs (R6 post-mortem: the fused kernel forced every
// phase to the 36 KB union -> 4 blocks/CU everywhere. Split kernels get
// their natural occupancy: edge 11.4 KB -> 8 blocks/CU.)
// ---------------------------------------------------------------------------
struct SPrep { ushort T[64][72]; };                                  //  9,216 B
struct SEdge { float xs[64]; float aggT[4][5][72]; float aggC[64][8];
               float w1s[8], b1s[4], w2s[256], b2s[64];
               float rs[4][64], rss[4][64]; };                       // ~11,424 B
struct SConv { ushort As[64][200]; ushort Yt[66][72];
               float aco[64], bco[64], cbs[64], ldsS[64], ldsSS[64]; }; // 36,384 B
struct SMlp  { ushort Ys[64][72]; ushort Ws[128][72];
               float a3s[64], b3s[64]; };                            // 28,160 B
struct STail { ushort h1s[16][264]; ushort h2s[16][264]; };          // 16,896 B

// ---------------------------------------------------------------------------
// prep: weight preprocessing item bb in [0,417). Outputs via bypass stores.
// ---------------------------------------------------------------------------
__device__ __forceinline__ void prep_body(
    SPrep& P, const int bb, const int tid,
    const float* __restrict__ wm1, const float* __restrict__ wm2,
    const float* __restrict__ wm3, const float* __restrict__ wp,
    const float* __restrict__ c2w, const float* __restrict__ c3w,
    ushort* __restrict__ wbf1t, ushort* __restrict__ wbf2t,
    ushort* __restrict__ wbf3t, ushort* __restrict__ wptbf,
    ushort* __restrict__ cwt2, ushort* __restrict__ cwt3)
{
  if (bb < 256) {
    auto& T = P.T;
    const int kc = bb >> 2, n0 = (bb & 3) << 6;
    const int kk = tid >> 2, np = (tid & 3) << 4;
    const float* srow = wm1 + (((size_t)(kk << 6) + kc) << 8) + n0 + np;
#pragma unroll
    for (int i = 0; i < 4; ++i) {
      const float4 v = *(const float4*)(srow + (i << 2));
      const int n = np + (i << 2);
      T[n + 0][kk] = f2bf(v.x); T[n + 1][kk] = f2bf(v.y);
      T[n + 2][kk] = f2bf(v.z); T[n + 3][kk] = f2bf(v.w);
    }
    __syncthreads();
    ushort* dst = wbf1t + ((size_t)kc << 14) + (n0 << 6);
    const int nl = tid >> 2, qk = (tid & 3) << 4;
    st_b128_sys(dst + (nl << 6) + qk, *(ushort8*)&T[nl][qk]);
    st_b128_sys(dst + (nl << 6) + qk + 8, *(ushort8*)&T[nl][qk + 8]);
    return;
  }
  if (bb < 320) {
    const int base = (((bb - 256) << 8) + tid) << 3;
    const int m = base >> 16;
    const int rem = base & 65535;
    const int kc = rem >> 14, within = rem & 16383;
    const int n = within >> 6, kk0 = within & 63;
    const float* src = m ? wm3 : wm2;
    ushort* dst = m ? wbf3t : wbf2t;
    ushort tmp[8];
#pragma unroll
    for (int j = 0; j < 8; ++j)
      tmp[j] = f2bf(src[(((kc << 6) | (kk0 + j)) << 8) + n]);
    st_b128_sys(&dst[rem], *(ushort8*)&tmp[0]);
    return;
  }
  if (bb == 320) {
    const int a = tid & 15, k0 = (tid >> 4) << 4;
    ushort tmp[16];
#pragma unroll
    for (int j = 0; j < 16; ++j) tmp[j] = f2bf(wp[((k0 + j) << 4) + a]);
    st_b128_sys(&wptbf[(a << 8) + k0], *(ushort8*)&tmp[0]);
    st_b128_sys(&wptbf[(a << 8) + k0 + 8], *(ushort8*)&tmp[8]);
    return;
  }
  // items 321..416: conv weights [o][c][kk] -> bf16 [o][kk*64+c]
  const int flat = (bb - 321) * 256 + tid;   // 0..24575
  const int m = flat >= 12288;
  const int idx = flat - (m ? 12288 : 0);
  const float* src = m ? c3w : c2w;
  ushort* dst = m ? cwt3 : cwt2;
  const int o = idx / 192, rem = idx - o * 192;
  const int kk = rem >> 6, cc = rem & 63;
  st_b16_sys(&dst[idx], f2bf(src[o * 192 + cc * 3 + kk]));
}

// ---------------------------------------------------------------------------
// edge: EdgeConv for graph b. out0 via bypass stores; stats via atomics.
// ---------------------------------------------------------------------------
__device__ __forceinline__ void edge_body(
    SEdge& E, const int b, const int tid,
    const float* __restrict__ x, const int* __restrict__ ei,
    const float* __restrict__ w1, const float* __restrict__ b1,
    const float* __restrict__ w2, const float* __restrict__ b2,
    ushort* __restrict__ out0, float* __restrict__ stats1)
{
  const int w = tid >> 6;
  if (tid < 8) E.w1s[tid] = w1[tid];
  if (tid < 4) E.b1s[tid] = b1[tid];
  if (tid < 64) { E.xs[tid] = x[(b << 6) + tid]; E.b2s[tid] = b2[tid]; }
  E.w2s[tid] = w2[tid];
  for (int i = tid; i < 1440; i += 256) (&E.aggT[0][0][0])[i] = 0.f;
  __syncthreads();

  const int e0 = b * EPG;
  const int4 s4 = ((const int4*)(ei + e0))[tid];
  const int4 d4 = ((const int4*)(ei + NEDGE + e0))[tid];
  float* agw = &E.aggT[w][0][0];
  const int sls[4] = {s4.x & 63, s4.y & 63, s4.z & 63, s4.w & 63};
  const int dls[4] = {d4.x & 63, d4.y & 63, d4.z & 63, d4.w & 63};
#pragma unroll
  for (int e = 0; e < 4; ++e) {
    const int dl = dls[e];
    const float xi = E.xs[dl];
    const float dx = E.xs[sls[e]] - xi;
#pragma unroll
    for (int j = 0; j < 4; ++j) {
      float h = fmaxf(fmaf(xi, E.w1s[j], fmaf(dx, E.w1s[4 + j], E.b1s[j])), 0.f);
      atomicAdd(&agw[j * 72 + dl], h);
    }
    atomicAdd(&agw[4 * 72 + dl], 1.0f);
  }
  __syncthreads();

  if (tid < 64) {
    const int n = tid;
    const float a0 = E.aggT[0][0][n] + E.aggT[1][0][n] + E.aggT[2][0][n] + E.aggT[3][0][n];
    const float a1 = E.aggT[0][1][n] + E.aggT[1][1][n] + E.aggT[2][1][n] + E.aggT[3][1][n];
    const float a2 = E.aggT[0][2][n] + E.aggT[1][2][n] + E.aggT[2][2][n] + E.aggT[3][2][n];
    const float a3v = E.aggT[0][3][n] + E.aggT[1][3][n] + E.aggT[2][3][n] + E.aggT[3][3][n];
    const float dg = E.aggT[0][4][n] + E.aggT[1][4][n] + E.aggT[2][4][n] + E.aggT[3][4][n];
    *(float4*)&E.aggC[n][0] = make_float4(a0, a1, a2, a3v);
    E.aggC[n][4] = dg;
  }
  __syncthreads();

  const int c = tid & 63, qq = tid >> 6;
  const float wc0 = E.w2s[c], wc1 = E.w2s[64 + c], wc2 = E.w2s[128 + c], wc3 = E.w2s[192 + c];
  const float b2c = E.b2s[c];
  float s = 0.f, ss = 0.f;
  for (int n = qq; n < 64; n += 4) {
    const float4 a = *(const float4*)&E.aggC[n][0];
    const float dg = E.aggC[n][4];
    float v = a.x * wc0 + a.y * wc1 + a.z * wc2 + a.w * wc3 + dg * b2c;
    st_b16_sys(&out0[(size_t)(((b << 6) + n) << 6) + c], f2bf(v));
    s += v; ss += v * v;
  }
  E.rs[qq][c] = s; E.rss[qq][c] = ss;
  __syncthreads();
  if (tid < 64) {
    float* dst = stats1 + ((b & (REP - 1)) << 7);
    atomicAdd(&dst[tid], E.rs[0][tid] + E.rs[1][tid] + E.rs[2][tid] + E.rs[3][tid]);
    atomicAdd(&dst[64 + tid], E.rss[0][tid] + E.rss[1][tid] + E.rss[2][tid] + E.rss[3][tid]);
  }
}

// ---------------------------------------------------------------------------
// k_pe: prep (blocks 0..416) merged with edge (blocks 417..1440).
// Stats zeroing is in the preceding memset; no intra-kernel dependency.
// LDS = max(SPrep, SEdge) = 11.4 KB -> 8 blocks/CU.
// ---------------------------------------------------------------------------
__global__ __launch_bounds__(256) void k_pe(
    const float* __restrict__ x, const int* __restrict__ ei,
    const float* __restrict__ w1, const float* __restrict__ b1,
    const float* __restrict__ w2, const float* __restrict__ b2,
    const float* __restrict__ wm1, const float* __restrict__ wm2,
    const float* __restrict__ wm3, const float* __restrict__ wp,
    const float* __restrict__ c2w, const float* __restrict__ c3w,
    ushort* __restrict__ wbf1t, ushort* __restrict__ wbf2t,
    ushort* __restrict__ wbf3t, ushort* __restrict__ wptbf,
    ushort* __restrict__ cwt2, ushort* __restrict__ cwt3,
    ushort* __restrict__ out0, float* __restrict__ stats1)
{
  __shared__ union { SPrep p; SEdge e; } sm;
  const int tid = threadIdx.x;
  const int bb = blockIdx.x;
  if (bb < 417)
    prep_body(sm.p, bb, tid, wm1, wm2, wm3, wp, c2w, c3w,
              wbf1t, wbf2t, wbf3t, wptbf, cwt2, cwt3);
  else
    edge_body(sm.e, bb - 417, tid, x, ei, w1, b1, w2, b2, out0, stats1);
}

// ---------------------------------------------------------------------------
// k_convm: BN + conv1d-as-MFMA for graph b. Stats via plain cached loads
// (kernel boundary provides coherence). Output via bypass stores.
// ---------------------------------------------------------------------------
__global__ __launch_bounds__(256) void k_convm(
    const ushort* __restrict__ in, const float* __restrict__ stats_in,
    const float* __restrict__ gamma, const float* __restrict__ beta,
    const ushort* __restrict__ cwt, const float* __restrict__ cb,
    ushort* __restrict__ out, float* __restrict__ stats_out)
{
  __shared__ SConv C;
  const int tid = threadIdx.x;
  const int b = blockIdx.x;

  if (tid < 64) {
    float smv = 0.f, sq = 0.f;
#pragma unroll 8
    for (int r = 0; r < REP; ++r) {
      smv += stats_in[(r << 7) + tid];
      sq += stats_in[(r << 7) + 64 + tid];
    }
    const float mean = smv * (1.0f / CNTF);
    const float var = sq * (1.0f / CNTF) - mean * mean;
    const float a = gamma[tid] * rsqrtf(var + EPSV);
    C.aco[tid] = a;
    C.bco[tid] = beta[tid] - mean * a;
    C.cbs[tid] = cb[tid];
    C.Yt[0][tid] = 0;
    C.Yt[65][tid] = 0;
  }
  __syncthreads();

  const size_t base = (size_t)b << 12;
  {
    const int lr = tid >> 2, p = (tid & 3) << 4;
    const ushort8 r0 = *(const ushort8*)&in[base + (lr << 6) + p];
    const ushort8 r1 = *(const ushort8*)&in[base + (lr << 6) + p + 8];
    ushort tmp[16];
#pragma unroll
    for (int j = 0; j < 8; ++j)
      tmp[j] = f2bf(fmaxf(fmaf(C.aco[p + j], bf2f(r0[j]), C.bco[p + j]), 0.f));
#pragma unroll
    for (int j = 0; j < 8; ++j)
      tmp[8 + j] = f2bf(fmaxf(fmaf(C.aco[p + 8 + j], bf2f(r1[j]), C.bco[p + 8 + j]), 0.f));
    *(ushort8*)&C.Yt[lr + 1][p] = *(ushort8*)&tmp[0];
    *(ushort8*)&C.Yt[lr + 1][p + 8] = *(ushort8*)&tmp[8];
  }
  {
    const ushort8* gw = (const ushort8*)cwt;
#pragma unroll
    for (int i = 0; i < 6; ++i) {
      const int e8 = (i << 8) + tid;
      const int o = e8 / 24, k8 = (e8 - o * 24) << 3;
      *(ushort8*)&C.As[o][k8] = gw[e8];
    }
  }
  __syncthreads();

  const int lane = tid & 63, w = tid >> 6;
  const int lm = lane & 15, q = lane >> 4;
  f32x4 acc[4];
#pragma unroll
  for (int nt = 0; nt < 4; ++nt) acc[nt] = (f32x4){0.f, 0.f, 0.f, 0.f};

#pragma unroll
  for (int kk = 0; kk < 3; ++kk) {
#pragma unroll
    for (int ks = 0; ks < 2; ++ks) {
      const short8 af = *(const short8*)&C.As[(w << 4) + lm][(kk << 6) + (ks << 5) + (q << 3)];
#pragma unroll
      for (int nt = 0; nt < 4; ++nt) {
        const short8 bfr = *(const short8*)&C.Yt[(nt << 4) + lm + kk][(ks << 5) + (q << 3)];
        acc[nt] = __builtin_amdgcn_mfma_f32_16x16x32_bf16(af, bfr, acc[nt], 0, 0, 0);
      }
    }
  }

  const int obase = (w << 4) + (q << 2);
  const float4 cb4 = *(const float4*)&C.cbs[obase];
  float s[4] = {0.f, 0.f, 0.f, 0.f}, ss[4] = {0.f, 0.f, 0.f, 0.f};
#pragma unroll
  for (int nt = 0; nt < 4; ++nt) {
    const int l = (nt << 4) + lm;
    float4 v = make_float4(acc[nt][0] + cb4.x, acc[nt][1] + cb4.y,
                           acc[nt][2] + cb4.z, acc[nt][3] + cb4.w);
    const uint u0 = (uint)f2bf(v.x) | ((uint)f2bf(v.y) << 16);
    const uint u1 = (uint)f2bf(v.z) | ((uint)f2bf(v.w) << 16);
    uint2v pk; pk.x = u0; pk.y = u1;
    st_b64_sys(&out[base + (l << 6) + obase], pk);
    s[0] += v.x; ss[0] += v.x * v.x;
    s[1] += v.y; ss[1] += v.y * v.y;
    s[2] += v.z; ss[2] += v.z * v.z;
    s[3] += v.w; ss[3] += v.w * v.w;
  }
#pragma unroll
  for (int i = 0; i < 4; ++i) {
#pragma unroll
    for (int off = 1; off < 16; off <<= 1) {
      s[i] += __shfl_xor(s[i], off);
      ss[i] += __shfl_xor(ss[i], off);
    }
    if (lm == 0) { C.ldsS[obase + i] = s[i]; C.ldsSS[obase + i] = ss[i]; }
  }
  __syncthreads();
  if (tid < 64) {
    float* dst = stats_out + ((b & (REP - 1)) << 7);
    atomicAdd(&dst[tid], C.ldsS[tid]);
    atomicAdd(&dst[64 + tid], C.ldsSS[tid]);
  }
}

// ---------------------------------------------------------------------------
// k_mlp1: R0 rich tiling. Grid (16 Mtiles of 64 graphs, 2 Ntiles of 128,
// 8 Ksplits); 256 blocks; acc[8]/wave. h1part via bypass stores.
// ---------------------------------------------------------------------------
__global__ __launch_bounds__(256) void k_mlp1(
    const ushort* __restrict__ z3, const float* __restrict__ stats3,
    const float* __restrict__ g3, const float* __restrict__ be3,
    const ushort* __restrict__ wbf1t, float* __restrict__ h1part)
{
  __shared__ SMlp M;
  const int tid = threadIdx.x;
  const int bx = blockIdx.x, by = blockIdx.y, bz = blockIdx.z;

  if (tid < 64) {
    float sme = 0.f, sq = 0.f;
#pragma unroll 8
    for (int r = 0; r < REP; ++r) {
      sme += stats3[(r << 7) + tid];
      sq += stats3[(r << 7) + 64 + tid];
    }
    const float mean = sme * (1.0f / CNTF);
    const float var = sq * (1.0f / CNTF) - mean * mean;
    const float a = g3[tid] * rsqrtf(var + EPSV);
    M.a3s[tid] = a;
    M.b3s[tid] = be3[tid] - mean * a;
  }
  __syncthreads();

  const int lane = tid & 63, w = tid >> 6;
  const int lm = lane & 15, q = lane >> 4;
  const int gy = tid >> 2, py = (tid & 3) << 4;   // Ys staging: graph, k-part
  const int nn = tid >> 1, pp = (tid & 1) << 2;   // Ws staging: n-row, short8-part
  const int g0 = bx << 6, n0 = by << 7;

  f32x4 acc[8];
#pragma unroll
  for (int nt = 0; nt < 8; ++nt) acc[nt] = (f32x4){0.f, 0.f, 0.f, 0.f};

  const size_t ybase = ((size_t)(g0 + gy) << 12);

#pragma unroll 1
  for (int ck = 0; ck < 8; ++ck) {
    const int kc = (bz << 9) + (ck << 6);
    if (ck) __syncthreads();
    // --- stage Ys: BN3+ReLU on bf16 z3 (channel = within-chunk index)
    {
      const ushort* src = z3 + ybase + kc + py;
      const ushort8 r0 = *(const ushort8*)src;
      const ushort8 r1 = *(const ushort8*)(src + 8);
      ushort tmp[16];
#pragma unroll
      for (int j = 0; j < 8; ++j)
        tmp[j] = f2bf(fmaxf(fmaf(M.a3s[py + j], bf2f(r0[j]), M.b3s[py + j]), 0.f));
#pragma unroll
      for (int j = 0; j < 8; ++j)
        tmp[8 + j] = f2bf(fmaxf(fmaf(M.a3s[py + 8 + j], bf2f(r1[j]), M.b3s[py + 8 + j]), 0.f));
      *(ushort8*)&M.Ys[gy][py] = *(ushort8*)&tmp[0];
      *(ushort8*)&M.Ys[gy][py + 8] = *(ushort8*)&tmp[8];
    }
    // --- stage Ws: straight copies from chunk-major wbf1t
    {
      const ushort8* gw = (const ushort8*)(wbf1t + ((size_t)((bz << 3) + ck) << 14) + ((size_t)n0 << 6));
#pragma unroll
      for (int i = 0; i < 4; ++i)
        *(ushort8*)&M.Ws[nn][(pp + i) << 3] = gw[(nn << 3) + pp + i];
    }
    __syncthreads();
#pragma unroll
    for (int ks = 0; ks < 2; ++ks) {
      const short8 af = *(const short8*)&M.Ys[(w << 4) + lm][(ks << 5) + (q << 3)];
#pragma unroll
      for (int nt = 0; nt < 8; ++nt) {
        const short8 bfr = *(const short8*)&M.Ws[(nt << 4) + lm][(ks << 5) + (q << 3)];
        acc[nt] = __builtin_amdgcn_mfma_f32_16x16x32_bf16(af, bfr, acc[nt], 0, 0, 0);
      }
    }
  }

  float* dst0 = h1part + ((size_t)bz << 18);
  const int gout = g0 + (w << 4) + (q << 2);
#pragma unroll
  for (int nt = 0; nt < 8; ++nt) {
    const int col = n0 + (nt << 4) + lm;
#pragma unroll
    for (int i = 0; i < 4; ++i)
      st_b32_sys(&dst0[((size_t)(gout + i) << 8) + col], acc[nt][i]);
  }
}

// ---------------------------------------------------------------------------
// k_tail: h1 reduce -> GEMM2 -> GEMM3 -> logits -> logsoftmax (64 blocks).
// B-operands direct from L2-hot global.
// ---------------------------------------------------------------------------
__global__ __launch_bounds__(256) void k_tail(
    const float* __restrict__ h1part, const float* __restrict__ bm1,
    const ushort* __restrict__ wbf2t, const float* __restrict__ bm2,
    const ushort* __restrict__ wbf3t, const float* __restrict__ bm3,
    const ushort* __restrict__ wptbf, const float* __restrict__ bp,
    float* __restrict__ out)
{
  __shared__ STail T;
  const int tid = threadIdx.x;
  const int g0 = blockIdx.x << 4;
  const int lane = tid & 63, w = tid >> 6;
  const int lm = lane & 15, q = lane >> 4;
  const int gr = q << 2;

  {
    const int r = tid >> 4, c0 = (tid & 15) << 4;
    const float* srcb = h1part + ((size_t)(g0 + r) << 8) + c0;
#pragma unroll
    for (int i = 0; i < 4; ++i) {
      float4 vs = *(const float4*)(bm1 + c0 + (i << 2));
#pragma unroll
      for (int bz = 0; bz < 8; ++bz) {
        const float4 p = *(const float4*)(srcb + ((size_t)bz << 18) + (i << 2));
        vs.x += p.x; vs.y += p.y; vs.z += p.z; vs.w += p.w;
      }
      *(ushort4*)&T.h1s[r][c0 + (i << 2)] = make_ushort4(
          f2bf(fmaxf(vs.x, 0.f)), f2bf(fmaxf(vs.y, 0.f)),
          f2bf(fmaxf(vs.z, 0.f)), f2bf(fmaxf(vs.w, 0.f)));
    }
  }
  __syncthreads();

  // ---- GEMM2 (B direct from global)
  f32x4 acc[4];
#pragma unroll
  for (int nt = 0; nt < 4; ++nt) acc[nt] = (f32x4){0.f, 0.f, 0.f, 0.f};
#pragma unroll
  for (int ck = 0; ck < 4; ++ck) {
#pragma unroll
    for (int ks = 0; ks < 2; ++ks) {
      const short8 af = *(const short8*)&T.h1s[lm][(ck << 6) + (ks << 5) + (q << 3)];
#pragma unroll
      for (int nt = 0; nt < 4; ++nt) {
        const int n = (w << 6) + (nt << 4) + lm;
        const short8 bfr = *(const short8*)&wbf2t[((size_t)ck << 14) + (n << 6) + (ks << 5) + (q << 3)];
        acc[nt] = __builtin_amdgcn_mfma_f32_16x16x32_bf16(af, bfr, acc[nt], 0, 0, 0);
      }
    }
  }
#pragma unroll
  for (int nt = 0; nt < 4; ++nt) {
    const int col = (w << 6) + (nt << 4) + lm;
    const float bv = bm2[col];
#pragma unroll
    for (int i = 0; i < 4; ++i)
      T.h2s[gr + i][col] = f2bf(fmaxf(acc[nt][i] + bv, 0.f));
  }
  __syncthreads();

  // ---- GEMM3 (B direct from global)
  f32x4 acc2[4];
#pragma unroll
  for (int nt = 0; nt < 4; ++nt) acc2[nt] = (f32x4){0.f, 0.f, 0.f, 0.f};
#pragma unroll
  for (int ck = 0; ck < 4; ++ck) {
#pragma unroll
    for (int ks = 0; ks < 2; ++ks) {
      const short8 af = *(const short8*)&T.h2s[lm][(ck << 6) + (ks << 5) + (q << 3)];
#pragma unroll
      for (int nt = 0; nt < 4; ++nt) {
        const int n = (w << 6) + (nt << 4) + lm;
        const short8 bfr = *(const short8*)&wbf3t[((size_t)ck << 14) + (n << 6) + (ks << 5) + (q << 3)];
        acc2[nt] = __builtin_amdgcn_mfma_f32_16x16x32_bf16(af, bfr, acc2[nt], 0, 0, 0);
      }
    }
  }
  __syncthreads();                  // all h2s reads done before overwrite
#pragma unroll
  for (int nt = 0; nt < 4; ++nt) {
    const int col = (w << 6) + (nt << 4) + lm;
    const float bv = bm3[col];
#pragma unroll
    for (int i = 0; i < 4; ++i)
      T.h2s[gr + i][col] = f2bf(fmaxf(acc2[nt][i] + bv, 0.f));
  }
  __syncthreads();

  if (w == 0) {
    f32x4 lacc = (f32x4){0.f, 0.f, 0.f, 0.f};
#pragma unroll
    for (int ks = 0; ks < 8; ++ks) {
      const short8 af = *(const short8*)&T.h2s[lm][(ks << 5) + (q << 3)];
      const short8 bfr = *(const short8*)&wptbf[(lm << 8) + (ks << 5) + (q << 3)];
      lacc = __builtin_amdgcn_mfma_f32_16x16x32_bf16(af, bfr, lacc, 0, 0, 0);
    }
    const float bpv = bp[lm];
    float lg[4], mx[4], se[4];
#pragma unroll
    for (int i = 0; i < 4; ++i) {
      lg[i] = lacc[i] + bpv;
      float m = lg[i];
#pragma unroll
      for (int off = 1; off < 16; off <<= 1) m = fmaxf(m, __shfl_xor(m, off));
      mx[i] = m;
      float e = expf(lg[i] - m);
#pragma unroll
      for (int off = 1; off < 16; off <<= 1) e += __shfl_xor(e, off);
      se[i] = e;
    }
#pragma unroll
    for (int i = 0; i < 4; ++i)
      out[((g0 + gr + i) << 4) + lm] = (lg[i] - mx[i]) - logf(se[i]);
  }
}

// ---------------------------------------------------------------------------
extern "C" void kernel_launch(void* const* d_in, const int* in_sizes, int n_in,
                              void* d_out, int out_size, void* d_ws, size_t ws_size,
                              hipStream_t stream)
{
  const float* x   = (const float*)d_in[0];
  const int*   ei  = (const int*)d_in[1];
  const float* w1  = (const float*)d_in[2];
  const float* b1  = (const float*)d_in[3];
  const float* w2  = (const float*)d_in[4];
  const float* b2  = (const float*)d_in[5];
  const float* c2w = (const float*)d_in[6];
  const float* c2b = (const float*)d_in[7];
  const float* c3w = (const float*)d_in[8];
  const float* c3b = (const float*)d_in[9];
  const float* g1  = (const float*)d_in[10];
  const float* be1 = (const float*)d_in[11];
  const float* g2  = (const float*)d_in[12];
  const float* be2 = (const float*)d_in[13];
  const float* g3  = (const float*)d_in[14];
  const float* be3 = (const float*)d_in[15];
  const float* wm1 = (const float*)d_in[16];
  const float* bm1 = (const float*)d_in[17];
  const float* wm2 = (const float*)d_in[18];
  const float* bm2 = (const float*)d_in[19];
  const float* wm3 = (const float*)d_in[20];
  const float* bm3 = (const float*)d_in[21];
  const float* wp  = (const float*)d_in[22];
  const float* bp  = (const float*)d_in[23];

  char* ws = (char*)d_ws;
  ushort* ubuf0 = (ushort*)ws;                          // 8 MiB: out0 (bf16)
  ushort* ubuf1 = (ushort*)(ws + ((size_t)8 << 20));    // 8 MiB: z2 (bf16)
  float*  h1part = (float*)(ws + ((size_t)16 << 20));   // 8 MiB fp32 partials
  ushort* wbf1t = (ushort*)(ws + ((size_t)24 << 20));   // 2 MiB bf16 wm1^T
  ushort* wbf2t = (ushort*)(ws + ((size_t)26 << 20));               // 128 KiB
  ushort* wbf3t = (ushort*)(ws + ((size_t)26 << 20) + (128 << 10)); // 128 KiB
  ushort* wptbf = (ushort*)(ws + ((size_t)26 << 20) + (256 << 10)); // 8 KiB
  float* stats = (float*)(ws + ((size_t)27 << 20));     // 48 KiB [3][REP][128]
  float* stats1 = stats;
  float* stats2 = stats + REP * 128;
  float* stats3 = stats + 2 * REP * 128;
  ushort* ubuf2 = (ushort*)(ws + ((size_t)32 << 20));   // 8 MiB: z3
  ushort* cwt2 = (ushort*)d_out;          // d_out scratch, overwritten at tail
  ushort* cwt3 = (ushort*)d_out + 12288;
  float* outp = (float*)d_out;

  // stats must be zero before edge atomics
  hipMemsetAsync(stats, 0, 3 * REP * 128 * sizeof(float), stream);

  // phase 0: weight prep (blocks 0..416) || edge conv (blocks 417..1440)
  k_pe<<<dim3(1441), dim3(256), 0, stream>>>(
      x, ei, w1, b1, w2, b2, wm1, wm2, wm3, wp, c2w, c3w,
      wbf1t, wbf2t, wbf3t, wptbf, cwt2, cwt3, ubuf0, stats1);
  // phase 1: BN1 + conv2
  k_convm<<<dim3(NB), dim3(256), 0, stream>>>(ubuf0, stats1, g1, be1, cwt2, c2b, ubuf1, stats2);
  // phase 2: BN2 + conv3
  k_convm<<<dim3(NB), dim3(256), 0, stream>>>(ubuf1, stats2, g2, be2, cwt3, c3b, ubuf2, stats3);
  // phase 3: BN3 + GEMM1 split-K partials
  k_mlp1<<<dim3(16, 2, 8), dim3(256), 0, stream>>>(ubuf2, stats3, g3, be3, wbf1t, h1part);
  // phase 4: tail
  k_tail<<<dim3(64), dim3(256), 0, stream>>>(h1part, bm1, wbf2t, bm2, wbf3t, bm3,
                                             wptbf, bp, outp);
}